// Round 3
// baseline (3884.196 us; speedup 1.0000x reference)
//
#include <hip/hip_runtime.h>
#include <hip/hip_bf16.h>

typedef __hip_bfloat16 bf16;
typedef _Float16 f16;

__device__ __forceinline__ float tof(float x){ return x; }
__device__ __forceinline__ float tof(f16 x){ return (float)x; }
__device__ __forceinline__ void stf(float* p, float v){ *p = v; }
__device__ __forceinline__ void stf(f16* p, float v){ *p = (f16)v; }

// ---------------------------------------------------------------- dtype detector
// flags[0] = 1 if float inputs are fp32, 0 if bf16.
// Method: decode first 512 halfwords of x as bf16; count exponents >= 0x88 or 0xFF.
// Genuine bf16 normals (|v|<~5): ~0 hits. fp32-reinterp: ~47% hits.
__global__ void detect_k(const unsigned short* __restrict__ xh, int* __restrict__ flags)
{
  if (threadIdx.x == 0 && blockIdx.x == 0) {
    int weird = 0;
    for (int i = 0; i < 512; ++i) {
      const int e = (xh[i] >> 7) & 0xFF;
      if (e == 0xFF || e >= 0x88) ++weird;
    }
    flags[0] = (weird > 32) ? 1 : 0;
  }
}

// ---------------------------------------------------------------- convert input -> fp32
__global__ __launch_bounds__(256) void cvt_k(
    const void* __restrict__ src, float* __restrict__ dst, int n, const int* __restrict__ flags)
{
  const int fp32 = flags[0];
  for (int i = blockIdx.x * 256 + threadIdx.x; i < n; i += gridDim.x * 256) {
    if (fp32) dst[i] = ((const float*)src)[i];
    else      dst[i] = __bfloat162float(((const bf16*)src)[i]);
  }
}

// ---------------------------------------------------------------- GEMM (all fp32)
// C(M,N) = act(A(M,K) @ B + bias) + res ; B is (K,N) or (N,K) if TRB.
// 64x64 tile, BK=16, 256 threads, 4x4 per thread. Dims multiples of 64/16.
template<bool TRB, int ACT>
__global__ __launch_bounds__(256) void gemm_k(
    const float* __restrict__ A, const float* __restrict__ B,
    const float* __restrict__ bias, const float* __restrict__ res,
    float* __restrict__ C, int M, int N, int K)
{
  __shared__ float As[16][64];
  __shared__ float Bs[16][64];
  const int tid = threadIdx.x;
  const int m0 = blockIdx.y * 64, n0 = blockIdx.x * 64;
  const int tx = tid & 15, ty = tid >> 4;
  float acc[4][4] = {};
  for (int k0 = 0; k0 < K; k0 += 16) {
    {
      const int m = tid >> 2, kq = tid & 3;
      const float* ap = A + (size_t)(m0 + m) * K + k0 + kq * 4;
      #pragma unroll
      for (int i = 0; i < 4; ++i) As[kq * 4 + i][m] = ap[i];
    }
    if (!TRB) {
      const int n = tid & 63, kb = tid >> 6;
      #pragma unroll
      for (int i = 0; i < 4; ++i)
        Bs[kb + i * 4][n] = B[(size_t)(k0 + kb + i * 4) * N + n0 + n];
    } else {
      const int n = tid >> 2, kq = tid & 3;
      const float* bp = B + (size_t)(n0 + n) * K + k0 + kq * 4;
      #pragma unroll
      for (int i = 0; i < 4; ++i) Bs[kq * 4 + i][n] = bp[i];
    }
    __syncthreads();
    #pragma unroll
    for (int kk = 0; kk < 16; ++kk) {
      float av[4], bv[4];
      #pragma unroll
      for (int i = 0; i < 4; ++i) av[i] = As[kk][ty * 4 + i];
      #pragma unroll
      for (int j = 0; j < 4; ++j) bv[j] = Bs[kk][tx * 4 + j];
      #pragma unroll
      for (int i = 0; i < 4; ++i)
        #pragma unroll
        for (int j = 0; j < 4; ++j) acc[i][j] += av[i] * bv[j];
    }
    __syncthreads();
  }
  #pragma unroll
  for (int i = 0; i < 4; ++i) {
    const int row = m0 + ty * 4 + i;
    #pragma unroll
    for (int j = 0; j < 4; ++j) {
      const int col = n0 + tx * 4 + j;
      float v = acc[i][j];
      if (bias) v += bias[col];
      if (ACT == 1) v = 0.5f * v * (1.0f + erff(v * 0.70710678118654752f));
      if (res) v += res[(size_t)row * N + col];
      C[(size_t)row * N + col] = v;
    }
  }
}

// ---------------------------------------------------------------- LayerNorm (row len 256)
__global__ __launch_bounds__(256) void ln_k(
    const float* __restrict__ in, float* __restrict__ out,
    const float* __restrict__ g, const float* __restrict__ b)
{
  const int row = blockIdx.x, t = threadIdx.x;
  __shared__ float red[256];
  float x = in[(size_t)row * 256 + t];
  red[t] = x; __syncthreads();
  for (int s = 128; s > 0; s >>= 1) { if (t < s) red[t] += red[t + s]; __syncthreads(); }
  const float m = red[0] * (1.0f / 256.0f);
  __syncthreads();
  const float d = x - m;
  red[t] = d * d; __syncthreads();
  for (int s = 128; s > 0; s >>= 1) { if (t < s) red[t] += red[t + s]; __syncthreads(); }
  const float rstd = rsqrtf(red[0] * (1.0f / 256.0f) + 1e-5f);
  out[(size_t)row * 256 + t] = d * rstd * g[t] + b[t];
}

// ---------------------------------------------------------------- L2 normalize rows (len 256), in place
__global__ __launch_bounds__(256) void l2n_k(float* __restrict__ x)
{
  const int row = blockIdx.x, t = threadIdx.x;
  __shared__ float red[256];
  float v = x[(size_t)row * 256 + t];
  red[t] = v * v; __syncthreads();
  for (int s = 128; s > 0; s >>= 1) { if (t < s) red[t] += red[t + s]; __syncthreads(); }
  x[(size_t)row * 256 + t] = v * rsqrtf(red[0]);
}

// ---------------------------------------------------------------- pos MLP: (s,c)->256, per patch
// patch_code may be int32 pairs or raw int64 words. Patch 1 is (0,1):
// int32 layout -> pc[3]==1 ; int64 layout -> pc[3]==0.
__global__ __launch_bounds__(256) void pos_k(
    const int* __restrict__ pc, const float* __restrict__ w1, const float* __restrict__ b1,
    const float* __restrict__ w2, const float* __restrict__ b2, float* __restrict__ pos)
{
  const int n = blockIdx.x, t = threadIdx.x;
  __shared__ float h[256];
  const int wide = (pc[3] == 0);
  const int sv = wide ? pc[4 * n] : pc[2 * n];
  const int cv = wide ? pc[4 * n + 2] : pc[2 * n + 1];
  float hv = (float)sv * w1[t] + (float)cv * w1[256 + t] + b1[t];
  h[t] = hv > 0.0f ? hv : 0.0f;
  __syncthreads();
  float acc = b2[t];
  for (int k = 0; k < 256; ++k) acc += h[k] * w2[k * 256 + t];
  pos[n * 256 + t] = acc;
}

// ---------------------------------------------------------------- assemble x = [proj+pos ; cls]
__global__ __launch_bounds__(256) void assemble_k(
    const float* __restrict__ proj, const float* __restrict__ pos,
    const float* __restrict__ cls, float* __restrict__ xb)
{
  const int row = blockIdx.x;           // 0..B*896-1
  const int b = row / 896, n = row % 896, t = threadIdx.x;
  float v;
  if (n < 640) v = proj[((size_t)b * 640 + n) * 256 + t] + pos[n * 256 + t];
  else         v = cls[(n - 640) * 256 + t];
  xb[(size_t)row * 256 + t] = v;
}

// ---------------------------------------------------------------- attention: one block per (q,h,b)
__global__ __launch_bounds__(256) void attn_k(
    const float* __restrict__ qkv, float* __restrict__ out)
{
  const int q = blockIdx.x, h = blockIdx.y, b = blockIdx.z, t = threadIdx.x;
  __shared__ float sc[896];
  __shared__ float qs[32];
  __shared__ float red[256];
  const float* qp = qkv + ((size_t)(b * 896 + q) * 768) + h * 32;
  if (t < 32) qs[t] = qp[t];
  __syncthreads();
  float lmax = -1e30f;
  for (int kk = t; kk < 896; kk += 256) {
    const float* kp = qkv + ((size_t)(b * 896 + kk) * 768) + 256 + h * 32;
    float s = 0.0f;
    #pragma unroll
    for (int d = 0; d < 32; ++d) s += qs[d] * kp[d];
    s *= 0.17677669529663687f;   // 1/sqrt(32)
    sc[kk] = s; lmax = fmaxf(lmax, s);
  }
  red[t] = lmax; __syncthreads();
  for (int s = 128; s > 0; s >>= 1) { if (t < s) red[t] = fmaxf(red[t], red[t + s]); __syncthreads(); }
  const float m = red[0]; __syncthreads();
  float lsum = 0.0f;
  for (int kk = t; kk < 896; kk += 256) { float p = expf(sc[kk] - m); sc[kk] = p; lsum += p; }
  red[t] = lsum; __syncthreads();
  for (int s = 128; s > 0; s >>= 1) { if (t < s) red[t] += red[t + s]; __syncthreads(); }
  const float denom = red[0];
  __syncthreads();
  const int d = t & 31, g = t >> 5;              // 8 k-groups of 112
  float part = 0.0f;
  for (int kk = g * 112; kk < (g + 1) * 112; ++kk)
    part += sc[kk] * qkv[((size_t)(b * 896 + kk) * 768) + 512 + h * 32 + d];
  red[t] = part; __syncthreads();
  if (t < 32) {
    float o = 0.0f;
    #pragma unroll
    for (int gg = 0; gg < 8; ++gg) o += red[gg * 32 + t];
    out[((size_t)(b * 896 + q) * 256) + h * 32 + t] = o / denom;
  }
}

// ---------------------------------------------------------------- build inv table (1024 pixels)
__global__ __launch_bounds__(1024) void inv_k(const int* __restrict__ pc, int* __restrict__ inv)
{
  const int t = threadIdx.x;
  if (t < 1024) inv[t] = 0;
  __syncthreads();
  if (t < 640) {
    const int wide = (pc[3] == 0);
    int s = wide ? pc[4 * t] : pc[2 * t];
    int coord = wide ? pc[4 * t + 2] : pc[2 * t + 1];
    s &= 1;
    const int gs = 16 << s;
    const int k = 1 << (1 - s);
    const int r = (coord / gs) * k, c = (coord % gs) * k;
    for (int oi = 0; oi < k; ++oi)
      for (int oj = 0; oj < k; ++oj) {
        const int rr = r + oi, cc = c + oj;
        if (rr >= 0 && rr < 32 && cc >= 0 && cc < 32)
          inv[rr * 32 + cc] = t;
      }
  }
}

// ---------------------------------------------------------------- gather masks -> img0 (B,256,32,32)
template<typename T>
__global__ __launch_bounds__(256) void gather_k(
    const float* __restrict__ masks, const int* __restrict__ inv, T* __restrict__ img)
{
  const int idx = blockIdx.x * 256 + threadIdx.x;   // 2*256*1024
  const int p = idx & 1023;
  const int rest = idx >> 10;
  const int d = rest & 255, b = rest >> 8;
  stf(&img[idx], masks[((size_t)b * 640 + inv[p]) * 256 + d]);
}

// ---------------------------------------------------------------- conv3x3 SAME, 256->32-chunk of 256
template<typename T>
__global__ __launch_bounds__(256) void conv3_k(
    const T* __restrict__ x, const float* __restrict__ w,
    const float* __restrict__ bias, T* __restrict__ y, int H, int W)
{
  const int tile = blockIdx.x;
  const int tw = W >> 4;
  const int ty0 = (tile / tw) << 4, tx0 = (tile % tw) << 4;
  const int co0 = blockIdx.y << 5;
  const int b = blockIdx.z;
  const int t = threadIdx.x;
  const int py = t >> 4, px = t & 15;
  const int oy = ty0 + py, ox = tx0 + px;
  __shared__ float xin[8][18][18];
  __shared__ float ws_[8][9][32];
  float acc[32];
  #pragma unroll
  for (int i = 0; i < 32; ++i) acc[i] = 0.0f;
  for (int c0 = 0; c0 < 256; c0 += 8) {
    for (int i = t; i < 8 * 324; i += 256) {
      const int ci = i / 324, r = i % 324, yy = r / 18, xx = r % 18;
      const int gy = ty0 + yy - 1, gx = tx0 + xx - 1;
      float v = 0.0f;
      if (gy >= 0 && gy < H && gx >= 0 && gx < W)
        v = tof(x[(((size_t)b * 256 + c0 + ci) * H + gy) * W + gx]);
      xin[ci][yy][xx] = v;
    }
    for (int i = t; i < 8 * 9 * 32; i += 256) {
      const int co = i & 31, r = i >> 5, ci = r / 9, kk = r % 9;
      ws_[ci][kk][co] = w[(((size_t)(co0 + co) * 256) + c0 + ci) * 9 + kk];
    }
    __syncthreads();
    #pragma unroll
    for (int ci = 0; ci < 8; ++ci) {
      #pragma unroll
      for (int kk = 0; kk < 9; ++kk) {
        const float v = xin[ci][py + kk / 3][px + kk % 3];
        #pragma unroll
        for (int co = 0; co < 32; ++co) acc[co] += v * ws_[ci][kk][co];
      }
    }
    __syncthreads();
  }
  #pragma unroll
  for (int co = 0; co < 32; ++co)
    stf(&y[(((size_t)b * 256 + co0 + co) * H + oy) * W + ox], acc[co] + bias[co0 + co]);
}

// ---------------------------------------------------------------- convT 2x2 stride 2 (H,W in; 2H,2W out)
template<typename T>
__global__ __launch_bounds__(256) void convt_k(
    const T* __restrict__ x, const float* __restrict__ w,
    const float* __restrict__ bias, T* __restrict__ y, int H, int W)
{
  const int tile = blockIdx.x;
  const int tw = (2 * W) >> 4;
  const int oy0 = (tile / tw) << 4, ox0 = (tile % tw) << 4;
  const int co0 = blockIdx.y << 5;
  const int b = blockIdx.z;
  const int t = threadIdx.x;
  const int py = t >> 4, px = t & 15;
  const int oy = oy0 + py, ox = ox0 + px;
  const int ly = py >> 1, lx = px >> 1;
  const int ij = (oy & 1) * 2 + (ox & 1);
  const int iy0 = oy0 >> 1, ix0 = ox0 >> 1;
  __shared__ float xin[8][8][8];
  __shared__ float ws_[8][32][4];
  float acc[32];
  #pragma unroll
  for (int i = 0; i < 32; ++i) acc[i] = 0.0f;
  for (int c0 = 0; c0 < 256; c0 += 8) {
    for (int i = t; i < 8 * 64; i += 256) {
      const int ci = i >> 6, r = i & 63, yy = r >> 3, xx = r & 7;
      xin[ci][yy][xx] = tof(x[(((size_t)b * 256 + c0 + ci) * H + iy0 + yy) * W + ix0 + xx]);
    }
    for (int i = t; i < 8 * 32 * 4; i += 256) {
      const int ci = i >> 7, r = i & 127, co = r >> 2, jj = r & 3;
      ws_[ci][co][jj] = w[(((size_t)(c0 + ci) * 256) + co0 + co) * 4 + jj];
    }
    __syncthreads();
    #pragma unroll
    for (int ci = 0; ci < 8; ++ci) {
      const float v = xin[ci][ly][lx];
      #pragma unroll
      for (int co = 0; co < 32; ++co) acc[co] += v * ws_[ci][co][ij];
    }
    __syncthreads();
  }
  #pragma unroll
  for (int co = 0; co < 32; ++co)
    stf(&y[(((size_t)b * 256 + co0 + co) * (2 * H) + oy) * (2 * W) + ox], acc[co] + bias[co0 + co]);
}

// ---------------------------------------------------------------- instance norm + leaky, in place
template<typename T>
__global__ __launch_bounds__(256) void inorm_k(T* __restrict__ x, int HW)
{
  const int bc = blockIdx.x, t = threadIdx.x;
  T* p = x + (size_t)bc * HW;
  float s = 0.0f, s2 = 0.0f;
  for (int i = t; i < HW; i += 256) { const float v = tof(p[i]); s += v; s2 += v * v; }
  __shared__ float r1[256], r2[256];
  r1[t] = s; r2[t] = s2; __syncthreads();
  for (int st = 128; st > 0; st >>= 1) {
    if (t < st) { r1[t] += r1[t + st]; r2[t] += r2[t + st]; }
    __syncthreads();
  }
  const float m = r1[0] / (float)HW;
  const float var = fmaxf(r2[0] / (float)HW - m * m, 0.0f);
  const float rstd = rsqrtf(var + 1e-5f);
  for (int i = t; i < HW; i += 256) {
    float v = (tof(p[i]) - m) * rstd;
    stf(&p[i], v >= 0.0f ? v : 0.01f * v);
  }
}

// ---------------------------------------------------------------- out conv 3x3: 256 -> 3; dtype per flag
template<typename T>
__global__ __launch_bounds__(256) void convout_k(
    const T* __restrict__ x, const float* __restrict__ w,
    const float* __restrict__ bias, void* __restrict__ yv, const int* __restrict__ flags)
{
  const int H = 256, W = 256;
  const int tile = blockIdx.x;
  const int tw = W >> 4;
  const int ty0 = (tile / tw) << 4, tx0 = (tile % tw) << 4;
  const int b = blockIdx.y;
  const int t = threadIdx.x;
  const int py = t >> 4, px = t & 15;
  const int oy = ty0 + py, ox = tx0 + px;
  __shared__ float xin[8][18][18];
  __shared__ float ws_[8][9][3];
  float acc[3] = {0.0f, 0.0f, 0.0f};
  for (int c0 = 0; c0 < 256; c0 += 8) {
    for (int i = t; i < 8 * 324; i += 256) {
      const int ci = i / 324, r = i % 324, yy = r / 18, xx = r % 18;
      const int gy = ty0 + yy - 1, gx = tx0 + xx - 1;
      float v = 0.0f;
      if (gy >= 0 && gy < H && gx >= 0 && gx < W)
        v = tof(x[(((size_t)b * 256 + c0 + ci) * H + gy) * W + gx]);
      xin[ci][yy][xx] = v;
    }
    for (int i = t; i < 8 * 9 * 3; i += 256) {
      const int co = i % 3, r = i / 3, ci = r / 9, kk = r % 9;
      ws_[ci][kk][co] = w[(((size_t)co * 256) + c0 + ci) * 9 + kk];
    }
    __syncthreads();
    #pragma unroll
    for (int ci = 0; ci < 8; ++ci) {
      #pragma unroll
      for (int kk = 0; kk < 9; ++kk) {
        const float v = xin[ci][py + kk / 3][px + kk % 3];
        #pragma unroll
        for (int co = 0; co < 3; ++co) acc[co] += v * ws_[ci][kk][co];
      }
    }
    __syncthreads();
  }
  const int fp32 = flags[0];
  #pragma unroll
  for (int co = 0; co < 3; ++co) {
    const size_t oidx = (((size_t)b * 3 + co) * H + oy) * W + ox;
    const float v = acc[co] + bias[co];
    if (fp32) ((float*)yv)[oidx] = v;
    else      ((bf16*)yv)[oidx] = __float2bfloat16(v);
  }
}

// ---------------------------------------------------------------- conv pipeline
template<typename T>
static void launch_convs(const float* masksb, const int* invbuf,
                         const float* ucw, const float* ucb,
                         const float* utw, const float* utb,
                         const float* ocw, const float* ocb,
                         T* R0, T* R1, T* R2, void* out, const int* flags, hipStream_t stream)
{
  gather_k<T><<<2048, 256, 0, stream>>>(masksb, invbuf, R0);
  int H = 32;
  for (int i = 0; i < 3; ++i) {
    conv3_k<T><<<dim3((H / 16) * (H / 16), 8, 2), 256, 0, stream>>>(
        R0, ucw + (size_t)i * 589824, ucb + i * 256, R1, H, H);
    inorm_k<T><<<512, 256, 0, stream>>>(R1, H * H);
    T* dst = (i == 2) ? R2 : R0;
    convt_k<T><<<dim3((2 * H / 16) * (2 * H / 16), 8, 2), 256, 0, stream>>>(
        R1, utw + (size_t)i * 262144, utb + i * 256, dst, H, H);
    inorm_k<T><<<512, 256, 0, stream>>>(dst, 4 * H * H);
    H *= 2;
  }
  convout_k<T><<<dim3(256, 2), 256, 0, stream>>>(R2, ocw, ocb, out, flags);
}

// ================================================================ host
extern "C" void kernel_launch(void* const* d_in, const int* in_sizes, int n_in,
                              void* d_out, int out_size, void* d_ws, size_t ws_size,
                              hipStream_t stream) {
  (void)in_sizes; (void)n_in; (void)out_size;
  const int* pc = (const int*)d_in[1];

  // ---- ws layout: [fp32 param copies | flags | conv activation regions] ----
  float* P = (float*)d_ws;
  size_t off = 0;
  auto alloc = [&](size_t n) { float* p = P + off; off += n; return p; };
  float* px    = alloc(655360);   // x
  float* pdw   = alloc(131072);   // proj_dec_w
  float* pdb   = alloc(256);
  float* pw1   = alloc(512);
  float* pb1   = alloc(256);
  float* pw2   = alloc(65536);
  float* pb2   = alloc(256);
  float* pcls  = alloc(65536);
  float* pln1g = alloc(512);
  float* pln1b = alloc(512);
  float* pqkvw = alloc(393216);
  float* pqkvb = alloc(1536);
  float* pattw = alloc(131072);
  float* pattb = alloc(512);
  float* pln2g = alloc(512);
  float* pln2b = alloc(512);
  float* pm1w  = alloc(524288);
  float* pm1b  = alloc(2048);
  float* pm2w  = alloc(524288);
  float* pm2b  = alloc(512);
  float* pdecg = alloc(256);
  float* pdecb = alloc(256);
  float* pprp  = alloc(65536);
  float* pprc  = alloc(65536);
  float* pmg   = alloc(256);
  float* pmb   = alloc(256);
  float* pucw  = alloc(1769472);
  float* pucb  = alloc(768);
  float* putw  = alloc(786432);
  float* putb  = alloc(768);
  float* pocw  = alloc(6912);
  float* pocb  = alloc(16);
  int*   flags = (int*)(P + off); off += 16;
  off = (off + 255) & ~(size_t)255;

  // conv activation regions after params
  char* actbase = (char*)(P + off);
  const size_t actoff = off * 4;
  // Plan A (fp32 acts) needs actoff + 201,326,592 B; Plan B (f16) actoff + 100,663,296 B.
  const bool planA = (ws_size >= actoff + 201326592ull);
  const size_t eb = planA ? 4 : 2;
  void* R0v = actbase;
  void* R1v = actbase + (size_t)8388608 * eb;
  char* R2v = actbase + (size_t)16777216 * eb;

  // transformer fp32 scratch overlaid at start of R2 region (dead before stage-3 convT)
  float* xbuf   = (float*)R2v;              // 2*896*256
  float* hbuf   = xbuf + 458752;
  float* qkvbuf = hbuf + 458752;            // 2*896*768
  float* hidbuf = qkvbuf + 1376256;         // 2*896*1024
  float* posbuf = hidbuf + 1835008;         // 640*256
  float* patbuf = posbuf + 163840;          // 2*640*256
  float* clsbuf = patbuf + 327680;          // 2*256*256
  float* masksb = clsbuf + 131072;          // 2*640*256
  int*   invbuf = (int*)(masksb + 327680);  // 1024

  // 0) dtype detect + convert every float input to fp32
  detect_k<<<1, 64, 0, stream>>>((const unsigned short*)d_in[0], flags);
  auto CV = [&](int idx, float* dst, int n) {
    int grid = (n + 255) / 256; if (grid > 2048) grid = 2048;
    cvt_k<<<grid, 256, 0, stream>>>(d_in[idx], dst, n, flags);
  };
  CV(0, px, 655360);   CV(2, pdw, 131072);  CV(3, pdb, 256);
  CV(4, pw1, 512);     CV(5, pb1, 256);     CV(6, pw2, 65536);   CV(7, pb2, 256);
  CV(8, pcls, 65536);  CV(9, pln1g, 512);   CV(10, pln1b, 512);
  CV(11, pqkvw, 393216); CV(12, pqkvb, 1536);
  CV(13, pattw, 131072); CV(14, pattb, 512);
  CV(15, pln2g, 512);  CV(16, pln2b, 512);
  CV(17, pm1w, 524288); CV(18, pm1b, 2048);
  CV(19, pm2w, 524288); CV(20, pm2b, 512);
  CV(21, pdecg, 256);  CV(22, pdecb, 256);
  CV(23, pprp, 65536); CV(24, pprc, 65536);
  CV(25, pmg, 256);    CV(26, pmb, 256);
  CV(27, pucw, 1769472); CV(28, pucb, 768);
  CV(29, putw, 786432);  CV(30, putb, 768);
  CV(31, pocw, 6912);    CV(32, pocb, 3);

  // 1) positional MLP + patch projection + sequence assembly
  pos_k<<<640, 256, 0, stream>>>(pc, pw1, pb1, pw2, pb2, posbuf);
  gemm_k<false, 0><<<dim3(4, 20), 256, 0, stream>>>(
      px, pdw, pdb, nullptr, hidbuf, 1280, 256, 512);
  assemble_k<<<1792, 256, 0, stream>>>(hidbuf, posbuf, pcls, xbuf);

  // 2) transformer blocks
  for (int l = 0; l < 2; ++l) {
    ln_k<<<1792, 256, 0, stream>>>(xbuf, hbuf, pln1g + l * 256, pln1b + l * 256);
    gemm_k<false, 0><<<dim3(12, 28), 256, 0, stream>>>(
        hbuf, pqkvw + (size_t)l * 196608, pqkvb + l * 768, nullptr, qkvbuf, 1792, 768, 256);
    attn_k<<<dim3(896, 8, 2), 256, 0, stream>>>(qkvbuf, hbuf);
    gemm_k<false, 0><<<dim3(4, 28), 256, 0, stream>>>(
        hbuf, pattw + (size_t)l * 65536, pattb + l * 256, xbuf, xbuf, 1792, 256, 256);
    ln_k<<<1792, 256, 0, stream>>>(xbuf, hbuf, pln2g + l * 256, pln2b + l * 256);
    gemm_k<false, 1><<<dim3(16, 28), 256, 0, stream>>>(
        hbuf, pm1w + (size_t)l * 262144, pm1b + l * 1024, nullptr, hidbuf, 1792, 1024, 256);
    gemm_k<false, 0><<<dim3(4, 28), 256, 0, stream>>>(
        hidbuf, pm2w + (size_t)l * 262144, pm2b + l * 256, xbuf, xbuf, 1792, 256, 1024);
  }

  // 3) decoder head: LN, projections, L2 norm, masks, mask-LN
  ln_k<<<1792, 256, 0, stream>>>(xbuf, hbuf, pdecg, pdecb);
  for (int b = 0; b < 2; ++b) {
    gemm_k<false, 0><<<dim3(4, 10), 256, 0, stream>>>(
        hbuf + (size_t)b * 896 * 256, pprp, nullptr, nullptr,
        patbuf + (size_t)b * 640 * 256, 640, 256, 256);
    gemm_k<false, 0><<<dim3(4, 4), 256, 0, stream>>>(
        hbuf + ((size_t)b * 896 + 640) * 256, pprc, nullptr, nullptr,
        clsbuf + (size_t)b * 65536, 256, 256, 256);
  }
  l2n_k<<<1280, 256, 0, stream>>>(patbuf);
  l2n_k<<<512, 256, 0, stream>>>(clsbuf);
  for (int b = 0; b < 2; ++b) {
    gemm_k<true, 0><<<dim3(4, 10), 256, 0, stream>>>(
        patbuf + (size_t)b * 163840, clsbuf + (size_t)b * 65536, nullptr, nullptr,
        masksb + (size_t)b * 163840, 640, 256, 256);
  }
  ln_k<<<1280, 256, 0, stream>>>(masksb, masksb, pmg, pmb);

  // 4) scatter table
  inv_k<<<1, 1024, 0, stream>>>(pc, invbuf);

  // 5) conv decoder + output head
  if (planA) {
    launch_convs<float>(masksb, invbuf, pucw, pucb, putw, putb, pocw, pocb,
                        (float*)R0v, (float*)R1v, (float*)R2v, d_out, flags, stream);
  } else {
    launch_convs<f16>(masksb, invbuf, pucw, pucb, putw, putb, pocw, pocb,
                      (f16*)R0v, (f16*)R1v, (f16*)R2v, d_out, flags, stream);
  }
}

// Round 4
// 3602.516 us; speedup vs baseline: 1.0782x; 1.0782x over previous
//
#include <hip/hip_runtime.h>
#include <hip/hip_bf16.h>

typedef __hip_bfloat16 bf16;
typedef _Float16 f16;

__device__ __forceinline__ float tof(float x){ return x; }
__device__ __forceinline__ float tof(f16 x){ return (float)x; }
__device__ __forceinline__ void stf(float* p, float v){ *p = v; }
__device__ __forceinline__ void stf(f16* p, float v){ *p = (f16)v; }

// ---------------------------------------------------------------- dtype detector
__global__ void detect_k(const unsigned short* __restrict__ xh, int* __restrict__ flags)
{
  if (threadIdx.x == 0 && blockIdx.x == 0) {
    int weird = 0;
    for (int i = 0; i < 512; ++i) {
      const int e = (xh[i] >> 7) & 0xFF;
      if (e == 0xFF || e >= 0x88) ++weird;
    }
    flags[0] = (weird > 32) ? 1 : 0;
  }
}

// ---------------------------------------------------------------- batched input->fp32 convert
#define NSEG 33
struct CvtDesc {
  const void* src[NSEG];
  unsigned dstOff[NSEG];
  unsigned n[NSEG];
};
__global__ __launch_bounds__(256) void cvtall_k(
    CvtDesc d, float* __restrict__ P, const int* __restrict__ flags)
{
  const int s = blockIdx.y;
  const unsigned n = d.n[s];
  const int fp32 = flags[0];
  float* dst = P + d.dstOff[s];
  const unsigned stride = gridDim.x * 256u;
  if (fp32) {
    const float* src = (const float*)d.src[s];
    for (unsigned i = blockIdx.x * 256u + threadIdx.x; i < n; i += stride) dst[i] = src[i];
  } else {
    const bf16* src = (const bf16*)d.src[s];
    for (unsigned i = blockIdx.x * 256u + threadIdx.x; i < n; i += stride)
      dst[i] = __bfloat162float(src[i]);
  }
}

// ---------------------------------------------------------------- GEMM (all fp32)
template<bool TRB, int ACT>
__global__ __launch_bounds__(256) void gemm_k(
    const float* __restrict__ A, const float* __restrict__ B,
    const float* __restrict__ bias, const float* __restrict__ res,
    float* __restrict__ C, int M, int N, int K)
{
  __shared__ float As[16][64];
  __shared__ float Bs[16][64];
  const int tid = threadIdx.x;
  const int m0 = blockIdx.y * 64, n0 = blockIdx.x * 64;
  const int tx = tid & 15, ty = tid >> 4;
  float acc[4][4] = {};
  for (int k0 = 0; k0 < K; k0 += 16) {
    {
      const int m = tid >> 2, kq = tid & 3;
      const float* ap = A + (size_t)(m0 + m) * K + k0 + kq * 4;
      #pragma unroll
      for (int i = 0; i < 4; ++i) As[kq * 4 + i][m] = ap[i];
    }
    if (!TRB) {
      const int n = tid & 63, kb = tid >> 6;
      #pragma unroll
      for (int i = 0; i < 4; ++i)
        Bs[kb + i * 4][n] = B[(size_t)(k0 + kb + i * 4) * N + n0 + n];
    } else {
      const int n = tid >> 2, kq = tid & 3;
      const float* bp = B + (size_t)(n0 + n) * K + k0 + kq * 4;
      #pragma unroll
      for (int i = 0; i < 4; ++i) Bs[kq * 4 + i][n] = bp[i];
    }
    __syncthreads();
    #pragma unroll
    for (int kk = 0; kk < 16; ++kk) {
      float av[4], bv[4];
      #pragma unroll
      for (int i = 0; i < 4; ++i) av[i] = As[kk][ty * 4 + i];
      #pragma unroll
      for (int j = 0; j < 4; ++j) bv[j] = Bs[kk][tx * 4 + j];
      #pragma unroll
      for (int i = 0; i < 4; ++i)
        #pragma unroll
        for (int j = 0; j < 4; ++j) acc[i][j] += av[i] * bv[j];
    }
    __syncthreads();
  }
  #pragma unroll
  for (int i = 0; i < 4; ++i) {
    const int row = m0 + ty * 4 + i;
    #pragma unroll
    for (int j = 0; j < 4; ++j) {
      const int col = n0 + tx * 4 + j;
      float v = acc[i][j];
      if (bias) v += bias[col];
      if (ACT == 1) v = 0.5f * v * (1.0f + erff(v * 0.70710678118654752f));
      if (res) v += res[(size_t)row * N + col];
      C[(size_t)row * N + col] = v;
    }
  }
}

// ---------------------------------------------------------------- LayerNorm (row len 256)
__global__ __launch_bounds__(256) void ln_k(
    const float* __restrict__ in, float* __restrict__ out,
    const float* __restrict__ g, const float* __restrict__ b)
{
  const int row = blockIdx.x, t = threadIdx.x;
  __shared__ float red[256];
  float x = in[(size_t)row * 256 + t];
  red[t] = x; __syncthreads();
  for (int s = 128; s > 0; s >>= 1) { if (t < s) red[t] += red[t + s]; __syncthreads(); }
  const float m = red[0] * (1.0f / 256.0f);
  __syncthreads();
  const float d = x - m;
  red[t] = d * d; __syncthreads();
  for (int s = 128; s > 0; s >>= 1) { if (t < s) red[t] += red[t + s]; __syncthreads(); }
  const float rstd = rsqrtf(red[0] * (1.0f / 256.0f) + 1e-5f);
  out[(size_t)row * 256 + t] = d * rstd * g[t] + b[t];
}

// ---------------------------------------------------------------- L2 normalize rows (len 256)
__global__ __launch_bounds__(256) void l2n_k(float* __restrict__ x)
{
  const int row = blockIdx.x, t = threadIdx.x;
  __shared__ float red[256];
  float v = x[(size_t)row * 256 + t];
  red[t] = v * v; __syncthreads();
  for (int s = 128; s > 0; s >>= 1) { if (t < s) red[t] += red[t + s]; __syncthreads(); }
  x[(size_t)row * 256 + t] = v * rsqrtf(red[0]);
}

// ---------------------------------------------------------------- pos MLP
__global__ __launch_bounds__(256) void pos_k(
    const int* __restrict__ pc, const float* __restrict__ w1, const float* __restrict__ b1,
    const float* __restrict__ w2, const float* __restrict__ b2, float* __restrict__ pos)
{
  const int n = blockIdx.x, t = threadIdx.x;
  __shared__ float h[256];
  const int wide = (pc[3] == 0);
  const int sv = wide ? pc[4 * n] : pc[2 * n];
  const int cv = wide ? pc[4 * n + 2] : pc[2 * n + 1];
  float hv = (float)sv * w1[t] + (float)cv * w1[256 + t] + b1[t];
  h[t] = hv > 0.0f ? hv : 0.0f;
  __syncthreads();
  float acc = b2[t];
  for (int k = 0; k < 256; ++k) acc += h[k] * w2[k * 256 + t];
  pos[n * 256 + t] = acc;
}

// ---------------------------------------------------------------- assemble x = [proj+pos ; cls]
__global__ __launch_bounds__(256) void assemble_k(
    const float* __restrict__ proj, const float* __restrict__ pos,
    const float* __restrict__ cls, float* __restrict__ xb)
{
  const int row = blockIdx.x;
  const int b = row / 896, n = row % 896, t = threadIdx.x;
  float v;
  if (n < 640) v = proj[((size_t)b * 640 + n) * 256 + t] + pos[n * 256 + t];
  else         v = cls[(n - 640) * 256 + t];
  xb[(size_t)row * 256 + t] = v;
}

// ---------------------------------------------------------------- attention: one block per (q,h,b)
__global__ __launch_bounds__(256) void attn_k(
    const float* __restrict__ qkv, float* __restrict__ out)
{
  const int q = blockIdx.x, h = blockIdx.y, b = blockIdx.z, t = threadIdx.x;
  __shared__ float sc[896];
  __shared__ float qs[32];
  __shared__ float red[256];
  const float* qp = qkv + ((size_t)(b * 896 + q) * 768) + h * 32;
  if (t < 32) qs[t] = qp[t];
  __syncthreads();
  float lmax = -1e30f;
  for (int kk = t; kk < 896; kk += 256) {
    const float* kp = qkv + ((size_t)(b * 896 + kk) * 768) + 256 + h * 32;
    float s = 0.0f;
    #pragma unroll
    for (int d = 0; d < 32; ++d) s += qs[d] * kp[d];
    s *= 0.17677669529663687f;
    sc[kk] = s; lmax = fmaxf(lmax, s);
  }
  red[t] = lmax; __syncthreads();
  for (int s = 128; s > 0; s >>= 1) { if (t < s) red[t] = fmaxf(red[t], red[t + s]); __syncthreads(); }
  const float m = red[0]; __syncthreads();
  float lsum = 0.0f;
  for (int kk = t; kk < 896; kk += 256) { float p = expf(sc[kk] - m); sc[kk] = p; lsum += p; }
  red[t] = lsum; __syncthreads();
  for (int s = 128; s > 0; s >>= 1) { if (t < s) red[t] += red[t + s]; __syncthreads(); }
  const float denom = red[0];
  __syncthreads();
  const int d = t & 31, g = t >> 5;
  float part = 0.0f;
  for (int kk = g * 112; kk < (g + 1) * 112; ++kk)
    part += sc[kk] * qkv[((size_t)(b * 896 + kk) * 768) + 512 + h * 32 + d];
  red[t] = part; __syncthreads();
  if (t < 32) {
    float o = 0.0f;
    #pragma unroll
    for (int gg = 0; gg < 8; ++gg) o += red[gg * 32 + t];
    out[((size_t)(b * 896 + q) * 256) + h * 32 + t] = o / denom;
  }
}

// ---------------------------------------------------------------- build inv table
__global__ __launch_bounds__(1024) void inv_k(const int* __restrict__ pc, int* __restrict__ inv)
{
  const int t = threadIdx.x;
  if (t < 1024) inv[t] = 0;
  __syncthreads();
  if (t < 640) {
    const int wide = (pc[3] == 0);
    int s = wide ? pc[4 * t] : pc[2 * t];
    int coord = wide ? pc[4 * t + 2] : pc[2 * t + 1];
    s &= 1;
    const int gs = 16 << s;
    const int k = 1 << (1 - s);
    const int r = (coord / gs) * k, c = (coord % gs) * k;
    for (int oi = 0; oi < k; ++oi)
      for (int oj = 0; oj < k; ++oj) {
        const int rr = r + oi, cc = c + oj;
        if (rr >= 0 && rr < 32 && cc >= 0 && cc < 32)
          inv[rr * 32 + cc] = t;
      }
  }
}

// ---------------------------------------------------------------- gather masks -> img0
template<typename T>
__global__ __launch_bounds__(256) void gather_k(
    const float* __restrict__ masks, const int* __restrict__ inv, T* __restrict__ img)
{
  const int idx = blockIdx.x * 256 + threadIdx.x;
  const int p = idx & 1023;
  const int rest = idx >> 10;
  const int d = rest & 255, b = rest >> 8;
  stf(&img[idx], masks[((size_t)b * 640 + inv[p]) * 256 + d]);
}

// ---------------------------------------------------------------- conv3x3 SAME, float4 weights, padded LDS
template<typename T>
__global__ __launch_bounds__(256) void conv3_k(
    const T* __restrict__ x, const float* __restrict__ w,
    const float* __restrict__ bias, T* __restrict__ y, int H, int W)
{
  const int tile = blockIdx.x;
  const int tw = W >> 4;
  const int ty0 = (tile / tw) << 4, tx0 = (tile % tw) << 4;
  const int co0 = blockIdx.y << 5;
  const int b = blockIdx.z;
  const int t = threadIdx.x;
  const int py = t >> 4, px = t & 15;
  const int oy = ty0 + py, ox = tx0 + px;
  __shared__ float xin[8][18][24];      // row stride 24 -> uniform 2-way (free) bank pattern
  __shared__ float ws_[8][9][32];       // read as float4, broadcast
  float acc[32];
  #pragma unroll
  for (int i = 0; i < 32; ++i) acc[i] = 0.0f;
  for (int c0 = 0; c0 < 256; c0 += 8) {
    for (int i = t; i < 8 * 324; i += 256) {
      const int ci = i / 324, r = i % 324, yy = r / 18, xx = r % 18;
      const int gy = ty0 + yy - 1, gx = tx0 + xx - 1;
      float v = 0.0f;
      if (gy >= 0 && gy < H && gx >= 0 && gx < W)
        v = tof(x[(((size_t)b * 256 + c0 + ci) * H + gy) * W + gx]);
      xin[ci][yy][xx] = v;
    }
    for (int i = t; i < 8 * 9 * 32; i += 256) {
      const int co = i & 31, r = i >> 5, ci = r / 9, kk = r % 9;
      ws_[ci][kk][co] = w[(((size_t)(co0 + co) * 256) + c0 + ci) * 9 + kk];
    }
    __syncthreads();
    #pragma unroll
    for (int ci = 0; ci < 8; ++ci) {
      float xv[9];
      #pragma unroll
      for (int kk = 0; kk < 9; ++kk) xv[kk] = xin[ci][py + kk / 3][px + kk % 3];
      #pragma unroll
      for (int kk = 0; kk < 9; ++kk) {
        const float4* wr = reinterpret_cast<const float4*>(&ws_[ci][kk][0]);
        #pragma unroll
        for (int c4 = 0; c4 < 8; ++c4) {
          const float4 wv = wr[c4];
          acc[c4 * 4 + 0] += xv[kk] * wv.x;
          acc[c4 * 4 + 1] += xv[kk] * wv.y;
          acc[c4 * 4 + 2] += xv[kk] * wv.z;
          acc[c4 * 4 + 3] += xv[kk] * wv.w;
        }
      }
    }
    __syncthreads();
  }
  #pragma unroll
  for (int co = 0; co < 32; ++co)
    stf(&y[(((size_t)b * 256 + co0 + co) * H + oy) * W + ox], acc[co] + bias[co0 + co]);
}

// ---------------------------------------------------------------- convT 2x2 stride 2
template<typename T>
__global__ __launch_bounds__(256) void convt_k(
    const T* __restrict__ x, const float* __restrict__ w,
    const float* __restrict__ bias, T* __restrict__ y, int H, int W)
{
  const int tile = blockIdx.x;
  const int tw = (2 * W) >> 4;
  const int oy0 = (tile / tw) << 4, ox0 = (tile % tw) << 4;
  const int co0 = blockIdx.y << 5;
  const int b = blockIdx.z;
  const int t = threadIdx.x;
  const int py = t >> 4, px = t & 15;
  const int oy = oy0 + py, ox = ox0 + px;
  const int ly = py >> 1, lx = px >> 1;
  const int ij = (oy & 1) * 2 + (ox & 1);
  const int iy0 = oy0 >> 1, ix0 = ox0 >> 1;
  __shared__ float xin[8][8][8];
  __shared__ float ws_[8][4][36];       // [ci][ij][co], ij stride 36 -> parity groups on distinct banks
  float acc[32];
  #pragma unroll
  for (int i = 0; i < 32; ++i) acc[i] = 0.0f;
  for (int c0 = 0; c0 < 256; c0 += 8) {
    for (int i = t; i < 8 * 64; i += 256) {
      const int ci = i >> 6, r = i & 63, yy = r >> 3, xx = r & 7;
      xin[ci][yy][xx] = tof(x[(((size_t)b * 256 + c0 + ci) * H + iy0 + yy) * W + ix0 + xx]);
    }
    for (int i = t; i < 8 * 32 * 4; i += 256) {
      const int ci = i >> 7, r = i & 127, co = r >> 2, jj = r & 3;
      ws_[ci][jj][co] = w[(((size_t)(c0 + ci) * 256) + co0 + co) * 4 + jj];
    }
    __syncthreads();
    #pragma unroll
    for (int ci = 0; ci < 8; ++ci) {
      const float v = xin[ci][ly][lx];
      const float4* wr = reinterpret_cast<const float4*>(&ws_[ci][ij][0]);
      #pragma unroll
      for (int c4 = 0; c4 < 8; ++c4) {
        const float4 wv = wr[c4];
        acc[c4 * 4 + 0] += v * wv.x;
        acc[c4 * 4 + 1] += v * wv.y;
        acc[c4 * 4 + 2] += v * wv.z;
        acc[c4 * 4 + 3] += v * wv.w;
      }
    }
    __syncthreads();
  }
  #pragma unroll
  for (int co = 0; co < 32; ++co)
    stf(&y[(((size_t)b * 256 + co0 + co) * (2 * H) + oy) * (2 * W) + ox], acc[co] + bias[co0 + co]);
}

// ---------------------------------------------------------------- instance norm + leaky
template<typename T>
__global__ __launch_bounds__(256) void inorm_k(T* __restrict__ x, int HW)
{
  const int bc = blockIdx.x, t = threadIdx.x;
  T* p = x + (size_t)bc * HW;
  float s = 0.0f, s2 = 0.0f;
  for (int i = t; i < HW; i += 256) { const float v = tof(p[i]); s += v; s2 += v * v; }
  __shared__ float r1[256], r2[256];
  r1[t] = s; r2[t] = s2; __syncthreads();
  for (int st = 128; st > 0; st >>= 1) {
    if (t < st) { r1[t] += r1[t + st]; r2[t] += r2[t + st]; }
    __syncthreads();
  }
  const float m = r1[0] / (float)HW;
  const float var = fmaxf(r2[0] / (float)HW - m * m, 0.0f);
  const float rstd = rsqrtf(var + 1e-5f);
  for (int i = t; i < HW; i += 256) {
    float v = (tof(p[i]) - m) * rstd;
    stf(&p[i], v >= 0.0f ? v : 0.01f * v);
  }
}

// ---------------------------------------------------------------- out conv 3x3: 256 -> 3
template<typename T>
__global__ __launch_bounds__(256) void convout_k(
    const T* __restrict__ x, const float* __restrict__ w,
    const float* __restrict__ bias, void* __restrict__ yv, const int* __restrict__ flags)
{
  const int H = 256, W = 256;
  const int tile = blockIdx.x;
  const int tw = W >> 4;
  const int ty0 = (tile / tw) << 4, tx0 = (tile % tw) << 4;
  const int b = blockIdx.y;
  const int t = threadIdx.x;
  const int py = t >> 4, px = t & 15;
  const int oy = ty0 + py, ox = tx0 + px;
  __shared__ float xin[8][18][24];
  __shared__ float ws_[8][9][3];
  float acc[3] = {0.0f, 0.0f, 0.0f};
  for (int c0 = 0; c0 < 256; c0 += 8) {
    for (int i = t; i < 8 * 324; i += 256) {
      const int ci = i / 324, r = i % 324, yy = r / 18, xx = r % 18;
      const int gy = ty0 + yy - 1, gx = tx0 + xx - 1;
      float v = 0.0f;
      if (gy >= 0 && gy < H && gx >= 0 && gx < W)
        v = tof(x[(((size_t)b * 256 + c0 + ci) * H + gy) * W + gx]);
      xin[ci][yy][xx] = v;
    }
    for (int i = t; i < 8 * 9 * 3; i += 256) {
      const int co = i % 3, r = i / 3, ci = r / 9, kk = r % 9;
      ws_[ci][kk][co] = w[(((size_t)co * 256) + c0 + ci) * 9 + kk];
    }
    __syncthreads();
    #pragma unroll
    for (int ci = 0; ci < 8; ++ci) {
      #pragma unroll
      for (int kk = 0; kk < 9; ++kk) {
        const float v = xin[ci][py + kk / 3][px + kk % 3];
        #pragma unroll
        for (int co = 0; co < 3; ++co) acc[co] += v * ws_[ci][kk][co];
      }
    }
    __syncthreads();
  }
  const int fp32 = flags[0];
  #pragma unroll
  for (int co = 0; co < 3; ++co) {
    const size_t oidx = (((size_t)b * 3 + co) * H + oy) * W + ox;
    const float v = acc[co] + bias[co];
    if (fp32) ((float*)yv)[oidx] = v;
    else      ((bf16*)yv)[oidx] = __float2bfloat16(v);
  }
}

// ---------------------------------------------------------------- conv pipeline
template<typename T>
static void launch_convs(const float* masksb, const int* invbuf,
                         const float* ucw, const float* ucb,
                         const float* utw, const float* utb,
                         const float* ocw, const float* ocb,
                         T* R0, T* R1, T* R2, void* out, const int* flags, hipStream_t stream)
{
  gather_k<T><<<2048, 256, 0, stream>>>(masksb, invbuf, R0);
  int H = 32;
  for (int i = 0; i < 3; ++i) {
    conv3_k<T><<<dim3((H / 16) * (H / 16), 8, 2), 256, 0, stream>>>(
        R0, ucw + (size_t)i * 589824, ucb + i * 256, R1, H, H);
    inorm_k<T><<<512, 256, 0, stream>>>(R1, H * H);
    T* dst = (i == 2) ? R2 : R0;
    convt_k<T><<<dim3((2 * H / 16) * (2 * H / 16), 8, 2), 256, 0, stream>>>(
        R1, utw + (size_t)i * 262144, utb + i * 256, dst, H, H);
    inorm_k<T><<<512, 256, 0, stream>>>(dst, 4 * H * H);
    H *= 2;
  }
  convout_k<T><<<dim3(256, 2), 256, 0, stream>>>(R2, ocw, ocb, out, flags);
}

// ================================================================ host
extern "C" void kernel_launch(void* const* d_in, const int* in_sizes, int n_in,
                              void* d_out, int out_size, void* d_ws, size_t ws_size,
                              hipStream_t stream) {
  (void)in_sizes; (void)n_in; (void)out_size;
  const int* pc = (const int*)d_in[1];

  float* P = (float*)d_ws;
  size_t off = 0;
  CvtDesc cd{};
  int seg = 0;
  auto alloc = [&](size_t n) { float* p = P + off; off += n; return p; };
  auto allocCv = [&](int idx, size_t n, size_t ncv) {
    float* p = P + off;
    cd.src[seg] = d_in[idx]; cd.dstOff[seg] = (unsigned)off; cd.n[seg] = (unsigned)ncv;
    ++seg; off += n; return p;
  };
  float* px    = allocCv(0, 655360, 655360);
  float* pdw   = allocCv(2, 131072, 131072);
  float* pdb   = allocCv(3, 256, 256);
  float* pw1   = allocCv(4, 512, 512);
  float* pb1   = allocCv(5, 256, 256);
  float* pw2   = allocCv(6, 65536, 65536);
  float* pb2   = allocCv(7, 256, 256);
  float* pcls  = allocCv(8, 65536, 65536);
  float* pln1g = allocCv(9, 512, 512);
  float* pln1b = allocCv(10, 512, 512);
  float* pqkvw = allocCv(11, 393216, 393216);
  float* pqkvb = allocCv(12, 1536, 1536);
  float* pattw = allocCv(13, 131072, 131072);
  float* pattb = allocCv(14, 512, 512);
  float* pln2g = allocCv(15, 512, 512);
  float* pln2b = allocCv(16, 512, 512);
  float* pm1w  = allocCv(17, 524288, 524288);
  float* pm1b  = allocCv(18, 2048, 2048);
  float* pm2w  = allocCv(19, 524288, 524288);
  float* pm2b  = allocCv(20, 512, 512);
  float* pdecg = allocCv(21, 256, 256);
  float* pdecb = allocCv(22, 256, 256);
  float* pprp  = allocCv(23, 65536, 65536);
  float* pprc  = allocCv(24, 65536, 65536);
  float* pmg   = allocCv(25, 256, 256);
  float* pmb   = allocCv(26, 256, 256);
  float* pucw  = allocCv(27, 1769472, 1769472);
  float* pucb  = allocCv(28, 768, 768);
  float* putw  = allocCv(29, 786432, 786432);
  float* putb  = allocCv(30, 768, 768);
  float* pocw  = allocCv(31, 6912, 6912);
  float* pocb  = allocCv(32, 16, 3);
  int*   flags = (int*)(P + off); off += 16;
  off = (off + 255) & ~(size_t)255;

  char* actbase = (char*)(P + off);
  const size_t actoff = off * 4;
  const bool planA = (ws_size >= actoff + 201326592ull);
  const size_t eb = planA ? 4 : 2;
  void* R0v = actbase;
  void* R1v = actbase + (size_t)8388608 * eb;
  char* R2v = actbase + (size_t)16777216 * eb;

  // transformer fp32 scratch overlaid at start of R2 region
  float* xbuf   = (float*)R2v;
  float* hbuf   = xbuf + 458752;
  float* qkvbuf = hbuf + 458752;
  float* hidbuf = qkvbuf + 1376256;
  float* posbuf = hidbuf + 1835008;
  float* patbuf = posbuf + 163840;
  float* clsbuf = patbuf + 327680;
  float* masksb = clsbuf + 131072;
  int*   invbuf = (int*)(masksb + 327680);

  // 0) dtype detect + one batched convert
  detect_k<<<1, 64, 0, stream>>>((const unsigned short*)d_in[0], flags);
  cvtall_k<<<dim3(256, NSEG), 256, 0, stream>>>(cd, P, flags);

  // 1) positional MLP + patch projection + sequence assembly
  pos_k<<<640, 256, 0, stream>>>(pc, pw1, pb1, pw2, pb2, posbuf);
  gemm_k<false, 0><<<dim3(4, 20), 256, 0, stream>>>(
      px, pdw, pdb, nullptr, hidbuf, 1280, 256, 512);
  assemble_k<<<1792, 256, 0, stream>>>(hidbuf, posbuf, pcls, xbuf);

  // 2) transformer blocks
  for (int l = 0; l < 2; ++l) {
    ln_k<<<1792, 256, 0, stream>>>(xbuf, hbuf, pln1g + l * 256, pln1b + l * 256);
    gemm_k<false, 0><<<dim3(12, 28), 256, 0, stream>>>(
        hbuf, pqkvw + (size_t)l * 196608, pqkvb + l * 768, nullptr, qkvbuf, 1792, 768, 256);
    attn_k<<<dim3(896, 8, 2), 256, 0, stream>>>(qkvbuf, hbuf);
    gemm_k<false, 0><<<dim3(4, 28), 256, 0, stream>>>(
        hbuf, pattw + (size_t)l * 65536, pattb + l * 256, xbuf, xbuf, 1792, 256, 256);
    ln_k<<<1792, 256, 0, stream>>>(xbuf, hbuf, pln2g + l * 256, pln2b + l * 256);
    gemm_k<false, 1><<<dim3(16, 28), 256, 0, stream>>>(
        hbuf, pm1w + (size_t)l * 262144, pm1b + l * 1024, nullptr, hidbuf, 1792, 1024, 256);
    gemm_k<false, 0><<<dim3(4, 28), 256, 0, stream>>>(
        hidbuf, pm2w + (size_t)l * 262144, pm2b + l * 256, xbuf, xbuf, 1792, 256, 1024);
  }

  // 3) decoder head
  ln_k<<<1792, 256, 0, stream>>>(xbuf, hbuf, pdecg, pdecb);
  for (int b = 0; b < 2; ++b) {
    gemm_k<false, 0><<<dim3(4, 10), 256, 0, stream>>>(
        hbuf + (size_t)b * 896 * 256, pprp, nullptr, nullptr,
        patbuf + (size_t)b * 640 * 256, 640, 256, 256);
    gemm_k<false, 0><<<dim3(4, 4), 256, 0, stream>>>(
        hbuf + ((size_t)b * 896 + 640) * 256, pprc, nullptr, nullptr,
        clsbuf + (size_t)b * 65536, 256, 256, 256);
  }
  l2n_k<<<1280, 256, 0, stream>>>(patbuf);
  l2n_k<<<512, 256, 0, stream>>>(clsbuf);
  for (int b = 0; b < 2; ++b) {
    gemm_k<true, 0><<<dim3(4, 10), 256, 0, stream>>>(
        patbuf + (size_t)b * 163840, clsbuf + (size_t)b * 65536, nullptr, nullptr,
        masksb + (size_t)b * 163840, 640, 256, 256);
  }
  ln_k<<<1280, 256, 0, stream>>>(masksb, masksb, pmg, pmb);

  // 4) scatter table
  inv_k<<<1, 1024, 0, stream>>>(pc, invbuf);

  // 5) conv decoder + output head
  if (planA) {
    launch_convs<float>(masksb, invbuf, pucw, pucb, putw, putb, pocw, pocb,
                        (float*)R0v, (float*)R1v, (float*)R2v, d_out, flags, stream);
  } else {
    launch_convs<f16>(masksb, invbuf, pucw, pucb, putw, putb, pocw, pocb,
                      (f16*)R0v, (f16*)R1v, (f16*)R2v, d_out, flags, stream);
  }
}

// Round 5
// 1881.722 us; speedup vs baseline: 2.0642x; 1.9145x over previous
//
#include <hip/hip_runtime.h>
#include <hip/hip_bf16.h>

typedef __hip_bfloat16 bf16;
typedef _Float16 f16;
typedef __attribute__((ext_vector_type(8))) _Float16 f16x8;
typedef __attribute__((ext_vector_type(4))) float f32x4;

// ---------------------------------------------------------------- dtype detector
__global__ void detect_k(const unsigned short* __restrict__ xh, int* __restrict__ flags)
{
  if (threadIdx.x == 0 && blockIdx.x == 0) {
    int weird = 0;
    for (int i = 0; i < 512; ++i) {
      const int e = (xh[i] >> 7) & 0xFF;
      if (e == 0xFF || e >= 0x88) ++weird;
    }
    flags[0] = (weird > 32) ? 1 : 0;
  }
}

// ---------------------------------------------------------------- batched input->fp32 convert
#define NSEG 33
struct CvtDesc {
  const void* src[NSEG];
  unsigned dstOff[NSEG];
  unsigned n[NSEG];
};
__global__ __launch_bounds__(256) void cvtall_k(
    CvtDesc d, float* __restrict__ P, const int* __restrict__ flags)
{
  const int s = blockIdx.y;
  const unsigned n = d.n[s];
  const int fp32 = flags[0];
  float* dst = P + d.dstOff[s];
  const unsigned stride = gridDim.x * 256u;
  if (fp32) {
    const float* src = (const float*)d.src[s];
    for (unsigned i = blockIdx.x * 256u + threadIdx.x; i < n; i += stride) dst[i] = src[i];
  } else {
    const bf16* src = (const bf16*)d.src[s];
    for (unsigned i = blockIdx.x * 256u + threadIdx.x; i < n; i += stride)
      dst[i] = __bfloat162float(src[i]);
  }
}

// ---------------------------------------------------------------- conv weight prep -> f16
// wf3: [stage][9][co][ci] from ucw OIHW ; wt: [stage][4(ij)][co][ci] from utw (ci,co,i,j)
__global__ __launch_bounds__(256) void prepw_k(
    const float* __restrict__ ucw, const float* __restrict__ utw,
    f16* __restrict__ wf3, f16* __restrict__ wt)
{
  const int n1 = 3 * 9 * 65536;
  const int n2 = 3 * 4 * 65536;
  for (int i = blockIdx.x * 256 + threadIdx.x; i < n1 + n2; i += gridDim.x * 256) {
    if (i < n1) {
      const int st = i / 589824, r = i % 589824;
      const int kk = r / 65536, rr = r % 65536;
      const int co = rr >> 8, ci = rr & 255;
      wf3[i] = (f16)ucw[(((size_t)st * 256 + co) * 256 + ci) * 9 + kk];
    } else {
      const int j = i - n1;
      const int st = j / 262144, r = j % 262144;
      const int ij = r / 65536, rr = r % 65536;
      const int co = rr >> 8, ci = rr & 255;
      wt[j] = (f16)utw[(((size_t)st * 256 + ci) * 256 + co) * 4 + ij];
    }
  }
}

// ---------------------------------------------------------------- GEMM (fp32, transformer)
template<bool TRB, int ACT>
__global__ __launch_bounds__(256) void gemm_k(
    const float* __restrict__ A, const float* __restrict__ B,
    const float* __restrict__ bias, const float* __restrict__ res,
    float* __restrict__ C, int M, int N, int K)
{
  __shared__ float As[16][64];
  __shared__ float Bs[16][64];
  const int tid = threadIdx.x;
  const int m0 = blockIdx.y * 64, n0 = blockIdx.x * 64;
  const int tx = tid & 15, ty = tid >> 4;
  float acc[4][4] = {};
  for (int k0 = 0; k0 < K; k0 += 16) {
    {
      const int m = tid >> 2, kq = tid & 3;
      const float* ap = A + (size_t)(m0 + m) * K + k0 + kq * 4;
      #pragma unroll
      for (int i = 0; i < 4; ++i) As[kq * 4 + i][m] = ap[i];
    }
    if (!TRB) {
      const int n = tid & 63, kb = tid >> 6;
      #pragma unroll
      for (int i = 0; i < 4; ++i)
        Bs[kb + i * 4][n] = B[(size_t)(k0 + kb + i * 4) * N + n0 + n];
    } else {
      const int n = tid >> 2, kq = tid & 3;
      const float* bp = B + (size_t)(n0 + n) * K + k0 + kq * 4;
      #pragma unroll
      for (int i = 0; i < 4; ++i) Bs[kq * 4 + i][n] = bp[i];
    }
    __syncthreads();
    #pragma unroll
    for (int kk = 0; kk < 16; ++kk) {
      float av[4], bv[4];
      #pragma unroll
      for (int i = 0; i < 4; ++i) av[i] = As[kk][ty * 4 + i];
      #pragma unroll
      for (int j = 0; j < 4; ++j) bv[j] = Bs[kk][tx * 4 + j];
      #pragma unroll
      for (int i = 0; i < 4; ++i)
        #pragma unroll
        for (int j = 0; j < 4; ++j) acc[i][j] += av[i] * bv[j];
    }
    __syncthreads();
  }
  #pragma unroll
  for (int i = 0; i < 4; ++i) {
    const int row = m0 + ty * 4 + i;
    #pragma unroll
    for (int j = 0; j < 4; ++j) {
      const int col = n0 + tx * 4 + j;
      float v = acc[i][j];
      if (bias) v += bias[col];
      if (ACT == 1) v = 0.5f * v * (1.0f + erff(v * 0.70710678118654752f));
      if (res) v += res[(size_t)row * N + col];
      C[(size_t)row * N + col] = v;
    }
  }
}

// ---------------------------------------------------------------- LayerNorm (row len 256)
__global__ __launch_bounds__(256) void ln_k(
    const float* __restrict__ in, float* __restrict__ out,
    const float* __restrict__ g, const float* __restrict__ b)
{
  const int row = blockIdx.x, t = threadIdx.x;
  __shared__ float red[256];
  float x = in[(size_t)row * 256 + t];
  red[t] = x; __syncthreads();
  for (int s = 128; s > 0; s >>= 1) { if (t < s) red[t] += red[t + s]; __syncthreads(); }
  const float m = red[0] * (1.0f / 256.0f);
  __syncthreads();
  const float d = x - m;
  red[t] = d * d; __syncthreads();
  for (int s = 128; s > 0; s >>= 1) { if (t < s) red[t] += red[t + s]; __syncthreads(); }
  const float rstd = rsqrtf(red[0] * (1.0f / 256.0f) + 1e-5f);
  out[(size_t)row * 256 + t] = d * rstd * g[t] + b[t];
}

// ---------------------------------------------------------------- L2 normalize rows
__global__ __launch_bounds__(256) void l2n_k(float* __restrict__ x)
{
  const int row = blockIdx.x, t = threadIdx.x;
  __shared__ float red[256];
  float v = x[(size_t)row * 256 + t];
  red[t] = v * v; __syncthreads();
  for (int s = 128; s > 0; s >>= 1) { if (t < s) red[t] += red[t + s]; __syncthreads(); }
  x[(size_t)row * 256 + t] = v * rsqrtf(red[0]);
}

// ---------------------------------------------------------------- pos MLP
__global__ __launch_bounds__(256) void pos_k(
    const int* __restrict__ pc, const float* __restrict__ w1, const float* __restrict__ b1,
    const float* __restrict__ w2, const float* __restrict__ b2, float* __restrict__ pos)
{
  const int n = blockIdx.x, t = threadIdx.x;
  __shared__ float h[256];
  const int wide = (pc[3] == 0);
  const int sv = wide ? pc[4 * n] : pc[2 * n];
  const int cv = wide ? pc[4 * n + 2] : pc[2 * n + 1];
  float hv = (float)sv * w1[t] + (float)cv * w1[256 + t] + b1[t];
  h[t] = hv > 0.0f ? hv : 0.0f;
  __syncthreads();
  float acc = b2[t];
  for (int k = 0; k < 256; ++k) acc += h[k] * w2[k * 256 + t];
  pos[n * 256 + t] = acc;
}

// ---------------------------------------------------------------- assemble x = [proj+pos ; cls]
__global__ __launch_bounds__(256) void assemble_k(
    const float* __restrict__ proj, const float* __restrict__ pos,
    const float* __restrict__ cls, float* __restrict__ xb)
{
  const int row = blockIdx.x;
  const int b = row / 896, n = row % 896, t = threadIdx.x;
  float v;
  if (n < 640) v = proj[((size_t)b * 640 + n) * 256 + t] + pos[n * 256 + t];
  else         v = cls[(n - 640) * 256 + t];
  xb[(size_t)row * 256 + t] = v;
}

// ---------------------------------------------------------------- attention
__global__ __launch_bounds__(256) void attn_k(
    const float* __restrict__ qkv, float* __restrict__ out)
{
  const int q = blockIdx.x, h = blockIdx.y, b = blockIdx.z, t = threadIdx.x;
  __shared__ float sc[896];
  __shared__ float qs[32];
  __shared__ float red[256];
  const float* qp = qkv + ((size_t)(b * 896 + q) * 768) + h * 32;
  if (t < 32) qs[t] = qp[t];
  __syncthreads();
  float lmax = -1e30f;
  for (int kk = t; kk < 896; kk += 256) {
    const float* kp = qkv + ((size_t)(b * 896 + kk) * 768) + 256 + h * 32;
    float s = 0.0f;
    #pragma unroll
    for (int d = 0; d < 32; ++d) s += qs[d] * kp[d];
    s *= 0.17677669529663687f;
    sc[kk] = s; lmax = fmaxf(lmax, s);
  }
  red[t] = lmax; __syncthreads();
  for (int s = 128; s > 0; s >>= 1) { if (t < s) red[t] = fmaxf(red[t], red[t + s]); __syncthreads(); }
  const float m = red[0]; __syncthreads();
  float lsum = 0.0f;
  for (int kk = t; kk < 896; kk += 256) { float p = expf(sc[kk] - m); sc[kk] = p; lsum += p; }
  red[t] = lsum; __syncthreads();
  for (int s = 128; s > 0; s >>= 1) { if (t < s) red[t] += red[t + s]; __syncthreads(); }
  const float denom = red[0];
  __syncthreads();
  const int d = t & 31, g = t >> 5;
  float part = 0.0f;
  for (int kk = g * 112; kk < (g + 1) * 112; ++kk)
    part += sc[kk] * qkv[((size_t)(b * 896 + kk) * 768) + 512 + h * 32 + d];
  red[t] = part; __syncthreads();
  if (t < 32) {
    float o = 0.0f;
    #pragma unroll
    for (int gg = 0; gg < 8; ++gg) o += red[gg * 32 + t];
    out[((size_t)(b * 896 + q) * 256) + h * 32 + t] = o / denom;
  }
}

// ---------------------------------------------------------------- build inv table
__global__ __launch_bounds__(1024) void inv_k(const int* __restrict__ pc, int* __restrict__ inv)
{
  const int t = threadIdx.x;
  if (t < 1024) inv[t] = 0;
  __syncthreads();
  if (t < 640) {
    const int wide = (pc[3] == 0);
    int s = wide ? pc[4 * t] : pc[2 * t];
    int coord = wide ? pc[4 * t + 2] : pc[2 * t + 1];
    s &= 1;
    const int gs = 16 << s;
    const int k = 1 << (1 - s);
    const int r = (coord / gs) * k, c = (coord % gs) * k;
    for (int oi = 0; oi < k; ++oi)
      for (int oj = 0; oj < k; ++oj) {
        const int rr = r + oi, cc = c + oj;
        if (rr >= 0 && rr < 32 && cc >= 0 && cc < 32)
          inv[rr * 32 + cc] = t;
      }
  }
}

// ---------------------------------------------------------------- gather masks -> NHWC f16 img
__global__ __launch_bounds__(256) void gather16_k(
    const float* __restrict__ masks, const int* __restrict__ inv, f16* __restrict__ img)
{
  const int p = blockIdx.x & 1023, b = blockIdx.x >> 10, t = threadIdx.x;
  img[((size_t)blockIdx.x << 8) + t] = (f16)masks[((size_t)b * 640 + inv[p]) * 256 + t];
}

// ---------------------------------------------------------------- MFMA conv3x3 (NHWC f16)
// block: 16x16 spatial patch x 64 co; 4 waves, wave tile 64(pos)x64(co), 4x4 frags 16x16x32
__global__ __launch_bounds__(256) void conv3m_k(
    const f16* __restrict__ x, const f16* __restrict__ wf, const float* __restrict__ bias,
    f16* __restrict__ y, int H, int W)
{
  const int tilesx = W >> 4;
  const int ty0 = (blockIdx.x / tilesx) << 4, tx0 = (blockIdx.x % tilesx) << 4;
  const int co0 = blockIdx.y << 6;
  const int b = blockIdx.z;
  const int t = threadIdx.x;
  const int lane = t & 63, wv = t >> 6;
  const int frow = lane & 15, kg = lane >> 4;
  __shared__ f16 halo[18][18][40];
  __shared__ f16 bt3[3][64][40];
  f32x4 acc[4][4];
  #pragma unroll
  for (int i = 0; i < 4; ++i)
    #pragma unroll
    for (int j = 0; j < 4; ++j) acc[i][j] = (f32x4){0.f, 0.f, 0.f, 0.f};

  for (int c0 = 0; c0 < 256; c0 += 32) {
    __syncthreads();
    for (int i = t; i < 1296; i += 256) {           // 18*18 cells x 4 parts of 8ch
      const int cell = i >> 2, part = i & 3;
      const int hy = cell / 18, hx = cell - hy * 18;
      const int gy = ty0 + hy - 1, gx = tx0 + hx - 1;
      f16x8 v = {(f16)0,(f16)0,(f16)0,(f16)0,(f16)0,(f16)0,(f16)0,(f16)0};
      if (gy >= 0 && gy < H && gx >= 0 && gx < W)
        v = *(const f16x8*)&x[(((size_t)b * H + gy) * W + gx) * 256 + c0 + part * 8];
      *(f16x8*)&halo[hy][hx][part * 8] = v;
    }
    for (int kyr = 0; kyr < 3; ++kyr) {
      __syncthreads();
      for (int i = t; i < 768; i += 256) {          // 3 taps x 64 co x 4 parts
        const int tr = i >> 8, rem = i & 255, co = rem >> 2, part = rem & 3;
        *(f16x8*)&bt3[tr][co][part * 8] =
            *(const f16x8*)&wf[(((size_t)(kyr * 3 + tr)) * 256 + co0 + co) * 256 + c0 + part * 8];
      }
      __syncthreads();
      #pragma unroll
      for (int kx = 0; kx < 3; ++kx) {
        f16x8 af[4], bf[4];
        #pragma unroll
        for (int fm = 0; fm < 4; ++fm) {
          const int pos = wv * 64 + fm * 16 + frow;
          af[fm] = *(const f16x8*)&halo[(pos >> 4) + kyr][(pos & 15) + kx][kg * 8];
        }
        #pragma unroll
        for (int fn = 0; fn < 4; ++fn)
          bf[fn] = *(const f16x8*)&bt3[kx][fn * 16 + frow][kg * 8];
        #pragma unroll
        for (int fm = 0; fm < 4; ++fm)
          #pragma unroll
          for (int fn = 0; fn < 4; ++fn)
            acc[fm][fn] = __builtin_amdgcn_mfma_f32_16x16x32_f16(af[fm], bf[fn], acc[fm][fn], 0, 0, 0);
      }
    }
  }
  #pragma unroll
  for (int fn = 0; fn < 4; ++fn) {
    const int col = co0 + fn * 16 + frow;
    const float bv = bias[col];
    #pragma unroll
    for (int fm = 0; fm < 4; ++fm)
      #pragma unroll
      for (int r = 0; r < 4; ++r) {
        const int pos = wv * 64 + fm * 16 + kg * 4 + r;
        y[(((size_t)b * H + ty0 + (pos >> 4)) * W + tx0 + (pos & 15)) * 256 + col] =
            (f16)(acc[fm][fn][r] + bv);
      }
  }
}

// ---------------------------------------------------------------- MFMA convT 2x2 s2 (one parity/block)
__global__ __launch_bounds__(256) void convtm_k(
    const f16* __restrict__ x, const f16* __restrict__ wtp, const float* __restrict__ bias,
    f16* __restrict__ y, int H, int W)
{
  const int tilesx = W >> 4;
  const int ty0 = (blockIdx.x / tilesx) << 4, tx0 = (blockIdx.x % tilesx) << 4;
  const int co0 = (blockIdx.y >> 2) << 6;
  const int par = blockIdx.y & 3;
  const int pa = par >> 1, pb = par & 1;
  const int b = blockIdx.z;
  const int t = threadIdx.x;
  const int lane = t & 63, wv = t >> 6;
  const int frow = lane & 15, kg = lane >> 4;
  __shared__ f16 at[256][40];
  __shared__ f16 btw[64][40];
  f32x4 acc[4][4];
  #pragma unroll
  for (int i = 0; i < 4; ++i)
    #pragma unroll
    for (int j = 0; j < 4; ++j) acc[i][j] = (f32x4){0.f, 0.f, 0.f, 0.f};

  for (int c0 = 0; c0 < 256; c0 += 32) {
    __syncthreads();
    for (int i = t; i < 1024; i += 256) {
      const int cell = i >> 2, part = i & 3;
      const int gy = ty0 + (cell >> 4), gx = tx0 + (cell & 15);
      *(f16x8*)&at[cell][part * 8] =
          *(const f16x8*)&x[(((size_t)b * H + gy) * W + gx) * 256 + c0 + part * 8];
    }
    {
      const int i = t;                               // 64 co x 4 parts = 256
      const int co = i >> 2, part = i & 3;
      *(f16x8*)&btw[co][part * 8] =
          *(const f16x8*)&wtp[((size_t)par * 256 + co0 + co) * 256 + c0 + part * 8];
    }
    __syncthreads();
    f16x8 af[4], bf[4];
    #pragma unroll
    for (int fm = 0; fm < 4; ++fm)
      af[fm] = *(const f16x8*)&at[wv * 64 + fm * 16 + frow][kg * 8];
    #pragma unroll
    for (int fn = 0; fn < 4; ++fn)
      bf[fn] = *(const f16x8*)&btw[fn * 16 + frow][kg * 8];
    #pragma unroll
    for (int fm = 0; fm < 4; ++fm)
      #pragma unroll
      for (int fn = 0; fn < 4; ++fn)
        acc[fm][fn] = __builtin_amdgcn_mfma_f32_16x16x32_f16(af[fm], bf[fn], acc[fm][fn], 0, 0, 0);
  }
  const int HO = H << 1, WO = W << 1;
  #pragma unroll
  for (int fn = 0; fn < 4; ++fn) {
    const int col = co0 + fn * 16 + frow;
    const float bv = bias[col];
    #pragma unroll
    for (int fm = 0; fm < 4; ++fm)
      #pragma unroll
      for (int r = 0; r < 4; ++r) {
        const int pos = wv * 64 + fm * 16 + kg * 4 + r;
        const int oy = ((ty0 + (pos >> 4)) << 1) + pa;
        const int ox = ((tx0 + (pos & 15)) << 1) + pb;
        y[(((size_t)b * HO + oy) * WO + ox) * 256 + col] = (f16)(acc[fm][fn][r] + bv);
      }
  }
}

// ---------------------------------------------------------------- instance-norm stats + normalize
__global__ __launch_bounds__(256) void stats1_k(
    const f16* __restrict__ x, float2* __restrict__ partial, int HW, int NS)
{
  const int s = blockIdx.x, b = blockIdx.y, t = threadIdx.x;
  const int rpb = HW / NS;
  const f16* p = x + ((size_t)b * HW + (size_t)s * rpb) * 256;
  float s1 = 0.f, s2 = 0.f;
  for (int r = 0; r < rpb; ++r) {
    const float v = (float)p[(size_t)r * 256 + t];
    s1 += v; s2 += v * v;
  }
  partial[((size_t)b * NS + s) * 256 + t] = make_float2(s1, s2);
}
__global__ __launch_bounds__(256) void stats2_k(
    const float2* __restrict__ partial, float2* __restrict__ mr, int HW, int NS)
{
  const int b = blockIdx.x, t = threadIdx.x;
  float s1 = 0.f, s2 = 0.f;
  for (int s = 0; s < NS; ++s) {
    const float2 v = partial[((size_t)b * NS + s) * 256 + t];
    s1 += v.x; s2 += v.y;
  }
  const float m = s1 / (float)HW;
  const float var = fmaxf(s2 / (float)HW - m * m, 0.f);
  mr[b * 256 + t] = make_float2(m, rsqrtf(var + 1e-5f));
}
__global__ __launch_bounds__(256) void norm_k(
    f16* __restrict__ x, const float2* __restrict__ mr, int HW)
{
  const int b = blockIdx.y, t = threadIdx.x;
  const float2 v = mr[b * 256 + t];
  f16* p = x + ((size_t)b * HW + (size_t)blockIdx.x * 8) * 256;
  #pragma unroll
  for (int r = 0; r < 8; ++r) {
    float z = ((float)p[(size_t)r * 256 + t] - v.x) * v.y;
    p[(size_t)r * 256 + t] = (f16)(z >= 0.f ? z : 0.01f * z);
  }
}

// ---------------------------------------------------------------- out conv 3x3: 256 -> 3 (NHWC f16 in)
__global__ __launch_bounds__(256) void convoutm_k(
    const f16* __restrict__ x, const float* __restrict__ w,
    const float* __restrict__ bias, void* __restrict__ yv, const int* __restrict__ flags)
{
  const int ty0 = (blockIdx.x >> 4) << 4, tx0 = (blockIdx.x & 15) << 4;
  const int b = blockIdx.y, t = threadIdx.x;
  const int py = t >> 4, px = t & 15;
  __shared__ float xin[18][18][9];
  __shared__ float wsm[8][9][3];
  float acc[3] = {0.f, 0.f, 0.f};
  for (int c0 = 0; c0 < 256; c0 += 8) {
    __syncthreads();
    for (int i = t; i < 2592; i += 256) {
      const int cell = i >> 3, ci = i & 7;
      const int hy = cell / 18, hx = cell - hy * 18;
      const int gy = ty0 + hy - 1, gx = tx0 + hx - 1;
      float v = 0.f;
      if (gy >= 0 && gy < 256 && gx >= 0 && gx < 256)
        v = (float)x[(((size_t)b * 256 + gy) * 256 + gx) * 256 + c0 + ci];
      xin[hy][hx][ci] = v;
    }
    for (int i = t; i < 216; i += 256) {
      const int co = i % 3, r = i / 3, ci = r / 9, kk = r % 9;
      wsm[ci][kk][co] = w[(((size_t)co * 256) + c0 + ci) * 9 + kk];
    }
    __syncthreads();
    #pragma unroll
    for (int ci = 0; ci < 8; ++ci)
      #pragma unroll
      for (int kk = 0; kk < 9; ++kk) {
        const float v = xin[py + kk / 3][px + kk % 3][ci];
        acc[0] += v * wsm[ci][kk][0];
        acc[1] += v * wsm[ci][kk][1];
        acc[2] += v * wsm[ci][kk][2];
      }
  }
  const int fp32 = flags[0];
  #pragma unroll
  for (int co = 0; co < 3; ++co) {
    const size_t oidx = (((size_t)b * 3 + co) * 256 + ty0 + py) * 256 + tx0 + px;
    const float v = acc[co] + bias[co];
    if (fp32) ((float*)yv)[oidx] = v;
    else      ((bf16*)yv)[oidx] = __float2bfloat16(v);
  }
}

// ================================================================ host
extern "C" void kernel_launch(void* const* d_in, const int* in_sizes, int n_in,
                              void* d_out, int out_size, void* d_ws, size_t ws_size,
                              hipStream_t stream) {
  (void)in_sizes; (void)n_in; (void)out_size; (void)ws_size;
  const int* pc = (const int*)d_in[1];

  float* P = (float*)d_ws;
  size_t off = 0;
  CvtDesc cd{};
  int seg = 0;
  auto alloc = [&](size_t n) { float* p = P + off; off += n; return p; };
  auto allocCv = [&](int idx, size_t n) {
    float* p = P + off;
    cd.src[seg] = d_in[idx]; cd.dstOff[seg] = (unsigned)off; cd.n[seg] = (unsigned)n;
    ++seg; off += n; return p;
  };

  // ---- persistent small region ----
  int*    flags   = (int*)alloc(16);
  int*    invbuf  = (int*)alloc(1024);
  float2* partial = (float2*)alloc(131072);        // 2 x 128 x 256 float2
  float2* mr1     = (float2*)alloc(1024);
  float* pdb   = allocCv(3, 256);
  float* pw1   = allocCv(4, 512);
  float* pb1   = allocCv(5, 256);
  float* pb2   = allocCv(7, 256);
  float* pln1g = allocCv(9, 512);
  float* pln1b = allocCv(10, 512);
  float* pqkvb = allocCv(12, 1536);
  float* pattb = allocCv(14, 512);
  float* pln2g = allocCv(15, 512);
  float* pln2b = allocCv(16, 512);
  float* pm1b  = allocCv(18, 2048);
  float* pm2b  = allocCv(20, 512);
  float* pdecg = allocCv(21, 256);
  float* pdecb = allocCv(22, 256);
  float* pmg   = allocCv(25, 256);
  float* pmb   = allocCv(26, 256);
  float* pucb  = allocCv(28, 768);
  float* putb  = allocCv(30, 768);
  float* pocw  = allocCv(31, 6912);
  float* pocb  = allocCv(32, 16);
  off = (off + 255) & ~(size_t)255;
  f16* wf3 = (f16*)alloc(884736);                  // 3*9*65536 f16
  f16* wt  = (f16*)alloc(393216);                  // 3*4*65536 f16
  off = (off + 255) & ~(size_t)255;

  // ---- zone A: big fp32 params + transformer scratch, later overlaid by R2 (f16) ----
  float* zoneA = P + off;
  f16*   R2h   = (f16*)zoneA;                      // 2*256*256*256 f16 = 16,777,216 floats
  {
    size_t zo = off;
    auto zCv = [&](int idx, size_t n) {
      float* p = P + zo;
      cd.src[seg] = d_in[idx]; cd.dstOff[seg] = (unsigned)zo; cd.n[seg] = (unsigned)n;
      ++seg; zo += n; return p;
    };
    float* px    = zCv(0, 655360);
    float* pdw   = zCv(2, 131072);
    float* pw2   = zCv(6, 65536);
    float* pcls  = zCv(8, 65536);
    float* pqkvw = zCv(11, 393216);
    float* pattw = zCv(13, 131072);
    float* pm1w  = zCv(17, 524288);
    float* pm2w  = zCv(19, 524288);
    float* pprp  = zCv(23, 65536);
    float* pprc  = zCv(24, 65536);
    float* pucw  = zCv(27, 1769472);
    float* putw  = zCv(29, 786432);
    float* xbuf   = P + zo; zo += 458752;
    float* hbuf   = P + zo; zo += 458752;
    float* qkvbuf = P + zo; zo += 1376256;
    float* hidbuf = P + zo; zo += 1835008;
    float* posbuf = P + zo; zo += 163840;
    float* patbuf = P + zo; zo += 327680;
    float* clsbuf = P + zo; zo += 131072;
    float* masksb = P + zo; zo += 327680;
    off += 16777216;                               // zone A extent = R2 size
    f16* R0h = (f16*)(P + off); off += 4194304;    // 2*128*128*256 f16
    f16* R1h = (f16*)(P + off); off += 4194304;

    // 0) detect dtype, convert all float inputs to fp32, prep f16 conv weights
    detect_k<<<1, 64, 0, stream>>>((const unsigned short*)d_in[0], flags);
    cvtall_k<<<dim3(256, NSEG), 256, 0, stream>>>(cd, P, flags);
    prepw_k<<<2048, 256, 0, stream>>>(pucw, putw, wf3, wt);

    // 1) positional MLP + patch projection + sequence assembly
    pos_k<<<640, 256, 0, stream>>>(pc, pw1, pb1, pw2, pb2, posbuf);
    gemm_k<false, 0><<<dim3(4, 20), 256, 0, stream>>>(
        px, pdw, pdb, nullptr, hidbuf, 1280, 256, 512);
    assemble_k<<<1792, 256, 0, stream>>>(hidbuf, posbuf, pcls, xbuf);

    // 2) transformer blocks
    for (int l = 0; l < 2; ++l) {
      ln_k<<<1792, 256, 0, stream>>>(xbuf, hbuf, pln1g + l * 256, pln1b + l * 256);
      gemm_k<false, 0><<<dim3(12, 28), 256, 0, stream>>>(
          hbuf, pqkvw + (size_t)l * 196608, pqkvb + l * 768, nullptr, qkvbuf, 1792, 768, 256);
      attn_k<<<dim3(896, 8, 2), 256, 0, stream>>>(qkvbuf, hbuf);
      gemm_k<false, 0><<<dim3(4, 28), 256, 0, stream>>>(
          hbuf, pattw + (size_t)l * 65536, pattb + l * 256, xbuf, xbuf, 1792, 256, 256);
      ln_k<<<1792, 256, 0, stream>>>(xbuf, hbuf, pln2g + l * 256, pln2b + l * 256);
      gemm_k<false, 1><<<dim3(16, 28), 256, 0, stream>>>(
          hbuf, pm1w + (size_t)l * 262144, pm1b + l * 1024, nullptr, hidbuf, 1792, 1024, 256);
      gemm_k<false, 0><<<dim3(4, 28), 256, 0, stream>>>(
          hidbuf, pm2w + (size_t)l * 262144, pm2b + l * 256, xbuf, xbuf, 1792, 256, 1024);
    }

    // 3) decoder head
    ln_k<<<1792, 256, 0, stream>>>(xbuf, hbuf, pdecg, pdecb);
    for (int b = 0; b < 2; ++b) {
      gemm_k<false, 0><<<dim3(4, 10), 256, 0, stream>>>(
          hbuf + (size_t)b * 896 * 256, pprp, nullptr, nullptr,
          patbuf + (size_t)b * 640 * 256, 640, 256, 256);
      gemm_k<false, 0><<<dim3(4, 4), 256, 0, stream>>>(
          hbuf + ((size_t)b * 896 + 640) * 256, pprc, nullptr, nullptr,
          clsbuf + (size_t)b * 65536, 256, 256, 256);
    }
    l2n_k<<<1280, 256, 0, stream>>>(patbuf);
    l2n_k<<<512, 256, 0, stream>>>(clsbuf);
    for (int b = 0; b < 2; ++b) {
      gemm_k<true, 0><<<dim3(4, 10), 256, 0, stream>>>(
          patbuf + (size_t)b * 163840, clsbuf + (size_t)b * 65536, nullptr, nullptr,
          masksb + (size_t)b * 163840, 640, 256, 256);
    }
    ln_k<<<1280, 256, 0, stream>>>(masksb, masksb, pmg, pmb);

    // 4) scatter table + gather (NHWC f16)
    inv_k<<<1, 1024, 0, stream>>>(pc, invbuf);
    gather16_k<<<2048, 256, 0, stream>>>(masksb, invbuf, R0h);

    // 5) MFMA conv decoder (transformer scratch + fp32 params dead before R2 write)
    const int NS = 128;
    int H = 32;
    for (int i = 0; i < 3; ++i) {
      conv3m_k<<<dim3((H / 16) * (H / 16), 4, 2), 256, 0, stream>>>(
          R0h, wf3 + (size_t)i * 9 * 65536, pucb + i * 256, R1h, H, H);
      stats1_k<<<dim3(NS, 2), 256, 0, stream>>>(R1h, partial, H * H, NS);
      stats2_k<<<2, 256, 0, stream>>>(partial, mr1, H * H, NS);
      norm_k<<<dim3(H * H / 8, 2), 256, 0, stream>>>(R1h, mr1, H * H);
      f16* dst = (i == 2) ? R2h : R0h;
      convtm_k<<<dim3((H / 16) * (H / 16), 16, 2), 256, 0, stream>>>(
          R1h, wt + (size_t)i * 4 * 65536, putb + i * 256, dst, H, H);
      stats1_k<<<dim3(NS, 2), 256, 0, stream>>>(dst, partial, 4 * H * H, NS);
      stats2_k<<<2, 256, 0, stream>>>(partial, mr1, 4 * H * H, NS);
      norm_k<<<dim3(4 * H * H / 8, 2), 256, 0, stream>>>(dst, mr1, 4 * H * H);
      H *= 2;
    }

    // 6) output conv 256 -> 3
    convoutm_k<<<dim3(256, 2), 256, 0, stream>>>(R2h, pocw, pocb, d_out, flags);
  }
}

// Round 6
// 1421.393 us; speedup vs baseline: 2.7327x; 1.3239x over previous
//
#include <hip/hip_runtime.h>
#include <hip/hip_bf16.h>

typedef __hip_bfloat16 bf16;
typedef _Float16 f16;
typedef __attribute__((ext_vector_type(8))) _Float16 f16x8;
typedef __attribute__((ext_vector_type(4))) float f32x4;

// ---------------------------------------------------------------- dtype detector
__global__ void detect_k(const unsigned short* __restrict__ xh, int* __restrict__ flags)
{
  if (threadIdx.x == 0 && blockIdx.x == 0) {
    int weird = 0;
    for (int i = 0; i < 512; ++i) {
      const int e = (xh[i] >> 7) & 0xFF;
      if (e == 0xFF || e >= 0x88) ++weird;
    }
    flags[0] = (weird > 32) ? 1 : 0;
  }
}

// ---------------------------------------------------------------- batched input->fp32 convert
#define NSEG 33
struct CvtDesc {
  const void* src[NSEG];
  unsigned dstOff[NSEG];
  unsigned n[NSEG];
};
__global__ __launch_bounds__(256) void cvtall_k(
    CvtDesc d, float* __restrict__ P, const int* __restrict__ flags)
{
  const int s = blockIdx.y;
  const unsigned n = d.n[s];
  const int fp32 = flags[0];
  float* dst = P + d.dstOff[s];
  const unsigned stride = gridDim.x * 256u;
  if (fp32) {
    const float* src = (const float*)d.src[s];
    for (unsigned i = blockIdx.x * 256u + threadIdx.x; i < n; i += stride) dst[i] = src[i];
  } else {
    const bf16* src = (const bf16*)d.src[s];
    for (unsigned i = blockIdx.x * 256u + threadIdx.x; i < n; i += stride)
      dst[i] = __bfloat162float(src[i]);
  }
}

// ---------------------------------------------------------------- conv weight prep -> f16
__global__ __launch_bounds__(256) void prepw_k(
    const float* __restrict__ ucw, const float* __restrict__ utw,
    f16* __restrict__ wf3, f16* __restrict__ wt)
{
  const int n1 = 3 * 9 * 65536;
  const int n2 = 3 * 4 * 65536;
  for (int i = blockIdx.x * 256 + threadIdx.x; i < n1 + n2; i += gridDim.x * 256) {
    if (i < n1) {
      const int st = i / 589824, r = i % 589824;
      const int kk = r / 65536, rr = r % 65536;
      const int co = rr >> 8, ci = rr & 255;
      wf3[i] = (f16)ucw[(((size_t)st * 256 + co) * 256 + ci) * 9 + kk];
    } else {
      const int j = i - n1;
      const int st = j / 262144, r = j % 262144;
      const int ij = r / 65536, rr = r % 65536;
      const int co = rr >> 8, ci = rr & 255;
      wt[j] = (f16)utw[(((size_t)st * 256 + ci) * 256 + co) * 4 + ij];
    }
  }
}

// ---------------------------------------------------------------- GEMM (fp32, transformer)
template<bool TRB, int ACT>
__global__ __launch_bounds__(256) void gemm_k(
    const float* __restrict__ A, const float* __restrict__ B,
    const float* __restrict__ bias, const float* __restrict__ res,
    float* __restrict__ C, int M, int N, int K)
{
  __shared__ float As[16][64];
  __shared__ float Bs[16][64];
  const int tid = threadIdx.x;
  const int m0 = blockIdx.y * 64, n0 = blockIdx.x * 64;
  const int tx = tid & 15, ty = tid >> 4;
  float acc[4][4] = {};
  for (int k0 = 0; k0 < K; k0 += 16) {
    {
      const int m = tid >> 2, kq = tid & 3;
      const float* ap = A + (size_t)(m0 + m) * K + k0 + kq * 4;
      #pragma unroll
      for (int i = 0; i < 4; ++i) As[kq * 4 + i][m] = ap[i];
    }
    if (!TRB) {
      const int n = tid & 63, kb = tid >> 6;
      #pragma unroll
      for (int i = 0; i < 4; ++i)
        Bs[kb + i * 4][n] = B[(size_t)(k0 + kb + i * 4) * N + n0 + n];
    } else {
      const int n = tid >> 2, kq = tid & 3;
      const float* bp = B + (size_t)(n0 + n) * K + k0 + kq * 4;
      #pragma unroll
      for (int i = 0; i < 4; ++i) Bs[kq * 4 + i][n] = bp[i];
    }
    __syncthreads();
    #pragma unroll
    for (int kk = 0; kk < 16; ++kk) {
      float av[4], bv[4];
      #pragma unroll
      for (int i = 0; i < 4; ++i) av[i] = As[kk][ty * 4 + i];
      #pragma unroll
      for (int j = 0; j < 4; ++j) bv[j] = Bs[kk][tx * 4 + j];
      #pragma unroll
      for (int i = 0; i < 4; ++i)
        #pragma unroll
        for (int j = 0; j < 4; ++j) acc[i][j] += av[i] * bv[j];
    }
    __syncthreads();
  }
  #pragma unroll
  for (int i = 0; i < 4; ++i) {
    const int row = m0 + ty * 4 + i;
    #pragma unroll
    for (int j = 0; j < 4; ++j) {
      const int col = n0 + tx * 4 + j;
      float v = acc[i][j];
      if (bias) v += bias[col];
      if (ACT == 1) v = 0.5f * v * (1.0f + erff(v * 0.70710678118654752f));
      if (res) v += res[(size_t)row * N + col];
      C[(size_t)row * N + col] = v;
    }
  }
}

// ---------------------------------------------------------------- LayerNorm (row len 256)
__global__ __launch_bounds__(256) void ln_k(
    const float* __restrict__ in, float* __restrict__ out,
    const float* __restrict__ g, const float* __restrict__ b)
{
  const int row = blockIdx.x, t = threadIdx.x;
  __shared__ float red[256];
  float x = in[(size_t)row * 256 + t];
  red[t] = x; __syncthreads();
  for (int s = 128; s > 0; s >>= 1) { if (t < s) red[t] += red[t + s]; __syncthreads(); }
  const float m = red[0] * (1.0f / 256.0f);
  __syncthreads();
  const float d = x - m;
  red[t] = d * d; __syncthreads();
  for (int s = 128; s > 0; s >>= 1) { if (t < s) red[t] += red[t + s]; __syncthreads(); }
  const float rstd = rsqrtf(red[0] * (1.0f / 256.0f) + 1e-5f);
  out[(size_t)row * 256 + t] = d * rstd * g[t] + b[t];
}

// ---------------------------------------------------------------- L2 normalize rows
__global__ __launch_bounds__(256) void l2n_k(float* __restrict__ x)
{
  const int row = blockIdx.x, t = threadIdx.x;
  __shared__ float red[256];
  float v = x[(size_t)row * 256 + t];
  red[t] = v * v; __syncthreads();
  for (int s = 128; s > 0; s >>= 1) { if (t < s) red[t] += red[t + s]; __syncthreads(); }
  x[(size_t)row * 256 + t] = v * rsqrtf(red[0]);
}

// ---------------------------------------------------------------- pos MLP
__global__ __launch_bounds__(256) void pos_k(
    const int* __restrict__ pc, const float* __restrict__ w1, const float* __restrict__ b1,
    const float* __restrict__ w2, const float* __restrict__ b2, float* __restrict__ pos)
{
  const int n = blockIdx.x, t = threadIdx.x;
  __shared__ float h[256];
  const int wide = (pc[3] == 0);
  const int sv = wide ? pc[4 * n] : pc[2 * n];
  const int cv = wide ? pc[4 * n + 2] : pc[2 * n + 1];
  float hv = (float)sv * w1[t] + (float)cv * w1[256 + t] + b1[t];
  h[t] = hv > 0.0f ? hv : 0.0f;
  __syncthreads();
  float acc = b2[t];
  for (int k = 0; k < 256; ++k) acc += h[k] * w2[k * 256 + t];
  pos[n * 256 + t] = acc;
}

// ---------------------------------------------------------------- assemble x = [proj+pos ; cls]
__global__ __launch_bounds__(256) void assemble_k(
    const float* __restrict__ proj, const float* __restrict__ pos,
    const float* __restrict__ cls, float* __restrict__ xb)
{
  const int row = blockIdx.x;
  const int b = row / 896, n = row % 896, t = threadIdx.x;
  float v;
  if (n < 640) v = proj[((size_t)b * 640 + n) * 256 + t] + pos[n * 256 + t];
  else         v = cls[(n - 640) * 256 + t];
  xb[(size_t)row * 256 + t] = v;
}

// ---------------------------------------------------------------- MFMA flash attention
// grid (28, 8, 2), 128 threads (2 waves); 32 q-rows per block, K/V tiles of 64.
__global__ __launch_bounds__(128) void attnm_k(
    const float* __restrict__ qkv, float* __restrict__ out)
{
  const int q0 = blockIdx.x << 5;
  const int h = blockIdx.y, b = blockIdx.z;
  const int t = threadIdx.x;
  const int lane = t & 63, wv = t >> 6;
  const int c = lane & 15, kg = lane >> 4;
  __shared__ f16 Qs[32][36];
  __shared__ f16 Ks[64][36];
  __shared__ f16 Vt[32][68];
  __shared__ f16 Pl[2][16][68];
  {
    // stage Q (scaled by 1/sqrt(32)): 32 rows x 4 parts of 8
    const int row = t >> 2, part = t & 3;
    const float* src = qkv + ((size_t)(b * 896 + q0 + row) * 768) + h * 32 + part * 8;
    f16 tmp[8];
    #pragma unroll
    for (int j = 0; j < 8; ++j) tmp[j] = (f16)(src[j] * 0.17677669529663687f);
    *(f16x8*)&Qs[row][part * 8] = *(const f16x8*)tmp;
  }
  const f32x4 z4 = {0.f, 0.f, 0.f, 0.f};
  f32x4 o0 = z4, o1 = z4;
  float m[4] = {-1e30f, -1e30f, -1e30f, -1e30f};
  float l[4] = {0.f, 0.f, 0.f, 0.f};

  for (int k0 = 0; k0 < 896; k0 += 64) {
    __syncthreads();
    for (int i = t; i < 256; i += 128) {          // K tile: 64 rows x 4 parts
      const int row = i >> 2, part = i & 3;
      const float* src = qkv + ((size_t)(b * 896 + k0 + row) * 768) + 256 + h * 32 + part * 8;
      f16 tmp[8];
      #pragma unroll
      for (int j = 0; j < 8; ++j) tmp[j] = (f16)src[j];
      *(f16x8*)&Ks[row][part * 8] = *(const f16x8*)tmp;
    }
    for (int i = t; i < 256; i += 128) {          // V tile transposed: Vt[d][kpos]
      const int row = i >> 2, part = i & 3;
      const float* src = qkv + ((size_t)(b * 896 + k0 + row) * 768) + 512 + h * 32 + part * 8;
      #pragma unroll
      for (int j = 0; j < 8; ++j) Vt[part * 8 + j][row] = (f16)src[j];
    }
    __syncthreads();
    // QK^T: S(16q x 64k) per wave
    const f16x8 aq = *(const f16x8*)&Qs[wv * 16 + c][kg * 8];
    f32x4 s[4];
    #pragma unroll
    for (int fn = 0; fn < 4; ++fn)
      s[fn] = __builtin_amdgcn_mfma_f32_16x16x32_f16(
          aq, *(const f16x8*)&Ks[fn * 16 + c][kg * 8], z4, 0, 0, 0);
    // online softmax (rows kg*4+r live across the 16-lane c-group)
    float sc[4];
    #pragma unroll
    for (int r = 0; r < 4; ++r) {
      float v = fmaxf(fmaxf(s[0][r], s[1][r]), fmaxf(s[2][r], s[3][r]));
      #pragma unroll
      for (int msk = 1; msk < 16; msk <<= 1) v = fmaxf(v, __shfl_xor(v, msk));
      const float mn = fmaxf(m[r], v);
      sc[r] = __expf(m[r] - mn);
      m[r] = mn;
    }
    #pragma unroll
    for (int r = 0; r < 4; ++r) {
      float ps = 0.f;
      #pragma unroll
      for (int fn = 0; fn < 4; ++fn) {
        const float p = __expf(s[fn][r] - m[r]);
        ps += p;
        Pl[wv][kg * 4 + r][fn * 16 + c] = (f16)p;
      }
      #pragma unroll
      for (int msk = 1; msk < 16; msk <<= 1) ps += __shfl_xor(ps, msk);
      l[r] = l[r] * sc[r] + ps;
    }
    #pragma unroll
    for (int r = 0; r < 4; ++r) { o0[r] *= sc[r]; o1[r] *= sc[r]; }
    // PV: O(16q x 32d) += P(16x64) @ V(64x32)
    const f16x8 a0 = *(const f16x8*)&Pl[wv][c][kg * 8];
    const f16x8 a1 = *(const f16x8*)&Pl[wv][c][32 + kg * 8];
    o0 = __builtin_amdgcn_mfma_f32_16x16x32_f16(a0, *(const f16x8*)&Vt[c][kg * 8], o0, 0, 0, 0);
    o0 = __builtin_amdgcn_mfma_f32_16x16x32_f16(a1, *(const f16x8*)&Vt[c][32 + kg * 8], o0, 0, 0, 0);
    o1 = __builtin_amdgcn_mfma_f32_16x16x32_f16(a0, *(const f16x8*)&Vt[16 + c][kg * 8], o1, 0, 0, 0);
    o1 = __builtin_amdgcn_mfma_f32_16x16x32_f16(a1, *(const f16x8*)&Vt[16 + c][32 + kg * 8], o1, 0, 0, 0);
  }
  #pragma unroll
  for (int r = 0; r < 4; ++r) {
    const int row = q0 + wv * 16 + kg * 4 + r;
    const float inv = 1.0f / l[r];
    out[((size_t)(b * 896 + row) * 256) + h * 32 + c] = o0[r] * inv;
    out[((size_t)(b * 896 + row) * 256) + h * 32 + 16 + c] = o1[r] * inv;
  }
}

// ---------------------------------------------------------------- build inv table
__global__ __launch_bounds__(1024) void inv_k(const int* __restrict__ pc, int* __restrict__ inv)
{
  const int t = threadIdx.x;
  if (t < 1024) inv[t] = 0;
  __syncthreads();
  if (t < 640) {
    const int wide = (pc[3] == 0);
    int s = wide ? pc[4 * t] : pc[2 * t];
    int coord = wide ? pc[4 * t + 2] : pc[2 * t + 1];
    s &= 1;
    const int gs = 16 << s;
    const int k = 1 << (1 - s);
    const int r = (coord / gs) * k, c = (coord % gs) * k;
    for (int oi = 0; oi < k; ++oi)
      for (int oj = 0; oj < k; ++oj) {
        const int rr = r + oi, cc = c + oj;
        if (rr >= 0 && rr < 32 && cc >= 0 && cc < 32)
          inv[rr * 32 + cc] = t;
      }
  }
}

// ---------------------------------------------------------------- gather masks -> NHWC f16 img
__global__ __launch_bounds__(256) void gather16_k(
    const float* __restrict__ masks, const int* __restrict__ inv, f16* __restrict__ img)
{
  const int p = blockIdx.x & 1023, b = blockIdx.x >> 10, t = threadIdx.x;
  img[((size_t)blockIdx.x << 8) + t] = (f16)masks[((size_t)b * 640 + inv[p]) * 256 + t];
}

// ---------------------------------------------------------------- MFMA conv3x3 (NHWC f16)
__global__ __launch_bounds__(256) void conv3m_k(
    const f16* __restrict__ x, const f16* __restrict__ wf, const float* __restrict__ bias,
    f16* __restrict__ y, int H, int W)
{
  const int tilesx = W >> 4;
  const int ty0 = (blockIdx.x / tilesx) << 4, tx0 = (blockIdx.x % tilesx) << 4;
  const int co0 = blockIdx.y << 6;
  const int b = blockIdx.z;
  const int t = threadIdx.x;
  const int lane = t & 63, wv = t >> 6;
  const int frow = lane & 15, kg = lane >> 4;
  __shared__ f16 halo[18][18][40];
  __shared__ f16 bt3[3][64][40];
  f32x4 acc[4][4];
  #pragma unroll
  for (int i = 0; i < 4; ++i)
    #pragma unroll
    for (int j = 0; j < 4; ++j) acc[i][j] = (f32x4){0.f, 0.f, 0.f, 0.f};

  for (int c0 = 0; c0 < 256; c0 += 32) {
    __syncthreads();
    for (int i = t; i < 1296; i += 256) {
      const int cell = i >> 2, part = i & 3;
      const int hy = cell / 18, hx = cell - hy * 18;
      const int gy = ty0 + hy - 1, gx = tx0 + hx - 1;
      f16x8 v = {(f16)0,(f16)0,(f16)0,(f16)0,(f16)0,(f16)0,(f16)0,(f16)0};
      if (gy >= 0 && gy < H && gx >= 0 && gx < W)
        v = *(const f16x8*)&x[(((size_t)b * H + gy) * W + gx) * 256 + c0 + part * 8];
      *(f16x8*)&halo[hy][hx][part * 8] = v;
    }
    for (int kyr = 0; kyr < 3; ++kyr) {
      __syncthreads();
      for (int i = t; i < 768; i += 256) {
        const int tr = i >> 8, rem = i & 255, co = rem >> 2, part = rem & 3;
        *(f16x8*)&bt3[tr][co][part * 8] =
            *(const f16x8*)&wf[(((size_t)(kyr * 3 + tr)) * 256 + co0 + co) * 256 + c0 + part * 8];
      }
      __syncthreads();
      #pragma unroll
      for (int kx = 0; kx < 3; ++kx) {
        f16x8 af[4], bf[4];
        #pragma unroll
        for (int fm = 0; fm < 4; ++fm) {
          const int pos = wv * 64 + fm * 16 + frow;
          af[fm] = *(const f16x8*)&halo[(pos >> 4) + kyr][(pos & 15) + kx][kg * 8];
        }
        #pragma unroll
        for (int fn = 0; fn < 4; ++fn)
          bf[fn] = *(const f16x8*)&bt3[kx][fn * 16 + frow][kg * 8];
        #pragma unroll
        for (int fm = 0; fm < 4; ++fm)
          #pragma unroll
          for (int fn = 0; fn < 4; ++fn)
            acc[fm][fn] = __builtin_amdgcn_mfma_f32_16x16x32_f16(af[fm], bf[fn], acc[fm][fn], 0, 0, 0);
      }
    }
  }
  #pragma unroll
  for (int fn = 0; fn < 4; ++fn) {
    const int col = co0 + fn * 16 + frow;
    const float bv = bias[col];
    #pragma unroll
    for (int fm = 0; fm < 4; ++fm)
      #pragma unroll
      for (int r = 0; r < 4; ++r) {
        const int pos = wv * 64 + fm * 16 + kg * 4 + r;
        y[(((size_t)b * H + ty0 + (pos >> 4)) * W + tx0 + (pos & 15)) * 256 + col] =
            (f16)(acc[fm][fn][r] + bv);
      }
  }
}

// ---------------------------------------------------------------- MFMA convT 2x2 s2
__global__ __launch_bounds__(256) void convtm_k(
    const f16* __restrict__ x, const f16* __restrict__ wtp, const float* __restrict__ bias,
    f16* __restrict__ y, int H, int W)
{
  const int tilesx = W >> 4;
  const int ty0 = (blockIdx.x / tilesx) << 4, tx0 = (blockIdx.x % tilesx) << 4;
  const int co0 = (blockIdx.y >> 2) << 6;
  const int par = blockIdx.y & 3;
  const int pa = par >> 1, pb = par & 1;
  const int b = blockIdx.z;
  const int t = threadIdx.x;
  const int lane = t & 63, wv = t >> 6;
  const int frow = lane & 15, kg = lane >> 4;
  __shared__ f16 at[256][40];
  __shared__ f16 btw[64][40];
  f32x4 acc[4][4];
  #pragma unroll
  for (int i = 0; i < 4; ++i)
    #pragma unroll
    for (int j = 0; j < 4; ++j) acc[i][j] = (f32x4){0.f, 0.f, 0.f, 0.f};

  for (int c0 = 0; c0 < 256; c0 += 32) {
    __syncthreads();
    for (int i = t; i < 1024; i += 256) {
      const int cell = i >> 2, part = i & 3;
      const int gy = ty0 + (cell >> 4), gx = tx0 + (cell & 15);
      *(f16x8*)&at[cell][part * 8] =
          *(const f16x8*)&x[(((size_t)b * H + gy) * W + gx) * 256 + c0 + part * 8];
    }
    {
      const int i = t;
      const int co = i >> 2, part = i & 3;
      *(f16x8*)&btw[co][part * 8] =
          *(const f16x8*)&wtp[((size_t)par * 256 + co0 + co) * 256 + c0 + part * 8];
    }
    __syncthreads();
    f16x8 af[4], bf[4];
    #pragma unroll
    for (int fm = 0; fm < 4; ++fm)
      af[fm] = *(const f16x8*)&at[wv * 64 + fm * 16 + frow][kg * 8];
    #pragma unroll
    for (int fn = 0; fn < 4; ++fn)
      bf[fn] = *(const f16x8*)&btw[fn * 16 + frow][kg * 8];
    #pragma unroll
    for (int fm = 0; fm < 4; ++fm)
      #pragma unroll
      for (int fn = 0; fn < 4; ++fn)
        acc[fm][fn] = __builtin_amdgcn_mfma_f32_16x16x32_f16(af[fm], bf[fn], acc[fm][fn], 0, 0, 0);
  }
  const int HO = H << 1, WO = W << 1;
  #pragma unroll
  for (int fn = 0; fn < 4; ++fn) {
    const int col = co0 + fn * 16 + frow;
    const float bv = bias[col];
    #pragma unroll
    for (int fm = 0; fm < 4; ++fm)
      #pragma unroll
      for (int r = 0; r < 4; ++r) {
        const int pos = wv * 64 + fm * 16 + kg * 4 + r;
        const int oy = ((ty0 + (pos >> 4)) << 1) + pa;
        const int ox = ((tx0 + (pos & 15)) << 1) + pb;
        y[(((size_t)b * HO + oy) * WO + ox) * 256 + col] = (f16)(acc[fm][fn][r] + bv);
      }
  }
}

// ---------------------------------------------------------------- instance-norm stats + normalize
__global__ __launch_bounds__(256) void stats1_k(
    const f16* __restrict__ x, float2* __restrict__ partial, int HW, int NS)
{
  const int s = blockIdx.x, b = blockIdx.y, t = threadIdx.x;
  const int rpb = HW / NS;
  const f16* p = x + ((size_t)b * HW + (size_t)s * rpb) * 256;
  float s1 = 0.f, s2 = 0.f;
  for (int r = 0; r < rpb; ++r) {
    const float v = (float)p[(size_t)r * 256 + t];
    s1 += v; s2 += v * v;
  }
  partial[((size_t)b * NS + s) * 256 + t] = make_float2(s1, s2);
}
__global__ __launch_bounds__(256) void stats2_k(
    const float2* __restrict__ partial, float2* __restrict__ mr, int HW, int NS)
{
  const int b = blockIdx.x, t = threadIdx.x;
  float s1 = 0.f, s2 = 0.f;
  for (int s = 0; s < NS; ++s) {
    const float2 v = partial[((size_t)b * NS + s) * 256 + t];
    s1 += v.x; s2 += v.y;
  }
  const float m = s1 / (float)HW;
  const float var = fmaxf(s2 / (float)HW - m * m, 0.f);
  mr[b * 256 + t] = make_float2(m, rsqrtf(var + 1e-5f));
}
__global__ __launch_bounds__(256) void norm_k(
    f16* __restrict__ x, const float2* __restrict__ mr, int HW)
{
  const int b = blockIdx.y, t = threadIdx.x;
  const float2 v = mr[b * 256 + t];
  f16* p = x + ((size_t)b * HW + (size_t)blockIdx.x * 8) * 256;
  #pragma unroll
  for (int r = 0; r < 8; ++r) {
    float z = ((float)p[(size_t)r * 256 + t] - v.x) * v.y;
    p[(size_t)r * 256 + t] = (f16)(z >= 0.f ? z : 0.01f * z);
  }
}

// ---------------------------------------------------------------- out conv 3x3: 256 -> 3
__global__ __launch_bounds__(256) void convoutm_k(
    const f16* __restrict__ x, const float* __restrict__ w,
    const float* __restrict__ bias, void* __restrict__ yv, const int* __restrict__ flags)
{
  const int ty0 = (blockIdx.x >> 4) << 4, tx0 = (blockIdx.x & 15) << 4;
  const int b = blockIdx.y, t = threadIdx.x;
  const int py = t >> 4, px = t & 15;
  __shared__ float xin[18][18][9];
  __shared__ float wsm[8][9][3];
  float acc[3] = {0.f, 0.f, 0.f};
  for (int c0 = 0; c0 < 256; c0 += 8) {
    __syncthreads();
    for (int i = t; i < 2592; i += 256) {
      const int cell = i >> 3, ci = i & 7;
      const int hy = cell / 18, hx = cell - hy * 18;
      const int gy = ty0 + hy - 1, gx = tx0 + hx - 1;
      float v = 0.f;
      if (gy >= 0 && gy < 256 && gx >= 0 && gx < 256)
        v = (float)x[(((size_t)b * 256 + gy) * 256 + gx) * 256 + c0 + ci];
      xin[hy][hx][ci] = v;
    }
    for (int i = t; i < 216; i += 256) {
      const int co = i % 3, r = i / 3, ci = r / 9, kk = r % 9;
      wsm[ci][kk][co] = w[(((size_t)co * 256) + c0 + ci) * 9 + kk];
    }
    __syncthreads();
    #pragma unroll
    for (int ci = 0; ci < 8; ++ci)
      #pragma unroll
      for (int kk = 0; kk < 9; ++kk) {
        const float v = xin[py + kk / 3][px + kk % 3][ci];
        acc[0] += v * wsm[ci][kk][0];
        acc[1] += v * wsm[ci][kk][1];
        acc[2] += v * wsm[ci][kk][2];
      }
  }
  const int fp32 = flags[0];
  #pragma unroll
  for (int co = 0; co < 3; ++co) {
    const size_t oidx = (((size_t)b * 3 + co) * 256 + ty0 + py) * 256 + tx0 + px;
    const float v = acc[co] + bias[co];
    if (fp32) ((float*)yv)[oidx] = v;
    else      ((bf16*)yv)[oidx] = __float2bfloat16(v);
  }
}

// ================================================================ host
extern "C" void kernel_launch(void* const* d_in, const int* in_sizes, int n_in,
                              void* d_out, int out_size, void* d_ws, size_t ws_size,
                              hipStream_t stream) {
  (void)in_sizes; (void)n_in; (void)out_size; (void)ws_size;
  const int* pc = (const int*)d_in[1];

  float* P = (float*)d_ws;
  size_t off = 0;
  CvtDesc cd{};
  int seg = 0;
  auto alloc = [&](size_t n) { float* p = P + off; off += n; return p; };
  auto allocCv = [&](int idx, size_t n) {
    float* p = P + off;
    cd.src[seg] = d_in[idx]; cd.dstOff[seg] = (unsigned)off; cd.n[seg] = (unsigned)n;
    ++seg; off += n; return p;
  };

  // ---- persistent small region ----
  int*    flags   = (int*)alloc(16);
  int*    invbuf  = (int*)alloc(1024);
  float2* partial = (float2*)alloc(131072);
  float2* mr1     = (float2*)alloc(1024);
  float* pdb   = allocCv(3, 256);
  float* pw1   = allocCv(4, 512);
  float* pb1   = allocCv(5, 256);
  float* pb2   = allocCv(7, 256);
  float* pln1g = allocCv(9, 512);
  float* pln1b = allocCv(10, 512);
  float* pqkvb = allocCv(12, 1536);
  float* pattb = allocCv(14, 512);
  float* pln2g = allocCv(15, 512);
  float* pln2b = allocCv(16, 512);
  float* pm1b  = allocCv(18, 2048);
  float* pm2b  = allocCv(20, 512);
  float* pdecg = allocCv(21, 256);
  float* pdecb = allocCv(22, 256);
  float* pmg   = allocCv(25, 256);
  float* pmb   = allocCv(26, 256);
  float* pucb  = allocCv(28, 768);
  float* putb  = allocCv(30, 768);
  float* pocw  = allocCv(31, 6912);
  float* pocb  = allocCv(32, 16);
  off = (off + 255) & ~(size_t)255;
  f16* wf3 = (f16*)alloc(884736);
  f16* wt  = (f16*)alloc(393216);
  off = (off + 255) & ~(size_t)255;

  // ---- zone A: big fp32 params + transformer scratch, later overlaid by R2 (f16) ----
  float* zoneA = P + off;
  f16*   R2h   = (f16*)zoneA;
  {
    size_t zo = off;
    auto zCv = [&](int idx, size_t n) {
      float* p = P + zo;
      cd.src[seg] = d_in[idx]; cd.dstOff[seg] = (unsigned)zo; cd.n[seg] = (unsigned)n;
      ++seg; zo += n; return p;
    };
    float* px    = zCv(0, 655360);
    float* pdw   = zCv(2, 131072);
    float* pw2   = zCv(6, 65536);
    float* pcls  = zCv(8, 65536);
    float* pqkvw = zCv(11, 393216);
    float* pattw = zCv(13, 131072);
    float* pm1w  = zCv(17, 524288);
    float* pm2w  = zCv(19, 524288);
    float* pprp  = zCv(23, 65536);
    float* pprc  = zCv(24, 65536);
    float* pucw  = zCv(27, 1769472);
    float* putw  = zCv(29, 786432);
    float* xbuf   = P + zo; zo += 458752;
    float* hbuf   = P + zo; zo += 458752;
    float* qkvbuf = P + zo; zo += 1376256;
    float* hidbuf = P + zo; zo += 1835008;
    float* posbuf = P + zo; zo += 163840;
    float* patbuf = P + zo; zo += 327680;
    float* clsbuf = P + zo; zo += 131072;
    float* masksb = P + zo; zo += 327680;
    off += 16777216;
    f16* R0h = (f16*)(P + off); off += 4194304;
    f16* R1h = (f16*)(P + off); off += 4194304;

    // 0) detect dtype, convert inputs to fp32, prep f16 conv weights
    detect_k<<<1, 64, 0, stream>>>((const unsigned short*)d_in[0], flags);
    cvtall_k<<<dim3(256, NSEG), 256, 0, stream>>>(cd, P, flags);
    prepw_k<<<2048, 256, 0, stream>>>(pucw, putw, wf3, wt);

    // 1) positional MLP + patch projection + sequence assembly
    pos_k<<<640, 256, 0, stream>>>(pc, pw1, pb1, pw2, pb2, posbuf);
    gemm_k<false, 0><<<dim3(4, 20), 256, 0, stream>>>(
        px, pdw, pdb, nullptr, hidbuf, 1280, 256, 512);
    assemble_k<<<1792, 256, 0, stream>>>(hidbuf, posbuf, pcls, xbuf);

    // 2) transformer blocks
    for (int l = 0; l < 2; ++l) {
      ln_k<<<1792, 256, 0, stream>>>(xbuf, hbuf, pln1g + l * 256, pln1b + l * 256);
      gemm_k<false, 0><<<dim3(12, 28), 256, 0, stream>>>(
          hbuf, pqkvw + (size_t)l * 196608, pqkvb + l * 768, nullptr, qkvbuf, 1792, 768, 256);
      attnm_k<<<dim3(28, 8, 2), 128, 0, stream>>>(qkvbuf, hbuf);
      gemm_k<false, 0><<<dim3(4, 28), 256, 0, stream>>>(
          hbuf, pattw + (size_t)l * 65536, pattb + l * 256, xbuf, xbuf, 1792, 256, 256);
      ln_k<<<1792, 256, 0, stream>>>(xbuf, hbuf, pln2g + l * 256, pln2b + l * 256);
      gemm_k<false, 1><<<dim3(16, 28), 256, 0, stream>>>(
          hbuf, pm1w + (size_t)l * 262144, pm1b + l * 1024, nullptr, hidbuf, 1792, 1024, 256);
      gemm_k<false, 0><<<dim3(4, 28), 256, 0, stream>>>(
          hidbuf, pm2w + (size_t)l * 262144, pm2b + l * 256, xbuf, xbuf, 1792, 256, 1024);
    }

    // 3) decoder head
    ln_k<<<1792, 256, 0, stream>>>(xbuf, hbuf, pdecg, pdecb);
    for (int b = 0; b < 2; ++b) {
      gemm_k<false, 0><<<dim3(4, 10), 256, 0, stream>>>(
          hbuf + (size_t)b * 896 * 256, pprp, nullptr, nullptr,
          patbuf + (size_t)b * 640 * 256, 640, 256, 256);
      gemm_k<false, 0><<<dim3(4, 4), 256, 0, stream>>>(
          hbuf + ((size_t)b * 896 + 640) * 256, pprc, nullptr, nullptr,
          clsbuf + (size_t)b * 65536, 256, 256, 256);
    }
    l2n_k<<<1280, 256, 0, stream>>>(patbuf);
    l2n_k<<<512, 256, 0, stream>>>(clsbuf);
    for (int b = 0; b < 2; ++b) {
      gemm_k<true, 0><<<dim3(4, 10), 256, 0, stream>>>(
          patbuf + (size_t)b * 163840, clsbuf + (size_t)b * 65536, nullptr, nullptr,
          masksb + (size_t)b * 163840, 640, 256, 256);
    }
    ln_k<<<1280, 256, 0, stream>>>(masksb, masksb, pmg, pmb);

    // 4) scatter table + gather (NHWC f16)
    inv_k<<<1, 1024, 0, stream>>>(pc, invbuf);
    gather16_k<<<2048, 256, 0, stream>>>(masksb, invbuf, R0h);

    // 5) MFMA conv decoder
    const int NS = 128;
    int H = 32;
    for (int i = 0; i < 3; ++i) {
      conv3m_k<<<dim3((H / 16) * (H / 16), 4, 2), 256, 0, stream>>>(
          R0h, wf3 + (size_t)i * 9 * 65536, pucb + i * 256, R1h, H, H);
      stats1_k<<<dim3(NS, 2), 256, 0, stream>>>(R1h, partial, H * H, NS);
      stats2_k<<<2, 256, 0, stream>>>(partial, mr1, H * H, NS);
      norm_k<<<dim3(H * H / 8, 2), 256, 0, stream>>>(R1h, mr1, H * H);
      f16* dst = (i == 2) ? R2h : R0h;
      convtm_k<<<dim3((H / 16) * (H / 16), 16, 2), 256, 0, stream>>>(
          R1h, wt + (size_t)i * 4 * 65536, putb + i * 256, dst, H, H);
      stats1_k<<<dim3(NS, 2), 256, 0, stream>>>(dst, partial, 4 * H * H, NS);
      stats2_k<<<2, 256, 0, stream>>>(partial, mr1, 4 * H * H, NS);
      norm_k<<<dim3(4 * H * H / 8, 2), 256, 0, stream>>>(dst, mr1, 4 * H * H);
      H *= 2;
    }

    // 6) output conv 256 -> 3
    convoutm_k<<<dim3(256, 2), 256, 0, stream>>>(R2h, pocw, pocb, d_out, flags);
  }
}

// Round 7
// 1399.498 us; speedup vs baseline: 2.7754x; 1.0156x over previous
//
#include <hip/hip_runtime.h>
#include <hip/hip_bf16.h>

typedef __hip_bfloat16 bf16;
typedef _Float16 f16;
typedef __attribute__((ext_vector_type(8))) _Float16 f16x8;
typedef __attribute__((ext_vector_type(4))) float f32x4;

// ---------------------------------------------------------------- dtype detector
__global__ void detect_k(const unsigned short* __restrict__ xh, int* __restrict__ flags)
{
  if (threadIdx.x == 0 && blockIdx.x == 0) {
    int weird = 0;
    for (int i = 0; i < 512; ++i) {
      const int e = (xh[i] >> 7) & 0xFF;
      if (e == 0xFF || e >= 0x88) ++weird;
    }
    flags[0] = (weird > 32) ? 1 : 0;
  }
}

// ---------------------------------------------------------------- batched input->fp32 convert
#define NSEG 33
struct CvtDesc {
  const void* src[NSEG];
  unsigned dstOff[NSEG];
  unsigned n[NSEG];
};
__global__ __launch_bounds__(256) void cvtall_k(
    CvtDesc d, float* __restrict__ P, const int* __restrict__ flags)
{
  const int s = blockIdx.y;
  const unsigned n = d.n[s];
  const int fp32 = flags[0];
  float* dst = P + d.dstOff[s];
  const unsigned stride = gridDim.x * 256u;
  if (fp32) {
    const float* src = (const float*)d.src[s];
    for (unsigned i = blockIdx.x * 256u + threadIdx.x; i < n; i += stride) dst[i] = src[i];
  } else {
    const bf16* src = (const bf16*)d.src[s];
    for (unsigned i = blockIdx.x * 256u + threadIdx.x; i < n; i += stride)
      dst[i] = __bfloat162float(src[i]);
  }
}

// ---------------------------------------------------------------- conv weight prep
// wf3: [stage][9][co][ci] f16 ; wt: [stage][4][co][ci] f16 ; ocwT: [tap][ci][co] fp32
__global__ __launch_bounds__(256) void prepw_k(
    const float* __restrict__ ucw, const float* __restrict__ utw, const float* __restrict__ ocw,
    f16* __restrict__ wf3, f16* __restrict__ wt, float* __restrict__ ocwT)
{
  const int n1 = 3 * 9 * 65536;
  const int n2 = 3 * 4 * 65536;
  const int n3 = 6912;
  for (int i = blockIdx.x * 256 + threadIdx.x; i < n1 + n2 + n3; i += gridDim.x * 256) {
    if (i < n1) {
      const int st = i / 589824, r = i % 589824;
      const int kk = r / 65536, rr = r % 65536;
      const int co = rr >> 8, ci = rr & 255;
      wf3[i] = (f16)ucw[(((size_t)st * 256 + co) * 256 + ci) * 9 + kk];
    } else if (i < n1 + n2) {
      const int j = i - n1;
      const int st = j / 262144, r = j % 262144;
      const int ij = r / 65536, rr = r % 65536;
      const int co = rr >> 8, ci = rr & 255;
      wt[j] = (f16)utw[(((size_t)st * 256 + ci) * 256 + co) * 4 + ij];
    } else {
      const int j = i - n1 - n2;          // j = (tap*256 + ci)*3 + co
      const int co = j % 3, r = j / 3;
      const int tap = r >> 8, ci = r & 255;
      ocwT[j] = ocw[((size_t)co * 256 + ci) * 9 + tap];
    }
  }
}

// ---------------------------------------------------------------- GEMM (fp32, transformer)
template<bool TRB, int ACT>
__global__ __launch_bounds__(256) void gemm_k(
    const float* __restrict__ A, const float* __restrict__ B,
    const float* __restrict__ bias, const float* __restrict__ res,
    float* __restrict__ C, int M, int N, int K)
{
  __shared__ float As[16][64];
  __shared__ float Bs[16][64];
  const int tid = threadIdx.x;
  const int m0 = blockIdx.y * 64, n0 = blockIdx.x * 64;
  const int tx = tid & 15, ty = tid >> 4;
  float acc[4][4] = {};
  for (int k0 = 0; k0 < K; k0 += 16) {
    {
      const int m = tid >> 2, kq = tid & 3;
      const float* ap = A + (size_t)(m0 + m) * K + k0 + kq * 4;
      #pragma unroll
      for (int i = 0; i < 4; ++i) As[kq * 4 + i][m] = ap[i];
    }
    if (!TRB) {
      const int n = tid & 63, kb = tid >> 6;
      #pragma unroll
      for (int i = 0; i < 4; ++i)
        Bs[kb + i * 4][n] = B[(size_t)(k0 + kb + i * 4) * N + n0 + n];
    } else {
      const int n = tid >> 2, kq = tid & 3;
      const float* bp = B + (size_t)(n0 + n) * K + k0 + kq * 4;
      #pragma unroll
      for (int i = 0; i < 4; ++i) Bs[kq * 4 + i][n] = bp[i];
    }
    __syncthreads();
    #pragma unroll
    for (int kk = 0; kk < 16; ++kk) {
      float av[4], bv[4];
      #pragma unroll
      for (int i = 0; i < 4; ++i) av[i] = As[kk][ty * 4 + i];
      #pragma unroll
      for (int j = 0; j < 4; ++j) bv[j] = Bs[kk][tx * 4 + j];
      #pragma unroll
      for (int i = 0; i < 4; ++i)
        #pragma unroll
        for (int j = 0; j < 4; ++j) acc[i][j] += av[i] * bv[j];
    }
    __syncthreads();
  }
  #pragma unroll
  for (int i = 0; i < 4; ++i) {
    const int row = m0 + ty * 4 + i;
    #pragma unroll
    for (int j = 0; j < 4; ++j) {
      const int col = n0 + tx * 4 + j;
      float v = acc[i][j];
      if (bias) v += bias[col];
      if (ACT == 1) v = 0.5f * v * (1.0f + erff(v * 0.70710678118654752f));
      if (res) v += res[(size_t)row * N + col];
      C[(size_t)row * N + col] = v;
    }
  }
}

// ---------------------------------------------------------------- LayerNorm (row len 256)
__global__ __launch_bounds__(256) void ln_k(
    const float* __restrict__ in, float* __restrict__ out,
    const float* __restrict__ g, const float* __restrict__ b)
{
  const int row = blockIdx.x, t = threadIdx.x;
  __shared__ float red[256];
  float x = in[(size_t)row * 256 + t];
  red[t] = x; __syncthreads();
  for (int s = 128; s > 0; s >>= 1) { if (t < s) red[t] += red[t + s]; __syncthreads(); }
  const float m = red[0] * (1.0f / 256.0f);
  __syncthreads();
  const float d = x - m;
  red[t] = d * d; __syncthreads();
  for (int s = 128; s > 0; s >>= 1) { if (t < s) red[t] += red[t + s]; __syncthreads(); }
  const float rstd = rsqrtf(red[0] * (1.0f / 256.0f) + 1e-5f);
  out[(size_t)row * 256 + t] = d * rstd * g[t] + b[t];
}

// ---------------------------------------------------------------- L2 normalize rows
__global__ __launch_bounds__(256) void l2n_k(float* __restrict__ x)
{
  const int row = blockIdx.x, t = threadIdx.x;
  __shared__ float red[256];
  float v = x[(size_t)row * 256 + t];
  red[t] = v * v; __syncthreads();
  for (int s = 128; s > 0; s >>= 1) { if (t < s) red[t] += red[t + s]; __syncthreads(); }
  x[(size_t)row * 256 + t] = v * rsqrtf(red[0]);
}

// ---------------------------------------------------------------- pos MLP
__global__ __launch_bounds__(256) void pos_k(
    const int* __restrict__ pc, const float* __restrict__ w1, const float* __restrict__ b1,
    const float* __restrict__ w2, const float* __restrict__ b2, float* __restrict__ pos)
{
  const int n = blockIdx.x, t = threadIdx.x;
  __shared__ float h[256];
  const int wide = (pc[3] == 0);
  const int sv = wide ? pc[4 * n] : pc[2 * n];
  const int cv = wide ? pc[4 * n + 2] : pc[2 * n + 1];
  float hv = (float)sv * w1[t] + (float)cv * w1[256 + t] + b1[t];
  h[t] = hv > 0.0f ? hv : 0.0f;
  __syncthreads();
  float acc = b2[t];
  for (int k = 0; k < 256; ++k) acc += h[k] * w2[k * 256 + t];
  pos[n * 256 + t] = acc;
}

// ---------------------------------------------------------------- assemble x = [proj+pos ; cls]
__global__ __launch_bounds__(256) void assemble_k(
    const float* __restrict__ proj, const float* __restrict__ pos,
    const float* __restrict__ cls, float* __restrict__ xb)
{
  const int row = blockIdx.x;
  const int b = row / 896, n = row % 896, t = threadIdx.x;
  float v;
  if (n < 640) v = proj[((size_t)b * 640 + n) * 256 + t] + pos[n * 256 + t];
  else         v = cls[(n - 640) * 256 + t];
  xb[(size_t)row * 256 + t] = v;
}

// ---------------------------------------------------------------- MFMA flash attention
__global__ __launch_bounds__(128) void attnm_k(
    const float* __restrict__ qkv, float* __restrict__ out)
{
  const int q0 = blockIdx.x << 5;
  const int h = blockIdx.y, b = blockIdx.z;
  const int t = threadIdx.x;
  const int lane = t & 63, wv = t >> 6;
  const int c = lane & 15, kg = lane >> 4;
  __shared__ f16 Qs[32][36];
  __shared__ f16 Ks[64][36];
  __shared__ f16 Vt[32][68];
  __shared__ f16 Pl[2][16][68];
  {
    const int row = t >> 2, part = t & 3;
    const float* src = qkv + ((size_t)(b * 896 + q0 + row) * 768) + h * 32 + part * 8;
    f16 tmp[8];
    #pragma unroll
    for (int j = 0; j < 8; ++j) tmp[j] = (f16)(src[j] * 0.17677669529663687f);
    *(f16x8*)&Qs[row][part * 8] = *(const f16x8*)tmp;
  }
  const f32x4 z4 = {0.f, 0.f, 0.f, 0.f};
  f32x4 o0 = z4, o1 = z4;
  float m[4] = {-1e30f, -1e30f, -1e30f, -1e30f};
  float l[4] = {0.f, 0.f, 0.f, 0.f};

  for (int k0 = 0; k0 < 896; k0 += 64) {
    __syncthreads();
    for (int i = t; i < 256; i += 128) {
      const int row = i >> 2, part = i & 3;
      const float* src = qkv + ((size_t)(b * 896 + k0 + row) * 768) + 256 + h * 32 + part * 8;
      f16 tmp[8];
      #pragma unroll
      for (int j = 0; j < 8; ++j) tmp[j] = (f16)src[j];
      *(f16x8*)&Ks[row][part * 8] = *(const f16x8*)tmp;
    }
    for (int i = t; i < 256; i += 128) {
      const int row = i >> 2, part = i & 3;
      const float* src = qkv + ((size_t)(b * 896 + k0 + row) * 768) + 512 + h * 32 + part * 8;
      #pragma unroll
      for (int j = 0; j < 8; ++j) Vt[part * 8 + j][row] = (f16)src[j];
    }
    __syncthreads();
    const f16x8 aq = *(const f16x8*)&Qs[wv * 16 + c][kg * 8];
    f32x4 s[4];
    #pragma unroll
    for (int fn = 0; fn < 4; ++fn)
      s[fn] = __builtin_amdgcn_mfma_f32_16x16x32_f16(
          aq, *(const f16x8*)&Ks[fn * 16 + c][kg * 8], z4, 0, 0, 0);
    float sc[4];
    #pragma unroll
    for (int r = 0; r < 4; ++r) {
      float v = fmaxf(fmaxf(s[0][r], s[1][r]), fmaxf(s[2][r], s[3][r]));
      #pragma unroll
      for (int msk = 1; msk < 16; msk <<= 1) v = fmaxf(v, __shfl_xor(v, msk));
      const float mn = fmaxf(m[r], v);
      sc[r] = __expf(m[r] - mn);
      m[r] = mn;
    }
    #pragma unroll
    for (int r = 0; r < 4; ++r) {
      float ps = 0.f;
      #pragma unroll
      for (int fn = 0; fn < 4; ++fn) {
        const float p = __expf(s[fn][r] - m[r]);
        ps += p;
        Pl[wv][kg * 4 + r][fn * 16 + c] = (f16)p;
      }
      #pragma unroll
      for (int msk = 1; msk < 16; msk <<= 1) ps += __shfl_xor(ps, msk);
      l[r] = l[r] * sc[r] + ps;
    }
    #pragma unroll
    for (int r = 0; r < 4; ++r) { o0[r] *= sc[r]; o1[r] *= sc[r]; }
    const f16x8 a0 = *(const f16x8*)&Pl[wv][c][kg * 8];
    const f16x8 a1 = *(const f16x8*)&Pl[wv][c][32 + kg * 8];
    o0 = __builtin_amdgcn_mfma_f32_16x16x32_f16(a0, *(const f16x8*)&Vt[c][kg * 8], o0, 0, 0, 0);
    o0 = __builtin_amdgcn_mfma_f32_16x16x32_f16(a1, *(const f16x8*)&Vt[c][32 + kg * 8], o0, 0, 0, 0);
    o1 = __builtin_amdgcn_mfma_f32_16x16x32_f16(a0, *(const f16x8*)&Vt[16 + c][kg * 8], o1, 0, 0, 0);
    o1 = __builtin_amdgcn_mfma_f32_16x16x32_f16(a1, *(const f16x8*)&Vt[16 + c][32 + kg * 8], o1, 0, 0, 0);
  }
  #pragma unroll
  for (int r = 0; r < 4; ++r) {
    const int row = q0 + wv * 16 + kg * 4 + r;
    const float inv = 1.0f / l[r];
    out[((size_t)(b * 896 + row) * 256) + h * 32 + c] = o0[r] * inv;
    out[((size_t)(b * 896 + row) * 256) + h * 32 + 16 + c] = o1[r] * inv;
  }
}

// ---------------------------------------------------------------- build inv table
__global__ __launch_bounds__(1024) void inv_k(const int* __restrict__ pc, int* __restrict__ inv)
{
  const int t = threadIdx.x;
  if (t < 1024) inv[t] = 0;
  __syncthreads();
  if (t < 640) {
    const int wide = (pc[3] == 0);
    int s = wide ? pc[4 * t] : pc[2 * t];
    int coord = wide ? pc[4 * t + 2] : pc[2 * t + 1];
    s &= 1;
    const int gs = 16 << s;
    const int k = 1 << (1 - s);
    const int r = (coord / gs) * k, c = (coord % gs) * k;
    for (int oi = 0; oi < k; ++oi)
      for (int oj = 0; oj < k; ++oj) {
        const int rr = r + oi, cc = c + oj;
        if (rr >= 0 && rr < 32 && cc >= 0 && cc < 32)
          inv[rr * 32 + cc] = t;
      }
  }
}

// ---------------------------------------------------------------- gather masks -> NHWC f16 img
__global__ __launch_bounds__(256) void gather16_k(
    const float* __restrict__ masks, const int* __restrict__ inv, f16* __restrict__ img)
{
  const int p = blockIdx.x & 1023, b = blockIdx.x >> 10, t = threadIdx.x;
  img[((size_t)blockIdx.x << 8) + t] = (f16)masks[((size_t)b * 640 + inv[p]) * 256 + t];
}

// ---------------------------------------------------------------- MFMA conv3x3 (NHWC f16)
__global__ __launch_bounds__(256) void conv3m_k(
    const f16* __restrict__ x, const f16* __restrict__ wf, const float* __restrict__ bias,
    f16* __restrict__ y, int H, int W)
{
  const int tilesx = W >> 4;
  const int ty0 = (blockIdx.x / tilesx) << 4, tx0 = (blockIdx.x % tilesx) << 4;
  const int co0 = blockIdx.y << 6;
  const int b = blockIdx.z;
  const int t = threadIdx.x;
  const int lane = t & 63, wv = t >> 6;
  const int frow = lane & 15, kg = lane >> 4;
  __shared__ f16 halo[18][18][40];
  __shared__ f16 bt3[3][64][40];
  f32x4 acc[4][4];
  #pragma unroll
  for (int i = 0; i < 4; ++i)
    #pragma unroll
    for (int j = 0; j < 4; ++j) acc[i][j] = (f32x4){0.f, 0.f, 0.f, 0.f};

  for (int c0 = 0; c0 < 256; c0 += 32) {
    __syncthreads();
    for (int i = t; i < 1296; i += 256) {
      const int cell = i >> 2, part = i & 3;
      const int hy = cell / 18, hx = cell - hy * 18;
      const int gy = ty0 + hy - 1, gx = tx0 + hx - 1;
      f16x8 v = {(f16)0,(f16)0,(f16)0,(f16)0,(f16)0,(f16)0,(f16)0,(f16)0};
      if (gy >= 0 && gy < H && gx >= 0 && gx < W)
        v = *(const f16x8*)&x[(((size_t)b * H + gy) * W + gx) * 256 + c0 + part * 8];
      *(f16x8*)&halo[hy][hx][part * 8] = v;
    }
    for (int kyr = 0; kyr < 3; ++kyr) {
      __syncthreads();
      for (int i = t; i < 768; i += 256) {
        const int tr = i >> 8, rem = i & 255, co = rem >> 2, part = rem & 3;
        *(f16x8*)&bt3[tr][co][part * 8] =
            *(const f16x8*)&wf[(((size_t)(kyr * 3 + tr)) * 256 + co0 + co) * 256 + c0 + part * 8];
      }
      __syncthreads();
      #pragma unroll
      for (int kx = 0; kx < 3; ++kx) {
        f16x8 af[4], bf[4];
        #pragma unroll
        for (int fm = 0; fm < 4; ++fm) {
          const int pos = wv * 64 + fm * 16 + frow;
          af[fm] = *(const f16x8*)&halo[(pos >> 4) + kyr][(pos & 15) + kx][kg * 8];
        }
        #pragma unroll
        for (int fn = 0; fn < 4; ++fn)
          bf[fn] = *(const f16x8*)&bt3[kx][fn * 16 + frow][kg * 8];
        #pragma unroll
        for (int fm = 0; fm < 4; ++fm)
          #pragma unroll
          for (int fn = 0; fn < 4; ++fn)
            acc[fm][fn] = __builtin_amdgcn_mfma_f32_16x16x32_f16(af[fm], bf[fn], acc[fm][fn], 0, 0, 0);
      }
    }
  }
  #pragma unroll
  for (int fn = 0; fn < 4; ++fn) {
    const int col = co0 + fn * 16 + frow;
    const float bv = bias[col];
    #pragma unroll
    for (int fm = 0; fm < 4; ++fm)
      #pragma unroll
      for (int r = 0; r < 4; ++r) {
        const int pos = wv * 64 + fm * 16 + kg * 4 + r;
        y[(((size_t)b * H + ty0 + (pos >> 4)) * W + tx0 + (pos & 15)) * 256 + col] =
            (f16)(acc[fm][fn][r] + bv);
      }
  }
}

// ---------------------------------------------------------------- MFMA convT 2x2 s2
__global__ __launch_bounds__(256) void convtm_k(
    const f16* __restrict__ x, const f16* __restrict__ wtp, const float* __restrict__ bias,
    f16* __restrict__ y, int H, int W)
{
  const int tilesx = W >> 4;
  const int ty0 = (blockIdx.x / tilesx) << 4, tx0 = (blockIdx.x % tilesx) << 4;
  const int co0 = (blockIdx.y >> 2) << 6;
  const int par = blockIdx.y & 3;
  const int pa = par >> 1, pb = par & 1;
  const int b = blockIdx.z;
  const int t = threadIdx.x;
  const int lane = t & 63, wv = t >> 6;
  const int frow = lane & 15, kg = lane >> 4;
  __shared__ f16 at[256][40];
  __shared__ f16 btw[64][40];
  f32x4 acc[4][4];
  #pragma unroll
  for (int i = 0; i < 4; ++i)
    #pragma unroll
    for (int j = 0; j < 4; ++j) acc[i][j] = (f32x4){0.f, 0.f, 0.f, 0.f};

  for (int c0 = 0; c0 < 256; c0 += 32) {
    __syncthreads();
    for (int i = t; i < 1024; i += 256) {
      const int cell = i >> 2, part = i & 3;
      const int gy = ty0 + (cell >> 4), gx = tx0 + (cell & 15);
      *(f16x8*)&at[cell][part * 8] =
          *(const f16x8*)&x[(((size_t)b * H + gy) * W + gx) * 256 + c0 + part * 8];
    }
    {
      const int i = t;
      const int co = i >> 2, part = i & 3;
      *(f16x8*)&btw[co][part * 8] =
          *(const f16x8*)&wtp[((size_t)par * 256 + co0 + co) * 256 + c0 + part * 8];
    }
    __syncthreads();
    f16x8 af[4], bf[4];
    #pragma unroll
    for (int fm = 0; fm < 4; ++fm)
      af[fm] = *(const f16x8*)&at[wv * 64 + fm * 16 + frow][kg * 8];
    #pragma unroll
    for (int fn = 0; fn < 4; ++fn)
      bf[fn] = *(const f16x8*)&btw[fn * 16 + frow][kg * 8];
    #pragma unroll
    for (int fm = 0; fm < 4; ++fm)
      #pragma unroll
      for (int fn = 0; fn < 4; ++fn)
        acc[fm][fn] = __builtin_amdgcn_mfma_f32_16x16x32_f16(af[fm], bf[fn], acc[fm][fn], 0, 0, 0);
  }
  const int HO = H << 1, WO = W << 1;
  #pragma unroll
  for (int fn = 0; fn < 4; ++fn) {
    const int col = co0 + fn * 16 + frow;
    const float bv = bias[col];
    #pragma unroll
    for (int fm = 0; fm < 4; ++fm)
      #pragma unroll
      for (int r = 0; r < 4; ++r) {
        const int pos = wv * 64 + fm * 16 + kg * 4 + r;
        const int oy = ((ty0 + (pos >> 4)) << 1) + pa;
        const int ox = ((tx0 + (pos & 15)) << 1) + pb;
        y[(((size_t)b * HO + oy) * WO + ox) * 256 + col] = (f16)(acc[fm][fn][r] + bv);
      }
  }
}

// ---------------------------------------------------------------- instance-norm stats + normalize
__global__ __launch_bounds__(256) void stats1_k(
    const f16* __restrict__ x, float2* __restrict__ partial, int HW, int NS)
{
  const int s = blockIdx.x, b = blockIdx.y, t = threadIdx.x;
  const int rpb = HW / NS;
  const f16* p = x + ((size_t)b * HW + (size_t)s * rpb) * 256;
  float s1 = 0.f, s2 = 0.f;
  for (int r = 0; r < rpb; ++r) {
    const float v = (float)p[(size_t)r * 256 + t];
    s1 += v; s2 += v * v;
  }
  partial[((size_t)b * NS + s) * 256 + t] = make_float2(s1, s2);
}
__global__ __launch_bounds__(256) void stats2_k(
    const float2* __restrict__ partial, float2* __restrict__ mr, int HW, int NS)
{
  const int b = blockIdx.x, t = threadIdx.x;
  float s1 = 0.f, s2 = 0.f;
  for (int s = 0; s < NS; ++s) {
    const float2 v = partial[((size_t)b * NS + s) * 256 + t];
    s1 += v.x; s2 += v.y;
  }
  const float m = s1 / (float)HW;
  const float var = fmaxf(s2 / (float)HW - m * m, 0.f);
  mr[b * 256 + t] = make_float2(m, rsqrtf(var + 1e-5f));
}
__global__ __launch_bounds__(256) void norm_k(
    f16* __restrict__ x, const float2* __restrict__ mr, int HW)
{
  const int b = blockIdx.y, t = threadIdx.x;
  const float2 v = mr[b * 256 + t];
  f16* p = x + ((size_t)b * HW + (size_t)blockIdx.x * 8) * 256;
  #pragma unroll
  for (int r = 0; r < 8; ++r) {
    float z = ((float)p[(size_t)r * 256 + t] - v.x) * v.y;
    p[(size_t)r * 256 + t] = (f16)(z >= 0.f ? z : 0.01f * z);
  }
}

// ---------------------------------------------------------------- out conv 3x3: 256 -> 3, direct
// one thread per output pixel; x from global (L1-amortized halo), weights wave-uniform scalar loads
__global__ __launch_bounds__(256) void convout2_k(
    const f16* __restrict__ x, const float* __restrict__ wT,
    const float* __restrict__ bias, void* __restrict__ yv, const int* __restrict__ flags)
{
  const int ty0 = (blockIdx.x >> 4) << 4, tx0 = (blockIdx.x & 15) << 4;
  const int b = blockIdx.y, t = threadIdx.x;
  const int oy = ty0 + (t >> 4), ox = tx0 + (t & 15);
  const f16* xb = x + ((size_t)b << 24);        // b * 256*256*256
  float acc0 = 0.f, acc1 = 0.f, acc2 = 0.f;
  for (int c0 = 0; c0 < 256; c0 += 8) {
    #pragma unroll
    for (int tap = 0; tap < 9; ++tap) {
      const int gy = oy + tap / 3 - 1, gx = ox + tap % 3 - 1;
      f16x8 xv = {(f16)0,(f16)0,(f16)0,(f16)0,(f16)0,(f16)0,(f16)0,(f16)0};
      if ((unsigned)gy < 256u && (unsigned)gx < 256u)
        xv = *(const f16x8*)&xb[(((size_t)(gy << 8) + gx) << 8) + c0];
      const float* wp = wT + ((size_t)tap * 256 + c0) * 3;   // wave-uniform -> s_load
      #pragma unroll
      for (int j = 0; j < 8; ++j) {
        const float xf = (float)xv[j];
        acc0 += xf * wp[j * 3 + 0];
        acc1 += xf * wp[j * 3 + 1];
        acc2 += xf * wp[j * 3 + 2];
      }
    }
  }
  const int fp32 = flags[0];
  const float o[3] = {acc0 + bias[0], acc1 + bias[1], acc2 + bias[2]};
  #pragma unroll
  for (int co = 0; co < 3; ++co) {
    const size_t oidx = (((size_t)b * 3 + co) * 256 + oy) * 256 + ox;
    if (fp32) ((float*)yv)[oidx] = o[co];
    else      ((bf16*)yv)[oidx] = __float2bfloat16(o[co]);
  }
}

// ================================================================ host
extern "C" void kernel_launch(void* const* d_in, const int* in_sizes, int n_in,
                              void* d_out, int out_size, void* d_ws, size_t ws_size,
                              hipStream_t stream) {
  (void)in_sizes; (void)n_in; (void)out_size; (void)ws_size;
  const int* pc = (const int*)d_in[1];

  float* P = (float*)d_ws;
  size_t off = 0;
  CvtDesc cd{};
  int seg = 0;
  auto alloc = [&](size_t n) { float* p = P + off; off += n; return p; };
  auto allocCv = [&](int idx, size_t n) {
    float* p = P + off;
    cd.src[seg] = d_in[idx]; cd.dstOff[seg] = (unsigned)off; cd.n[seg] = (unsigned)n;
    ++seg; off += n; return p;
  };

  // ---- persistent small region ----
  int*    flags   = (int*)alloc(16);
  int*    invbuf  = (int*)alloc(1024);
  float2* partial = (float2*)alloc(131072);
  float2* mr1     = (float2*)alloc(1024);
  float* pdb   = allocCv(3, 256);
  float* pw1   = allocCv(4, 512);
  float* pb1   = allocCv(5, 256);
  float* pb2   = allocCv(7, 256);
  float* pln1g = allocCv(9, 512);
  float* pln1b = allocCv(10, 512);
  float* pqkvb = allocCv(12, 1536);
  float* pattb = allocCv(14, 512);
  float* pln2g = allocCv(15, 512);
  float* pln2b = allocCv(16, 512);
  float* pm1b  = allocCv(18, 2048);
  float* pm2b  = allocCv(20, 512);
  float* pdecg = allocCv(21, 256);
  float* pdecb = allocCv(22, 256);
  float* pmg   = allocCv(25, 256);
  float* pmb   = allocCv(26, 256);
  float* pucb  = allocCv(28, 768);
  float* putb  = allocCv(30, 768);
  float* pocw  = allocCv(31, 6912);
  float* pocb  = allocCv(32, 16);
  float* pocwT = alloc(6928);
  off = (off + 255) & ~(size_t)255;
  f16* wf3 = (f16*)alloc(884736);
  f16* wt  = (f16*)alloc(393216);
  off = (off + 255) & ~(size_t)255;

  // ---- zone A: big fp32 params + transformer scratch, later overlaid by R2 (f16) ----
  float* zoneA = P + off;
  f16*   R2h   = (f16*)zoneA;
  {
    size_t zo = off;
    auto zCv = [&](int idx, size_t n) {
      float* p = P + zo;
      cd.src[seg] = d_in[idx]; cd.dstOff[seg] = (unsigned)zo; cd.n[seg] = (unsigned)n;
      ++seg; zo += n; return p;
    };
    float* px    = zCv(0, 655360);
    float* pdw   = zCv(2, 131072);
    float* pw2   = zCv(6, 65536);
    float* pcls  = zCv(8, 65536);
    float* pqkvw = zCv(11, 393216);
    float* pattw = zCv(13, 131072);
    float* pm1w  = zCv(17, 524288);
    float* pm2w  = zCv(19, 524288);
    float* pprp  = zCv(23, 65536);
    float* pprc  = zCv(24, 65536);
    float* pucw  = zCv(27, 1769472);
    float* putw  = zCv(29, 786432);
    float* xbuf   = P + zo; zo += 458752;
    float* hbuf   = P + zo; zo += 458752;
    float* qkvbuf = P + zo; zo += 1376256;
    float* hidbuf = P + zo; zo += 1835008;
    float* posbuf = P + zo; zo += 163840;
    float* patbuf = P + zo; zo += 327680;
    float* clsbuf = P + zo; zo += 131072;
    float* masksb = P + zo; zo += 327680;
    off += 16777216;
    f16* R0h = (f16*)(P + off); off += 4194304;
    f16* R1h = (f16*)(P + off); off += 4194304;

    // 0) detect dtype, convert inputs to fp32, prep f16 conv weights + transposed out-conv weights
    detect_k<<<1, 64, 0, stream>>>((const unsigned short*)d_in[0], flags);
    cvtall_k<<<dim3(256, NSEG), 256, 0, stream>>>(cd, P, flags);
    prepw_k<<<2048, 256, 0, stream>>>(pucw, putw, pocw, wf3, wt, pocwT);

    // 1) positional MLP + patch projection + sequence assembly
    pos_k<<<640, 256, 0, stream>>>(pc, pw1, pb1, pw2, pb2, posbuf);
    gemm_k<false, 0><<<dim3(4, 20), 256, 0, stream>>>(
        px, pdw, pdb, nullptr, hidbuf, 1280, 256, 512);
    assemble_k<<<1792, 256, 0, stream>>>(hidbuf, posbuf, pcls, xbuf);

    // 2) transformer blocks
    for (int l = 0; l < 2; ++l) {
      ln_k<<<1792, 256, 0, stream>>>(xbuf, hbuf, pln1g + l * 256, pln1b + l * 256);
      gemm_k<false, 0><<<dim3(12, 28), 256, 0, stream>>>(
          hbuf, pqkvw + (size_t)l * 196608, pqkvb + l * 768, nullptr, qkvbuf, 1792, 768, 256);
      attnm_k<<<dim3(28, 8, 2), 128, 0, stream>>>(qkvbuf, hbuf);
      gemm_k<false, 0><<<dim3(4, 28), 256, 0, stream>>>(
          hbuf, pattw + (size_t)l * 65536, pattb + l * 256, xbuf, xbuf, 1792, 256, 256);
      ln_k<<<1792, 256, 0, stream>>>(xbuf, hbuf, pln2g + l * 256, pln2b + l * 256);
      gemm_k<false, 1><<<dim3(16, 28), 256, 0, stream>>>(
          hbuf, pm1w + (size_t)l * 262144, pm1b + l * 1024, nullptr, hidbuf, 1792, 1024, 256);
      gemm_k<false, 0><<<dim3(4, 28), 256, 0, stream>>>(
          hidbuf, pm2w + (size_t)l * 262144, pm2b + l * 256, xbuf, xbuf, 1792, 256, 1024);
    }

    // 3) decoder head
    ln_k<<<1792, 256, 0, stream>>>(xbuf, hbuf, pdecg, pdecb);
    for (int b = 0; b < 2; ++b) {
      gemm_k<false, 0><<<dim3(4, 10), 256, 0, stream>>>(
          hbuf + (size_t)b * 896 * 256, pprp, nullptr, nullptr,
          patbuf + (size_t)b * 640 * 256, 640, 256, 256);
      gemm_k<false, 0><<<dim3(4, 4), 256, 0, stream>>>(
          hbuf + ((size_t)b * 896 + 640) * 256, pprc, nullptr, nullptr,
          clsbuf + (size_t)b * 65536, 256, 256, 256);
    }
    l2n_k<<<1280, 256, 0, stream>>>(patbuf);
    l2n_k<<<512, 256, 0, stream>>>(clsbuf);
    for (int b = 0; b < 2; ++b) {
      gemm_k<true, 0><<<dim3(4, 10), 256, 0, stream>>>(
          patbuf + (size_t)b * 163840, clsbuf + (size_t)b * 65536, nullptr, nullptr,
          masksb + (size_t)b * 163840, 640, 256, 256);
    }
    ln_k<<<1280, 256, 0, stream>>>(masksb, masksb, pmg, pmb);

    // 4) scatter table + gather (NHWC f16)
    inv_k<<<1, 1024, 0, stream>>>(pc, invbuf);
    gather16_k<<<2048, 256, 0, stream>>>(masksb, invbuf, R0h);

    // 5) MFMA conv decoder
    const int NS = 128;
    int H = 32;
    for (int i = 0; i < 3; ++i) {
      conv3m_k<<<dim3((H / 16) * (H / 16), 4, 2), 256, 0, stream>>>(
          R0h, wf3 + (size_t)i * 9 * 65536, pucb + i * 256, R1h, H, H);
      stats1_k<<<dim3(NS, 2), 256, 0, stream>>>(R1h, partial, H * H, NS);
      stats2_k<<<2, 256, 0, stream>>>(partial, mr1, H * H, NS);
      norm_k<<<dim3(H * H / 8, 2), 256, 0, stream>>>(R1h, mr1, H * H);
      f16* dst = (i == 2) ? R2h : R0h;
      convtm_k<<<dim3((H / 16) * (H / 16), 16, 2), 256, 0, stream>>>(
          R1h, wt + (size_t)i * 4 * 65536, putb + i * 256, dst, H, H);
      stats1_k<<<dim3(NS, 2), 256, 0, stream>>>(dst, partial, 4 * H * H, NS);
      stats2_k<<<2, 256, 0, stream>>>(partial, mr1, 4 * H * H, NS);
      norm_k<<<dim3(4 * H * H / 8, 2), 256, 0, stream>>>(dst, mr1, 4 * H * H);
      H *= 2;
    }

    // 6) output conv 256 -> 3 (direct, no LDS)
    convout2_k<<<dim3(256, 2), 256, 0, stream>>>(R2h, pocwT, pocb, d_out, flags);
  }
}

// Round 8
// 1333.904 us; speedup vs baseline: 2.9119x; 1.0492x over previous
//
#include <hip/hip_runtime.h>
#include <hip/hip_bf16.h>

typedef __hip_bfloat16 bf16;
typedef _Float16 f16;
typedef __attribute__((ext_vector_type(8))) _Float16 f16x8;
typedef __attribute__((ext_vector_type(4))) float f32x4;

// ---------------------------------------------------------------- dtype detector
__global__ void detect_k(const unsigned short* __restrict__ xh, int* __restrict__ flags)
{
  if (threadIdx.x == 0 && blockIdx.x == 0) {
    int weird = 0;
    for (int i = 0; i < 512; ++i) {
      const int e = (xh[i] >> 7) & 0xFF;
      if (e == 0xFF || e >= 0x88) ++weird;
    }
    flags[0] = (weird > 32) ? 1 : 0;
  }
}

// ---------------------------------------------------------------- batched input->fp32 convert
#define NSEG 33
struct CvtDesc {
  const void* src[NSEG];
  unsigned dstOff[NSEG];
  unsigned n[NSEG];
};
__global__ __launch_bounds__(256) void cvtall_k(
    CvtDesc d, float* __restrict__ P, const int* __restrict__ flags)
{
  const int s = blockIdx.y;
  const unsigned n = d.n[s];
  const int fp32 = flags[0];
  float* dst = P + d.dstOff[s];
  const unsigned stride = gridDim.x * 256u;
  if (fp32) {
    const float* src = (const float*)d.src[s];
    for (unsigned i = blockIdx.x * 256u + threadIdx.x; i < n; i += stride) dst[i] = src[i];
  } else {
    const bf16* src = (const bf16*)d.src[s];
    for (unsigned i = blockIdx.x * 256u + threadIdx.x; i < n; i += stride)
      dst[i] = __bfloat162float(src[i]);
  }
}

// ---------------------------------------------------------------- conv weight prep
__global__ __launch_bounds__(256) void prepw_k(
    const float* __restrict__ ucw, const float* __restrict__ utw, const float* __restrict__ ocw,
    f16* __restrict__ wf3, f16* __restrict__ wt, float* __restrict__ ocwT)
{
  const int n1 = 3 * 9 * 65536;
  const int n2 = 3 * 4 * 65536;
  const int n3 = 6912;
  for (int i = blockIdx.x * 256 + threadIdx.x; i < n1 + n2 + n3; i += gridDim.x * 256) {
    if (i < n1) {
      const int st = i / 589824, r = i % 589824;
      const int kk = r / 65536, rr = r % 65536;
      const int co = rr >> 8, ci = rr & 255;
      wf3[i] = (f16)ucw[(((size_t)st * 256 + co) * 256 + ci) * 9 + kk];
    } else if (i < n1 + n2) {
      const int j = i - n1;
      const int st = j / 262144, r = j % 262144;
      const int ij = r / 65536, rr = r % 65536;
      const int co = rr >> 8, ci = rr & 255;
      wt[j] = (f16)utw[(((size_t)st * 256 + ci) * 256 + co) * 4 + ij];
    } else {
      const int j = i - n1 - n2;
      const int co = j % 3, r = j / 3;
      const int tap = r >> 8, ci = r & 255;
      ocwT[j] = ocw[((size_t)co * 256 + ci) * 9 + tap];
    }
  }
}

// ---------------------------------------------------------------- MFMA GEMM (fp32 io, f16 compute)
// C(M,N) = act(A @ B + bias) + res. 128x128 tile, 4 waves, BK=32.
// B is (K,N) fp32, or (N,K) if TRB.
template<bool TRB, int ACT>
__global__ __launch_bounds__(256) void gemm16_k(
    const float* __restrict__ A, const float* __restrict__ B,
    const float* __restrict__ bias, const float* __restrict__ res,
    float* __restrict__ C, int M, int N, int K)
{
  const int m0 = blockIdx.y << 7, n0 = blockIdx.x << 7;
  const int t = threadIdx.x;
  const int lane = t & 63, wv = t >> 6;
  const int wm = wv >> 1, wn = wv & 1;
  const int frow = lane & 15, kg = lane >> 4;
  __shared__ f16 As[128][40];
  __shared__ f16 Bs[128][40];
  f32x4 acc[4][4];
  #pragma unroll
  for (int i = 0; i < 4; ++i)
    #pragma unroll
    for (int j = 0; j < 4; ++j) acc[i][j] = (f32x4){0.f, 0.f, 0.f, 0.f};

  for (int k0 = 0; k0 < K; k0 += 32) {
    __syncthreads();
    {
      const int row = t >> 1, kh = (t & 1) << 4;
      const float* ap = A + (size_t)(m0 + row) * K + k0 + kh;
      #pragma unroll
      for (int j = 0; j < 16; ++j) As[row][kh + j] = (f16)ap[j];
    }
    if (TRB) {
      const int row = t >> 1, kh = (t & 1) << 4;
      const float* bp = B + (size_t)(n0 + row) * K + k0 + kh;
      #pragma unroll
      for (int j = 0; j < 16; ++j) Bs[row][kh + j] = (f16)bp[j];
    } else {
      #pragma unroll
      for (int i2 = 0; i2 < 16; ++i2) {
        const int i = i2 * 256 + t;
        const int n = i & 127, kk = i >> 7;
        Bs[n][kk] = (f16)B[(size_t)(k0 + kk) * N + n0 + n];
      }
    }
    __syncthreads();
    f16x8 af[4], bf[4];
    #pragma unroll
    for (int fm = 0; fm < 4; ++fm)
      af[fm] = *(const f16x8*)&As[wm * 64 + fm * 16 + frow][kg * 8];
    #pragma unroll
    for (int fn = 0; fn < 4; ++fn)
      bf[fn] = *(const f16x8*)&Bs[wn * 64 + fn * 16 + frow][kg * 8];
    #pragma unroll
    for (int fm = 0; fm < 4; ++fm)
      #pragma unroll
      for (int fn = 0; fn < 4; ++fn)
        acc[fm][fn] = __builtin_amdgcn_mfma_f32_16x16x32_f16(af[fm], bf[fn], acc[fm][fn], 0, 0, 0);
  }
  #pragma unroll
  for (int fn = 0; fn < 4; ++fn) {
    const int col = n0 + wn * 64 + fn * 16 + frow;
    const float bv = bias ? bias[col] : 0.f;
    #pragma unroll
    for (int fm = 0; fm < 4; ++fm)
      #pragma unroll
      for (int r = 0; r < 4; ++r) {
        const int row = m0 + wm * 64 + fm * 16 + kg * 4 + r;
        float v = acc[fm][fn][r] + bv;
        if (ACT == 1) v = 0.5f * v * (1.0f + erff(v * 0.70710678118654752f));
        if (res) v += res[(size_t)row * N + col];
        C[(size_t)row * N + col] = v;
      }
  }
}

// ---------------------------------------------------------------- LayerNorm (row len 256)
__global__ __launch_bounds__(256) void ln_k(
    const float* __restrict__ in, float* __restrict__ out,
    const float* __restrict__ g, const float* __restrict__ b)
{
  const int row = blockIdx.x, t = threadIdx.x;
  __shared__ float red[256];
  float x = in[(size_t)row * 256 + t];
  red[t] = x; __syncthreads();
  for (int s = 128; s > 0; s >>= 1) { if (t < s) red[t] += red[t + s]; __syncthreads(); }
  const float m = red[0] * (1.0f / 256.0f);
  __syncthreads();
  const float d = x - m;
  red[t] = d * d; __syncthreads();
  for (int s = 128; s > 0; s >>= 1) { if (t < s) red[t] += red[t + s]; __syncthreads(); }
  const float rstd = rsqrtf(red[0] * (1.0f / 256.0f) + 1e-5f);
  out[(size_t)row * 256 + t] = d * rstd * g[t] + b[t];
}

// ---------------------------------------------------------------- L2 normalize rows
__global__ __launch_bounds__(256) void l2n_k(float* __restrict__ x)
{
  const int row = blockIdx.x, t = threadIdx.x;
  __shared__ float red[256];
  float v = x[(size_t)row * 256 + t];
  red[t] = v * v; __syncthreads();
  for (int s = 128; s > 0; s >>= 1) { if (t < s) red[t] += red[t + s]; __syncthreads(); }
  x[(size_t)row * 256 + t] = v * rsqrtf(red[0]);
}

// ---------------------------------------------------------------- pos MLP
__global__ __launch_bounds__(256) void pos_k(
    const int* __restrict__ pc, const float* __restrict__ w1, const float* __restrict__ b1,
    const float* __restrict__ w2, const float* __restrict__ b2, float* __restrict__ pos)
{
  const int n = blockIdx.x, t = threadIdx.x;
  __shared__ float h[256];
  const int wide = (pc[3] == 0);
  const int sv = wide ? pc[4 * n] : pc[2 * n];
  const int cv = wide ? pc[4 * n + 2] : pc[2 * n + 1];
  float hv = (float)sv * w1[t] + (float)cv * w1[256 + t] + b1[t];
  h[t] = hv > 0.0f ? hv : 0.0f;
  __syncthreads();
  float acc = b2[t];
  for (int k = 0; k < 256; ++k) acc += h[k] * w2[k * 256 + t];
  pos[n * 256 + t] = acc;
}

// ---------------------------------------------------------------- assemble x = [proj+pos ; cls]
__global__ __launch_bounds__(256) void assemble_k(
    const float* __restrict__ proj, const float* __restrict__ pos,
    const float* __restrict__ cls, float* __restrict__ xb)
{
  const int row = blockIdx.x;
  const int b = row / 896, n = row % 896, t = threadIdx.x;
  float v;
  if (n < 640) v = proj[((size_t)b * 640 + n) * 256 + t] + pos[n * 256 + t];
  else         v = cls[(n - 640) * 256 + t];
  xb[(size_t)row * 256 + t] = v;
}

// ---------------------------------------------------------------- MFMA flash attention
__global__ __launch_bounds__(128) void attnm_k(
    const float* __restrict__ qkv, float* __restrict__ out)
{
  const int q0 = blockIdx.x << 5;
  const int h = blockIdx.y, b = blockIdx.z;
  const int t = threadIdx.x;
  const int lane = t & 63, wv = t >> 6;
  const int c = lane & 15, kg = lane >> 4;
  __shared__ f16 Qs[32][36];
  __shared__ f16 Ks[64][36];
  __shared__ f16 Vt[32][68];
  __shared__ f16 Pl[2][16][68];
  {
    const int row = t >> 2, part = t & 3;
    const float* src = qkv + ((size_t)(b * 896 + q0 + row) * 768) + h * 32 + part * 8;
    f16 tmp[8];
    #pragma unroll
    for (int j = 0; j < 8; ++j) tmp[j] = (f16)(src[j] * 0.17677669529663687f);
    *(f16x8*)&Qs[row][part * 8] = *(const f16x8*)tmp;
  }
  const f32x4 z4 = {0.f, 0.f, 0.f, 0.f};
  f32x4 o0 = z4, o1 = z4;
  float m[4] = {-1e30f, -1e30f, -1e30f, -1e30f};
  float l[4] = {0.f, 0.f, 0.f, 0.f};

  for (int k0 = 0; k0 < 896; k0 += 64) {
    __syncthreads();
    for (int i = t; i < 256; i += 128) {
      const int row = i >> 2, part = i & 3;
      const float* src = qkv + ((size_t)(b * 896 + k0 + row) * 768) + 256 + h * 32 + part * 8;
      f16 tmp[8];
      #pragma unroll
      for (int j = 0; j < 8; ++j) tmp[j] = (f16)src[j];
      *(f16x8*)&Ks[row][part * 8] = *(const f16x8*)tmp;
    }
    for (int i = t; i < 256; i += 128) {
      const int row = i >> 2, part = i & 3;
      const float* src = qkv + ((size_t)(b * 896 + k0 + row) * 768) + 512 + h * 32 + part * 8;
      #pragma unroll
      for (int j = 0; j < 8; ++j) Vt[part * 8 + j][row] = (f16)src[j];
    }
    __syncthreads();
    const f16x8 aq = *(const f16x8*)&Qs[wv * 16 + c][kg * 8];
    f32x4 s[4];
    #pragma unroll
    for (int fn = 0; fn < 4; ++fn)
      s[fn] = __builtin_amdgcn_mfma_f32_16x16x32_f16(
          aq, *(const f16x8*)&Ks[fn * 16 + c][kg * 8], z4, 0, 0, 0);
    float sc[4];
    #pragma unroll
    for (int r = 0; r < 4; ++r) {
      float v = fmaxf(fmaxf(s[0][r], s[1][r]), fmaxf(s[2][r], s[3][r]));
      #pragma unroll
      for (int msk = 1; msk < 16; msk <<= 1) v = fmaxf(v, __shfl_xor(v, msk));
      const float mn = fmaxf(m[r], v);
      sc[r] = __expf(m[r] - mn);
      m[r] = mn;
    }
    #pragma unroll
    for (int r = 0; r < 4; ++r) {
      float ps = 0.f;
      #pragma unroll
      for (int fn = 0; fn < 4; ++fn) {
        const float p = __expf(s[fn][r] - m[r]);
        ps += p;
        Pl[wv][kg * 4 + r][fn * 16 + c] = (f16)p;
      }
      #pragma unroll
      for (int msk = 1; msk < 16; msk <<= 1) ps += __shfl_xor(ps, msk);
      l[r] = l[r] * sc[r] + ps;
    }
    #pragma unroll
    for (int r = 0; r < 4; ++r) { o0[r] *= sc[r]; o1[r] *= sc[r]; }
    const f16x8 a0 = *(const f16x8*)&Pl[wv][c][kg * 8];
    const f16x8 a1 = *(const f16x8*)&Pl[wv][c][32 + kg * 8];
    o0 = __builtin_amdgcn_mfma_f32_16x16x32_f16(a0, *(const f16x8*)&Vt[c][kg * 8], o0, 0, 0, 0);
    o0 = __builtin_amdgcn_mfma_f32_16x16x32_f16(a1, *(const f16x8*)&Vt[c][32 + kg * 8], o0, 0, 0, 0);
    o1 = __builtin_amdgcn_mfma_f32_16x16x32_f16(a0, *(const f16x8*)&Vt[16 + c][kg * 8], o1, 0, 0, 0);
    o1 = __builtin_amdgcn_mfma_f32_16x16x32_f16(a1, *(const f16x8*)&Vt[16 + c][32 + kg * 8], o1, 0, 0, 0);
  }
  #pragma unroll
  for (int r = 0; r < 4; ++r) {
    const int row = q0 + wv * 16 + kg * 4 + r;
    const float inv = 1.0f / l[r];
    out[((size_t)(b * 896 + row) * 256) + h * 32 + c] = o0[r] * inv;
    out[((size_t)(b * 896 + row) * 256) + h * 32 + 16 + c] = o1[r] * inv;
  }
}

// ---------------------------------------------------------------- build inv table
__global__ __launch_bounds__(1024) void inv_k(const int* __restrict__ pc, int* __restrict__ inv)
{
  const int t = threadIdx.x;
  if (t < 1024) inv[t] = 0;
  __syncthreads();
  if (t < 640) {
    const int wide = (pc[3] == 0);
    int s = wide ? pc[4 * t] : pc[2 * t];
    int coord = wide ? pc[4 * t + 2] : pc[2 * t + 1];
    s &= 1;
    const int gs = 16 << s;
    const int k = 1 << (1 - s);
    const int r = (coord / gs) * k, c = (coord % gs) * k;
    for (int oi = 0; oi < k; ++oi)
      for (int oj = 0; oj < k; ++oj) {
        const int rr = r + oi, cc = c + oj;
        if (rr >= 0 && rr < 32 && cc >= 0 && cc < 32)
          inv[rr * 32 + cc] = t;
      }
  }
}

// ---------------------------------------------------------------- gather masks -> NHWC f16 img
__global__ __launch_bounds__(256) void gather16_k(
    const float* __restrict__ masks, const int* __restrict__ inv, f16* __restrict__ img)
{
  const int p = blockIdx.x & 1023, b = blockIdx.x >> 10, t = threadIdx.x;
  img[((size_t)blockIdx.x << 8) + t] = (f16)masks[((size_t)b * 640 + inv[p]) * 256 + t];
}

// ---------------------------------------------------------------- MFMA conv3x3 (NHWC f16)
__global__ __launch_bounds__(256) void conv3m_k(
    const f16* __restrict__ x, const f16* __restrict__ wf, const float* __restrict__ bias,
    f16* __restrict__ y, int H, int W)
{
  const int tilesx = W >> 4;
  const int ty0 = (blockIdx.x / tilesx) << 4, tx0 = (blockIdx.x % tilesx) << 4;
  const int co0 = blockIdx.y << 6;
  const int b = blockIdx.z;
  const int t = threadIdx.x;
  const int lane = t & 63, wv = t >> 6;
  const int frow = lane & 15, kg = lane >> 4;
  __shared__ f16 halo[18][18][40];
  __shared__ f16 bt3[3][64][40];
  f32x4 acc[4][4];
  #pragma unroll
  for (int i = 0; i < 4; ++i)
    #pragma unroll
    for (int j = 0; j < 4; ++j) acc[i][j] = (f32x4){0.f, 0.f, 0.f, 0.f};

  for (int c0 = 0; c0 < 256; c0 += 32) {
    __syncthreads();
    for (int i = t; i < 1296; i += 256) {
      const int cell = i >> 2, part = i & 3;
      const int hy = cell / 18, hx = cell - hy * 18;
      const int gy = ty0 + hy - 1, gx = tx0 + hx - 1;
      f16x8 v = {(f16)0,(f16)0,(f16)0,(f16)0,(f16)0,(f16)0,(f16)0,(f16)0};
      if (gy >= 0 && gy < H && gx >= 0 && gx < W)
        v = *(const f16x8*)&x[(((size_t)b * H + gy) * W + gx) * 256 + c0 + part * 8];
      *(f16x8*)&halo[hy][hx][part * 8] = v;
    }
    for (int kyr = 0; kyr < 3; ++kyr) {
      __syncthreads();
      for (int i = t; i < 768; i += 256) {
        const int tr = i >> 8, rem = i & 255, co = rem >> 2, part = rem & 3;
        *(f16x8*)&bt3[tr][co][part * 8] =
            *(const f16x8*)&wf[(((size_t)(kyr * 3 + tr)) * 256 + co0 + co) * 256 + c0 + part * 8];
      }
      __syncthreads();
      #pragma unroll
      for (int kx = 0; kx < 3; ++kx) {
        f16x8 af[4], bf[4];
        #pragma unroll
        for (int fm = 0; fm < 4; ++fm) {
          const int pos = wv * 64 + fm * 16 + frow;
          af[fm] = *(const f16x8*)&halo[(pos >> 4) + kyr][(pos & 15) + kx][kg * 8];
        }
        #pragma unroll
        for (int fn = 0; fn < 4; ++fn)
          bf[fn] = *(const f16x8*)&bt3[kx][fn * 16 + frow][kg * 8];
        #pragma unroll
        for (int fm = 0; fm < 4; ++fm)
          #pragma unroll
          for (int fn = 0; fn < 4; ++fn)
            acc[fm][fn] = __builtin_amdgcn_mfma_f32_16x16x32_f16(af[fm], bf[fn], acc[fm][fn], 0, 0, 0);
      }
    }
  }
  #pragma unroll
  for (int fn = 0; fn < 4; ++fn) {
    const int col = co0 + fn * 16 + frow;
    const float bv = bias[col];
    #pragma unroll
    for (int fm = 0; fm < 4; ++fm)
      #pragma unroll
      for (int r = 0; r < 4; ++r) {
        const int pos = wv * 64 + fm * 16 + kg * 4 + r;
        y[(((size_t)b * H + ty0 + (pos >> 4)) * W + tx0 + (pos & 15)) * 256 + col] =
            (f16)(acc[fm][fn][r] + bv);
      }
  }
}

// ---------------------------------------------------------------- MFMA convT 2x2 s2
__global__ __launch_bounds__(256) void convtm_k(
    const f16* __restrict__ x, const f16* __restrict__ wtp, const float* __restrict__ bias,
    f16* __restrict__ y, int H, int W)
{
  const int tilesx = W >> 4;
  const int ty0 = (blockIdx.x / tilesx) << 4, tx0 = (blockIdx.x % tilesx) << 4;
  const int co0 = (blockIdx.y >> 2) << 6;
  const int par = blockIdx.y & 3;
  const int pa = par >> 1, pb = par & 1;
  const int b = blockIdx.z;
  const int t = threadIdx.x;
  const int lane = t & 63, wv = t >> 6;
  const int frow = lane & 15, kg = lane >> 4;
  __shared__ f16 at[256][40];
  __shared__ f16 btw[64][40];
  f32x4 acc[4][4];
  #pragma unroll
  for (int i = 0; i < 4; ++i)
    #pragma unroll
    for (int j = 0; j < 4; ++j) acc[i][j] = (f32x4){0.f, 0.f, 0.f, 0.f};

  for (int c0 = 0; c0 < 256; c0 += 32) {
    __syncthreads();
    for (int i = t; i < 1024; i += 256) {
      const int cell = i >> 2, part = i & 3;
      const int gy = ty0 + (cell >> 4), gx = tx0 + (cell & 15);
      *(f16x8*)&at[cell][part * 8] =
          *(const f16x8*)&x[(((size_t)b * H + gy) * W + gx) * 256 + c0 + part * 8];
    }
    {
      const int i = t;
      const int co = i >> 2, part = i & 3;
      *(f16x8*)&btw[co][part * 8] =
          *(const f16x8*)&wtp[((size_t)par * 256 + co0 + co) * 256 + c0 + part * 8];
    }
    __syncthreads();
    f16x8 af[4], bf[4];
    #pragma unroll
    for (int fm = 0; fm < 4; ++fm)
      af[fm] = *(const f16x8*)&at[wv * 64 + fm * 16 + frow][kg * 8];
    #pragma unroll
    for (int fn = 0; fn < 4; ++fn)
      bf[fn] = *(const f16x8*)&btw[fn * 16 + frow][kg * 8];
    #pragma unroll
    for (int fm = 0; fm < 4; ++fm)
      #pragma unroll
      for (int fn = 0; fn < 4; ++fn)
        acc[fm][fn] = __builtin_amdgcn_mfma_f32_16x16x32_f16(af[fm], bf[fn], acc[fm][fn], 0, 0, 0);
  }
  const int HO = H << 1, WO = W << 1;
  #pragma unroll
  for (int fn = 0; fn < 4; ++fn) {
    const int col = co0 + fn * 16 + frow;
    const float bv = bias[col];
    #pragma unroll
    for (int fm = 0; fm < 4; ++fm)
      #pragma unroll
      for (int r = 0; r < 4; ++r) {
        const int pos = wv * 64 + fm * 16 + kg * 4 + r;
        const int oy = ((ty0 + (pos >> 4)) << 1) + pa;
        const int ox = ((tx0 + (pos & 15)) << 1) + pb;
        y[(((size_t)b * HO + oy) * WO + ox) * 256 + col] = (f16)(acc[fm][fn][r] + bv);
      }
  }
}

// ---------------------------------------------------------------- instance-norm stats + normalize
__global__ __launch_bounds__(256) void stats1_k(
    const f16* __restrict__ x, float2* __restrict__ partial, int HW, int NS)
{
  const int s = blockIdx.x, b = blockIdx.y, t = threadIdx.x;
  const int rpb = HW / NS;
  const f16* p = x + ((size_t)b * HW + (size_t)s * rpb) * 256;
  float s1 = 0.f, s2 = 0.f;
  for (int r = 0; r < rpb; ++r) {
    const float v = (float)p[(size_t)r * 256 + t];
    s1 += v; s2 += v * v;
  }
  partial[((size_t)b * NS + s) * 256 + t] = make_float2(s1, s2);
}
__global__ __launch_bounds__(256) void stats2_k(
    const float2* __restrict__ partial, float2* __restrict__ mr, int HW, int NS)
{
  const int b = blockIdx.x, t = threadIdx.x;
  float s1 = 0.f, s2 = 0.f;
  for (int s = 0; s < NS; ++s) {
    const float2 v = partial[((size_t)b * NS + s) * 256 + t];
    s1 += v.x; s2 += v.y;
  }
  const float m = s1 / (float)HW;
  const float var = fmaxf(s2 / (float)HW - m * m, 0.f);
  mr[b * 256 + t] = make_float2(m, rsqrtf(var + 1e-5f));
}
__global__ __launch_bounds__(256) void norm_k(
    f16* __restrict__ x, const float2* __restrict__ mr, int HW)
{
  const int b = blockIdx.y, t = threadIdx.x;
  const float2 v = mr[b * 256 + t];
  f16* p = x + ((size_t)b * HW + (size_t)blockIdx.x * 8) * 256;
  #pragma unroll
  for (int r = 0; r < 8; ++r) {
    float z = ((float)p[(size_t)r * 256 + t] - v.x) * v.y;
    p[(size_t)r * 256 + t] = (f16)(z >= 0.f ? z : 0.01f * z);
  }
}

// ---------------------------------------------------------------- out conv 3x3: split-K partials
// grid (256 tiles, 8 = b*4+cs); each block covers 64 input channels -> fp32 partials
__global__ __launch_bounds__(256) void convout3_k(
    const f16* __restrict__ x, const float* __restrict__ wT, float* __restrict__ part)
{
  const int ty0 = (blockIdx.x >> 4) << 4, tx0 = (blockIdx.x & 15) << 4;
  const int by = blockIdx.y;
  const int b = by >> 2, cs = by & 3;
  const int t = threadIdx.x;
  const int oy = ty0 + (t >> 4), ox = tx0 + (t & 15);
  const f16* xb = x + ((size_t)b << 24);
  float acc0 = 0.f, acc1 = 0.f, acc2 = 0.f;
  const int cbeg = cs << 6;
  for (int c0 = cbeg; c0 < cbeg + 64; c0 += 8) {
    #pragma unroll
    for (int tap = 0; tap < 9; ++tap) {
      const int gy = oy + tap / 3 - 1, gx = ox + tap % 3 - 1;
      f16x8 xv = {(f16)0,(f16)0,(f16)0,(f16)0,(f16)0,(f16)0,(f16)0,(f16)0};
      if ((unsigned)gy < 256u && (unsigned)gx < 256u)
        xv = *(const f16x8*)&xb[(((size_t)(gy << 8) + gx) << 8) + c0];
      const float* wp = wT + ((size_t)tap * 256 + c0) * 3;
      #pragma unroll
      for (int j = 0; j < 8; ++j) {
        const float xf = (float)xv[j];
        acc0 += xf * wp[j * 3 + 0];
        acc1 += xf * wp[j * 3 + 1];
        acc2 += xf * wp[j * 3 + 2];
      }
    }
  }
  const int pix = (oy << 8) + ox;
  part[((size_t)by * 3 + 0) * 65536 + pix] = acc0;
  part[((size_t)by * 3 + 1) * 65536 + pix] = acc1;
  part[((size_t)by * 3 + 2) * 65536 + pix] = acc2;
}
__global__ __launch_bounds__(256) void outfin_k(
    const float* __restrict__ part, const float* __restrict__ bias,
    void* __restrict__ yv, const int* __restrict__ flags)
{
  const int idx = blockIdx.x * 256 + threadIdx.x;   // 2*65536
  const int b = idx >> 16, pix = idx & 65535;
  const int fp32 = flags[0];
  #pragma unroll
  for (int co = 0; co < 3; ++co) {
    float v = bias[co];
    #pragma unroll
    for (int cs = 0; cs < 4; ++cs)
      v += part[((size_t)(b * 4 + cs) * 3 + co) * 65536 + pix];
    const size_t oidx = (((size_t)b * 3 + co) << 16) + pix;
    if (fp32) ((float*)yv)[oidx] = v;
    else      ((bf16*)yv)[oidx] = __float2bfloat16(v);
  }
}

// ================================================================ host
extern "C" void kernel_launch(void* const* d_in, const int* in_sizes, int n_in,
                              void* d_out, int out_size, void* d_ws, size_t ws_size,
                              hipStream_t stream) {
  (void)in_sizes; (void)n_in; (void)out_size; (void)ws_size;
  const int* pc = (const int*)d_in[1];

  float* P = (float*)d_ws;
  size_t off = 0;
  CvtDesc cd{};
  int seg = 0;
  auto alloc = [&](size_t n) { float* p = P + off; off += n; return p; };
  auto allocCv = [&](int idx, size_t n) {
    float* p = P + off;
    cd.src[seg] = d_in[idx]; cd.dstOff[seg] = (unsigned)off; cd.n[seg] = (unsigned)n;
    ++seg; off += n; return p;
  };

  // ---- persistent small region ----
  int*    flags   = (int*)alloc(16);
  int*    invbuf  = (int*)alloc(1024);
  float2* partial = (float2*)alloc(131072);
  float2* mr1     = (float2*)alloc(1024);
  float* pdb   = allocCv(3, 256);
  float* pw1   = allocCv(4, 512);
  float* pb1   = allocCv(5, 256);
  float* pb2   = allocCv(7, 256);
  float* pln1g = allocCv(9, 512);
  float* pln1b = allocCv(10, 512);
  float* pqkvb = allocCv(12, 1536);
  float* pattb = allocCv(14, 512);
  float* pln2g = allocCv(15, 512);
  float* pln2b = allocCv(16, 512);
  float* pm1b  = allocCv(18, 2048);
  float* pm2b  = allocCv(20, 512);
  float* pdecg = allocCv(21, 256);
  float* pdecb = allocCv(22, 256);
  float* pmg   = allocCv(25, 256);
  float* pmb   = allocCv(26, 256);
  float* pucb  = allocCv(28, 768);
  float* putb  = allocCv(30, 768);
  float* pocw  = allocCv(31, 6912);
  float* pocb  = allocCv(32, 16);
  float* pocwT = alloc(6928);
  float* opart = alloc(1572864);               // 8 x 3 x 65536 fp32 out-conv partials
  off = (off + 255) & ~(size_t)255;
  f16* wf3 = (f16*)alloc(884736);
  f16* wt  = (f16*)alloc(393216);
  off = (off + 255) & ~(size_t)255;

  // ---- zone A: big fp32 params + transformer scratch, later overlaid by R2 (f16) ----
  float* zoneA = P + off;
  f16*   R2h   = (f16*)zoneA;
  {
    size_t zo = off;
    auto zCv = [&](int idx, size_t n) {
      float* p = P + zo;
      cd.src[seg] = d_in[idx]; cd.dstOff[seg] = (unsigned)zo; cd.n[seg] = (unsigned)n;
      ++seg; zo += n; return p;
    };
    float* px    = zCv(0, 655360);
    float* pdw   = zCv(2, 131072);
    float* pw2   = zCv(6, 65536);
    float* pcls  = zCv(8, 65536);
    float* pqkvw = zCv(11, 393216);
    float* pattw = zCv(13, 131072);
    float* pm1w  = zCv(17, 524288);
    float* pm2w  = zCv(19, 524288);
    float* pprp  = zCv(23, 65536);
    float* pprc  = zCv(24, 65536);
    float* pucw  = zCv(27, 1769472);
    float* putw  = zCv(29, 786432);
    float* xbuf   = P + zo; zo += 458752;
    float* hbuf   = P + zo; zo += 458752;
    float* qkvbuf = P + zo; zo += 1376256;
    float* hidbuf = P + zo; zo += 1835008;
    float* posbuf = P + zo; zo += 163840;
    float* patbuf = P + zo; zo += 327680;
    float* clsbuf = P + zo; zo += 131072;
    float* masksb = P + zo; zo += 327680;
    off += 16777216;
    f16* R0h = (f16*)(P + off); off += 4194304;
    f16* R1h = (f16*)(P + off); off += 4194304;

    // 0) detect dtype, convert inputs to fp32, prep conv weights
    detect_k<<<1, 64, 0, stream>>>((const unsigned short*)d_in[0], flags);
    cvtall_k<<<dim3(256, NSEG), 256, 0, stream>>>(cd, P, flags);
    prepw_k<<<2048, 256, 0, stream>>>(pucw, putw, pocw, wf3, wt, pocwT);

    // 1) positional MLP + patch projection + sequence assembly
    pos_k<<<640, 256, 0, stream>>>(pc, pw1, pb1, pw2, pb2, posbuf);
    gemm16_k<false, 0><<<dim3(2, 10), 256, 0, stream>>>(
        px, pdw, pdb, nullptr, hidbuf, 1280, 256, 512);
    assemble_k<<<1792, 256, 0, stream>>>(hidbuf, posbuf, pcls, xbuf);

    // 2) transformer blocks (MFMA GEMMs)
    for (int l = 0; l < 2; ++l) {
      ln_k<<<1792, 256, 0, stream>>>(xbuf, hbuf, pln1g + l * 256, pln1b + l * 256);
      gemm16_k<false, 0><<<dim3(6, 14), 256, 0, stream>>>(
          hbuf, pqkvw + (size_t)l * 196608, pqkvb + l * 768, nullptr, qkvbuf, 1792, 768, 256);
      attnm_k<<<dim3(28, 8, 2), 128, 0, stream>>>(qkvbuf, hbuf);
      gemm16_k<false, 0><<<dim3(2, 14), 256, 0, stream>>>(
          hbuf, pattw + (size_t)l * 65536, pattb + l * 256, xbuf, xbuf, 1792, 256, 256);
      ln_k<<<1792, 256, 0, stream>>>(xbuf, hbuf, pln2g + l * 256, pln2b + l * 256);
      gemm16_k<false, 1><<<dim3(8, 14), 256, 0, stream>>>(
          hbuf, pm1w + (size_t)l * 262144, pm1b + l * 1024, nullptr, hidbuf, 1792, 1024, 256);
      gemm16_k<false, 0><<<dim3(2, 14), 256, 0, stream>>>(
          hidbuf, pm2w + (size_t)l * 262144, pm2b + l * 256, xbuf, xbuf, 1792, 256, 1024);
    }

    // 3) decoder head
    ln_k<<<1792, 256, 0, stream>>>(xbuf, hbuf, pdecg, pdecb);
    for (int b = 0; b < 2; ++b) {
      gemm16_k<false, 0><<<dim3(2, 5), 256, 0, stream>>>(
          hbuf + (size_t)b * 896 * 256, pprp, nullptr, nullptr,
          patbuf + (size_t)b * 640 * 256, 640, 256, 256);
      gemm16_k<false, 0><<<dim3(2, 2), 256, 0, stream>>>(
          hbuf + ((size_t)b * 896 + 640) * 256, pprc, nullptr, nullptr,
          clsbuf + (size_t)b * 65536, 256, 256, 256);
    }
    l2n_k<<<1280, 256, 0, stream>>>(patbuf);
    l2n_k<<<512, 256, 0, stream>>>(clsbuf);
    for (int b = 0; b < 2; ++b) {
      gemm16_k<true, 0><<<dim3(2, 5), 256, 0, stream>>>(
          patbuf + (size_t)b * 163840, clsbuf + (size_t)b * 65536, nullptr, nullptr,
          masksb + (size_t)b * 163840, 640, 256, 256);
    }
    ln_k<<<1280, 256, 0, stream>>>(masksb, masksb, pmg, pmb);

    // 4) scatter table + gather (NHWC f16)
    inv_k<<<1, 1024, 0, stream>>>(pc, invbuf);
    gather16_k<<<2048, 256, 0, stream>>>(masksb, invbuf, R0h);

    // 5) MFMA conv decoder
    const int NS = 128;
    int H = 32;
    for (int i = 0; i < 3; ++i) {
      conv3m_k<<<dim3((H / 16) * (H / 16), 4, 2), 256, 0, stream>>>(
          R0h, wf3 + (size_t)i * 9 * 65536, pucb + i * 256, R1h, H, H);
      stats1_k<<<dim3(NS, 2), 256, 0, stream>>>(R1h, partial, H * H, NS);
      stats2_k<<<2, 256, 0, stream>>>(partial, mr1, H * H, NS);
      norm_k<<<dim3(H * H / 8, 2), 256, 0, stream>>>(R1h, mr1, H * H);
      f16* dst = (i == 2) ? R2h : R0h;
      convtm_k<<<dim3((H / 16) * (H / 16), 16, 2), 256, 0, stream>>>(
          R1h, wt + (size_t)i * 4 * 65536, putb + i * 256, dst, H, H);
      stats1_k<<<dim3(NS, 2), 256, 0, stream>>>(dst, partial, 4 * H * H, NS);
      stats2_k<<<2, 256, 0, stream>>>(partial, mr1, 4 * H * H, NS);
      norm_k<<<dim3(4 * H * H / 8, 2), 256, 0, stream>>>(dst, mr1, 4 * H * H);
      H *= 2;
    }

    // 6) output conv 256 -> 3 (split-K partials + finalize)
    convout3_k<<<dim3(256, 8), 256, 0, stream>>>(R2h, pocwT, opart);
    outfin_k<<<512, 256, 0, stream>>>(opart, pocb, d_out, flags);
  }
}

// Round 9
// 1059.566 us; speedup vs baseline: 3.6658x; 1.2589x over previous
//
#include <hip/hip_runtime.h>
#include <hip/hip_bf16.h>

typedef __hip_bfloat16 bf16;
typedef _Float16 f16;
typedef __attribute__((ext_vector_type(8))) _Float16 f16x8;
typedef __attribute__((ext_vector_type(4))) float f32x4;

// ---------------------------------------------------------------- dtype detector
__global__ void detect_k(const unsigned short* __restrict__ xh, int* __restrict__ flags)
{
  if (threadIdx.x == 0 && blockIdx.x == 0) {
    int weird = 0;
    for (int i = 0; i < 512; ++i) {
      const int e = (xh[i] >> 7) & 0xFF;
      if (e == 0xFF || e >= 0x88) ++weird;
    }
    flags[0] = (weird > 32) ? 1 : 0;
  }
}

// ---------------------------------------------------------------- batched input->fp32 convert
#define NSEG 33
struct CvtDesc {
  const void* src[NSEG];
  unsigned dstOff[NSEG];
  unsigned n[NSEG];
};
__global__ __launch_bounds__(256) void cvtall_k(
    CvtDesc d, float* __restrict__ P, const int* __restrict__ flags)
{
  const int s = blockIdx.y;
  const unsigned n = d.n[s];
  const int fp32 = flags[0];
  float* dst = P + d.dstOff[s];
  const unsigned stride = gridDim.x * 256u;
  if (fp32) {
    const float* src = (const float*)d.src[s];
    for (unsigned i = blockIdx.x * 256u + threadIdx.x; i < n; i += stride) dst[i] = src[i];
  } else {
    const bf16* src = (const bf16*)d.src[s];
    for (unsigned i = blockIdx.x * 256u + threadIdx.x; i < n; i += stride)
      dst[i] = __bfloat162float(src[i]);
  }
}

// ---------------------------------------------------------------- conv weight prep
// wf3: [st][9][co][ci] f16 ; wt: [st][4][co][ci] f16 ; wocp: [9][16][256] f16 (co>=3 zero)
__global__ __launch_bounds__(256) void prepw_k(
    const float* __restrict__ ucw, const float* __restrict__ utw, const float* __restrict__ ocw,
    f16* __restrict__ wf3, f16* __restrict__ wt, f16* __restrict__ wocp)
{
  const int n1 = 3 * 9 * 65536;
  const int n2 = 3 * 4 * 65536;
  const int n3 = 9 * 16 * 256;
  for (int i = blockIdx.x * 256 + threadIdx.x; i < n1 + n2 + n3; i += gridDim.x * 256) {
    if (i < n1) {
      const int st = i / 589824, r = i % 589824;
      const int kk = r / 65536, rr = r % 65536;
      const int co = rr >> 8, ci = rr & 255;
      wf3[i] = (f16)ucw[(((size_t)st * 256 + co) * 256 + ci) * 9 + kk];
    } else if (i < n1 + n2) {
      const int j = i - n1;
      const int st = j / 262144, r = j % 262144;
      const int ij = r / 65536, rr = r % 65536;
      const int co = rr >> 8, ci = rr & 255;
      wt[j] = (f16)utw[(((size_t)st * 256 + ci) * 256 + co) * 4 + ij];
    } else {
      const int j = i - n1 - n2;
      const int tap = j >> 12, rem = j & 4095;
      const int co = rem >> 8, ci = rem & 255;
      wocp[j] = (co < 3) ? (f16)ocw[(((size_t)co * 256) + ci) * 9 + tap] : (f16)0.f;
    }
  }
}

// ---------------------------------------------------------------- MFMA GEMM 64x64 tile, 4 waves
// C(M,N) = act(A @ B + bias) + res. B is (K,N) fp32, or (N,K) if TRB. BK=32.
template<bool TRB, int ACT>
__global__ __launch_bounds__(256) void gemm64_k(
    const float* __restrict__ A, const float* __restrict__ B,
    const float* __restrict__ bias, const float* __restrict__ res,
    float* __restrict__ C, int M, int N, int K)
{
  const int m0 = blockIdx.y << 6, n0 = blockIdx.x << 6;
  const int t = threadIdx.x;
  const int lane = t & 63, wv = t >> 6;
  const int wm = wv >> 1, wn = wv & 1;
  const int frow = lane & 15, kg = lane >> 4;
  __shared__ f16 As[64][40];
  __shared__ f16 Bs[64][40];
  f32x4 acc[2][2];
  #pragma unroll
  for (int i = 0; i < 2; ++i)
    #pragma unroll
    for (int j = 0; j < 2; ++j) acc[i][j] = (f32x4){0.f, 0.f, 0.f, 0.f};

  for (int k0 = 0; k0 < K; k0 += 32) {
    __syncthreads();
    {
      const int row = t >> 2, kh = (t & 3) << 3;
      const float* ap = A + (size_t)(m0 + row) * K + k0 + kh;
      #pragma unroll
      for (int j = 0; j < 8; ++j) As[row][kh + j] = (f16)ap[j];
    }
    if (TRB) {
      const int row = t >> 2, kh = (t & 3) << 3;
      const float* bp = B + (size_t)(n0 + row) * K + k0 + kh;
      #pragma unroll
      for (int j = 0; j < 8; ++j) Bs[row][kh + j] = (f16)bp[j];
    } else {
      #pragma unroll
      for (int i2 = 0; i2 < 8; ++i2) {
        const int i = i2 * 256 + t;
        const int n = i & 63, kk = i >> 6;
        Bs[n][kk] = (f16)B[(size_t)(k0 + kk) * N + n0 + n];
      }
    }
    __syncthreads();
    f16x8 af[2], bf[2];
    #pragma unroll
    for (int fm = 0; fm < 2; ++fm)
      af[fm] = *(const f16x8*)&As[wm * 32 + fm * 16 + frow][kg * 8];
    #pragma unroll
    for (int fn = 0; fn < 2; ++fn)
      bf[fn] = *(const f16x8*)&Bs[wn * 32 + fn * 16 + frow][kg * 8];
    #pragma unroll
    for (int fm = 0; fm < 2; ++fm)
      #pragma unroll
      for (int fn = 0; fn < 2; ++fn)
        acc[fm][fn] = __builtin_amdgcn_mfma_f32_16x16x32_f16(af[fm], bf[fn], acc[fm][fn], 0, 0, 0);
  }
  #pragma unroll
  for (int fn = 0; fn < 2; ++fn) {
    const int col = n0 + wn * 32 + fn * 16 + frow;
    const float bv = bias ? bias[col] : 0.f;
    #pragma unroll
    for (int fm = 0; fm < 2; ++fm)
      #pragma unroll
      for (int r = 0; r < 4; ++r) {
        const int row = m0 + wm * 32 + fm * 16 + kg * 4 + r;
        float v = acc[fm][fn][r] + bv;
        if (ACT == 1) v = 0.5f * v * (1.0f + erff(v * 0.70710678118654752f));
        if (res) v += res[(size_t)row * N + col];
        C[(size_t)row * N + col] = v;
      }
  }
}

// ---------------------------------------------------------------- LayerNorm (row len 256)
__global__ __launch_bounds__(256) void ln_k(
    const float* __restrict__ in, float* __restrict__ out,
    const float* __restrict__ g, const float* __restrict__ b)
{
  const int row = blockIdx.x, t = threadIdx.x;
  __shared__ float red[256];
  float x = in[(size_t)row * 256 + t];
  red[t] = x; __syncthreads();
  for (int s = 128; s > 0; s >>= 1) { if (t < s) red[t] += red[t + s]; __syncthreads(); }
  const float m = red[0] * (1.0f / 256.0f);
  __syncthreads();
  const float d = x - m;
  red[t] = d * d; __syncthreads();
  for (int s = 128; s > 0; s >>= 1) { if (t < s) red[t] += red[t + s]; __syncthreads(); }
  const float rstd = rsqrtf(red[0] * (1.0f / 256.0f) + 1e-5f);
  out[(size_t)row * 256 + t] = d * rstd * g[t] + b[t];
}

// ---------------------------------------------------------------- L2 normalize rows
__global__ __launch_bounds__(256) void l2n_k(float* __restrict__ x)
{
  const int row = blockIdx.x, t = threadIdx.x;
  __shared__ float red[256];
  float v = x[(size_t)row * 256 + t];
  red[t] = v * v; __syncthreads();
  for (int s = 128; s > 0; s >>= 1) { if (t < s) red[t] += red[t + s]; __syncthreads(); }
  x[(size_t)row * 256 + t] = v * rsqrtf(red[0]);
}

// ---------------------------------------------------------------- pos MLP
__global__ __launch_bounds__(256) void pos_k(
    const int* __restrict__ pc, const float* __restrict__ w1, const float* __restrict__ b1,
    const float* __restrict__ w2, const float* __restrict__ b2, float* __restrict__ pos)
{
  const int n = blockIdx.x, t = threadIdx.x;
  __shared__ float h[256];
  const int wide = (pc[3] == 0);
  const int sv = wide ? pc[4 * n] : pc[2 * n];
  const int cv = wide ? pc[4 * n + 2] : pc[2 * n + 1];
  float hv = (float)sv * w1[t] + (float)cv * w1[256 + t] + b1[t];
  h[t] = hv > 0.0f ? hv : 0.0f;
  __syncthreads();
  float acc = b2[t];
  for (int k = 0; k < 256; ++k) acc += h[k] * w2[k * 256 + t];
  pos[n * 256 + t] = acc;
}

// ---------------------------------------------------------------- assemble x = [proj+pos ; cls]
__global__ __launch_bounds__(256) void assemble_k(
    const float* __restrict__ proj, const float* __restrict__ pos,
    const float* __restrict__ cls, float* __restrict__ xb)
{
  const int row = blockIdx.x;
  const int b = row / 896, n = row % 896, t = threadIdx.x;
  float v;
  if (n < 640) v = proj[((size_t)b * 640 + n) * 256 + t] + pos[n * 256 + t];
  else         v = cls[(n - 640) * 256 + t];
  xb[(size_t)row * 256 + t] = v;
}

// ---------------------------------------------------------------- MFMA flash attention
__global__ __launch_bounds__(128) void attnm_k(
    const float* __restrict__ qkv, float* __restrict__ out)
{
  const int q0 = blockIdx.x << 5;
  const int h = blockIdx.y, b = blockIdx.z;
  const int t = threadIdx.x;
  const int lane = t & 63, wv = t >> 6;
  const int c = lane & 15, kg = lane >> 4;
  __shared__ f16 Qs[32][36];
  __shared__ f16 Ks[64][36];
  __shared__ f16 Vt[32][68];
  __shared__ f16 Pl[2][16][68];
  {
    const int row = t >> 2, part = t & 3;
    const float* src = qkv + ((size_t)(b * 896 + q0 + row) * 768) + h * 32 + part * 8;
    f16 tmp[8];
    #pragma unroll
    for (int j = 0; j < 8; ++j) tmp[j] = (f16)(src[j] * 0.17677669529663687f);
    *(f16x8*)&Qs[row][part * 8] = *(const f16x8*)tmp;
  }
  const f32x4 z4 = {0.f, 0.f, 0.f, 0.f};
  f32x4 o0 = z4, o1 = z4;
  float m[4] = {-1e30f, -1e30f, -1e30f, -1e30f};
  float l[4] = {0.f, 0.f, 0.f, 0.f};

  for (int k0 = 0; k0 < 896; k0 += 64) {
    __syncthreads();
    for (int i = t; i < 256; i += 128) {
      const int row = i >> 2, part = i & 3;
      const float* src = qkv + ((size_t)(b * 896 + k0 + row) * 768) + 256 + h * 32 + part * 8;
      f16 tmp[8];
      #pragma unroll
      for (int j = 0; j < 8; ++j) tmp[j] = (f16)src[j];
      *(f16x8*)&Ks[row][part * 8] = *(const f16x8*)tmp;
    }
    for (int i = t; i < 256; i += 128) {
      const int row = i >> 2, part = i & 3;
      const float* src = qkv + ((size_t)(b * 896 + k0 + row) * 768) + 512 + h * 32 + part * 8;
      #pragma unroll
      for (int j = 0; j < 8; ++j) Vt[part * 8 + j][row] = (f16)src[j];
    }
    __syncthreads();
    const f16x8 aq = *(const f16x8*)&Qs[wv * 16 + c][kg * 8];
    f32x4 s[4];
    #pragma unroll
    for (int fn = 0; fn < 4; ++fn)
      s[fn] = __builtin_amdgcn_mfma_f32_16x16x32_f16(
          aq, *(const f16x8*)&Ks[fn * 16 + c][kg * 8], z4, 0, 0, 0);
    float sc[4];
    #pragma unroll
    for (int r = 0; r < 4; ++r) {
      float v = fmaxf(fmaxf(s[0][r], s[1][r]), fmaxf(s[2][r], s[3][r]));
      #pragma unroll
      for (int msk = 1; msk < 16; msk <<= 1) v = fmaxf(v, __shfl_xor(v, msk));
      const float mn = fmaxf(m[r], v);
      sc[r] = __expf(m[r] - mn);
      m[r] = mn;
    }
    #pragma unroll
    for (int r = 0; r < 4; ++r) {
      float ps = 0.f;
      #pragma unroll
      for (int fn = 0; fn < 4; ++fn) {
        const float p = __expf(s[fn][r] - m[r]);
        ps += p;
        Pl[wv][kg * 4 + r][fn * 16 + c] = (f16)p;
      }
      #pragma unroll
      for (int msk = 1; msk < 16; msk <<= 1) ps += __shfl_xor(ps, msk);
      l[r] = l[r] * sc[r] + ps;
    }
    #pragma unroll
    for (int r = 0; r < 4; ++r) { o0[r] *= sc[r]; o1[r] *= sc[r]; }
    const f16x8 a0 = *(const f16x8*)&Pl[wv][c][kg * 8];
    const f16x8 a1 = *(const f16x8*)&Pl[wv][c][32 + kg * 8];
    o0 = __builtin_amdgcn_mfma_f32_16x16x32_f16(a0, *(const f16x8*)&Vt[c][kg * 8], o0, 0, 0, 0);
    o0 = __builtin_amdgcn_mfma_f32_16x16x32_f16(a1, *(const f16x8*)&Vt[c][32 + kg * 8], o0, 0, 0, 0);
    o1 = __builtin_amdgcn_mfma_f32_16x16x32_f16(a0, *(const f16x8*)&Vt[16 + c][kg * 8], o1, 0, 0, 0);
    o1 = __builtin_amdgcn_mfma_f32_16x16x32_f16(a1, *(const f16x8*)&Vt[16 + c][32 + kg * 8], o1, 0, 0, 0);
  }
  #pragma unroll
  for (int r = 0; r < 4; ++r) {
    const int row = q0 + wv * 16 + kg * 4 + r;
    const float inv = 1.0f / l[r];
    out[((size_t)(b * 896 + row) * 256) + h * 32 + c] = o0[r] * inv;
    out[((size_t)(b * 896 + row) * 256) + h * 32 + 16 + c] = o1[r] * inv;
  }
}

// ---------------------------------------------------------------- build inv table
__global__ __launch_bounds__(1024) void inv_k(const int* __restrict__ pc, int* __restrict__ inv)
{
  const int t = threadIdx.x;
  if (t < 1024) inv[t] = 0;
  __syncthreads();
  if (t < 640) {
    const int wide = (pc[3] == 0);
    int s = wide ? pc[4 * t] : pc[2 * t];
    int coord = wide ? pc[4 * t + 2] : pc[2 * t + 1];
    s &= 1;
    const int gs = 16 << s;
    const int k = 1 << (1 - s);
    const int r = (coord / gs) * k, c = (coord % gs) * k;
    for (int oi = 0; oi < k; ++oi)
      for (int oj = 0; oj < k; ++oj) {
        const int rr = r + oi, cc = c + oj;
        if (rr >= 0 && rr < 32 && cc >= 0 && cc < 32)
          inv[rr * 32 + cc] = t;
      }
  }
}

// ---------------------------------------------------------------- gather masks -> NHWC f16 img
__global__ __launch_bounds__(256) void gather16_k(
    const float* __restrict__ masks, const int* __restrict__ inv, f16* __restrict__ img)
{
  const int p = blockIdx.x & 1023, b = blockIdx.x >> 10, t = threadIdx.x;
  img[((size_t)blockIdx.x << 8) + t] = (f16)masks[((size_t)b * 640 + inv[p]) * 256 + t];
}

// ---------------------------------------------------------------- MFMA conv3x3 (NHWC f16)
__global__ __launch_bounds__(256) void conv3m_k(
    const f16* __restrict__ x, const f16* __restrict__ wf, const float* __restrict__ bias,
    f16* __restrict__ y, int H, int W)
{
  const int tilesx = W >> 4;
  const int ty0 = (blockIdx.x / tilesx) << 4, tx0 = (blockIdx.x % tilesx) << 4;
  const int co0 = blockIdx.y << 6;
  const int b = blockIdx.z;
  const int t = threadIdx.x;
  const int lane = t & 63, wv = t >> 6;
  const int frow = lane & 15, kg = lane >> 4;
  __shared__ f16 halo[18][18][40];
  __shared__ f16 bt3[3][64][40];
  f32x4 acc[4][4];
  #pragma unroll
  for (int i = 0; i < 4; ++i)
    #pragma unroll
    for (int j = 0; j < 4; ++j) acc[i][j] = (f32x4){0.f, 0.f, 0.f, 0.f};

  for (int c0 = 0; c0 < 256; c0 += 32) {
    __syncthreads();
    for (int i = t; i < 1296; i += 256) {
      const int cell = i >> 2, part = i & 3;
      const int hy = cell / 18, hx = cell - hy * 18;
      const int gy = ty0 + hy - 1, gx = tx0 + hx - 1;
      f16x8 v = {(f16)0,(f16)0,(f16)0,(f16)0,(f16)0,(f16)0,(f16)0,(f16)0};
      if (gy >= 0 && gy < H && gx >= 0 && gx < W)
        v = *(const f16x8*)&x[(((size_t)b * H + gy) * W + gx) * 256 + c0 + part * 8];
      *(f16x8*)&halo[hy][hx][part * 8] = v;
    }
    for (int kyr = 0; kyr < 3; ++kyr) {
      __syncthreads();
      for (int i = t; i < 768; i += 256) {
        const int tr = i >> 8, rem = i & 255, co = rem >> 2, part = rem & 3;
        *(f16x8*)&bt3[tr][co][part * 8] =
            *(const f16x8*)&wf[(((size_t)(kyr * 3 + tr)) * 256 + co0 + co) * 256 + c0 + part * 8];
      }
      __syncthreads();
      #pragma unroll
      for (int kx = 0; kx < 3; ++kx) {
        f16x8 af[4], bf[4];
        #pragma unroll
        for (int fm = 0; fm < 4; ++fm) {
          const int pos = wv * 64 + fm * 16 + frow;
          af[fm] = *(const f16x8*)&halo[(pos >> 4) + kyr][(pos & 15) + kx][kg * 8];
        }
        #pragma unroll
        for (int fn = 0; fn < 4; ++fn)
          bf[fn] = *(const f16x8*)&bt3[kx][fn * 16 + frow][kg * 8];
        #pragma unroll
        for (int fm = 0; fm < 4; ++fm)
          #pragma unroll
          for (int fn = 0; fn < 4; ++fn)
            acc[fm][fn] = __builtin_amdgcn_mfma_f32_16x16x32_f16(af[fm], bf[fn], acc[fm][fn], 0, 0, 0);
      }
    }
  }
  #pragma unroll
  for (int fn = 0; fn < 4; ++fn) {
    const int col = co0 + fn * 16 + frow;
    const float bv = bias[col];
    #pragma unroll
    for (int fm = 0; fm < 4; ++fm)
      #pragma unroll
      for (int r = 0; r < 4; ++r) {
        const int pos = wv * 64 + fm * 16 + kg * 4 + r;
        y[(((size_t)b * H + ty0 + (pos >> 4)) * W + tx0 + (pos & 15)) * 256 + col] =
            (f16)(acc[fm][fn][r] + bv);
      }
  }
}

// ---------------------------------------------------------------- MFMA convT 2x2 s2
__global__ __launch_bounds__(256) void convtm_k(
    const f16* __restrict__ x, const f16* __restrict__ wtp, const float* __restrict__ bias,
    f16* __restrict__ y, int H, int W)
{
  const int tilesx = W >> 4;
  const int ty0 = (blockIdx.x / tilesx) << 4, tx0 = (blockIdx.x % tilesx) << 4;
  const int co0 = (blockIdx.y >> 2) << 6;
  const int par = blockIdx.y & 3;
  const int pa = par >> 1, pb = par & 1;
  const int b = blockIdx.z;
  const int t = threadIdx.x;
  const int lane = t & 63, wv = t >> 6;
  const int frow = lane & 15, kg = lane >> 4;
  __shared__ f16 at[256][40];
  __shared__ f16 btw[64][40];
  f32x4 acc[4][4];
  #pragma unroll
  for (int i = 0; i < 4; ++i)
    #pragma unroll
    for (int j = 0; j < 4; ++j) acc[i][j] = (f32x4){0.f, 0.f, 0.f, 0.f};

  for (int c0 = 0; c0 < 256; c0 += 32) {
    __syncthreads();
    for (int i = t; i < 1024; i += 256) {
      const int cell = i >> 2, part = i & 3;
      const int gy = ty0 + (cell >> 4), gx = tx0 + (cell & 15);
      *(f16x8*)&at[cell][part * 8] =
          *(const f16x8*)&x[(((size_t)b * H + gy) * W + gx) * 256 + c0 + part * 8];
    }
    {
      const int i = t;
      const int co = i >> 2, part = i & 3;
      *(f16x8*)&btw[co][part * 8] =
          *(const f16x8*)&wtp[((size_t)par * 256 + co0 + co) * 256 + c0 + part * 8];
    }
    __syncthreads();
    f16x8 af[4], bf[4];
    #pragma unroll
    for (int fm = 0; fm < 4; ++fm)
      af[fm] = *(const f16x8*)&at[wv * 64 + fm * 16 + frow][kg * 8];
    #pragma unroll
    for (int fn = 0; fn < 4; ++fn)
      bf[fn] = *(const f16x8*)&btw[fn * 16 + frow][kg * 8];
    #pragma unroll
    for (int fm = 0; fm < 4; ++fm)
      #pragma unroll
      for (int fn = 0; fn < 4; ++fn)
        acc[fm][fn] = __builtin_amdgcn_mfma_f32_16x16x32_f16(af[fm], bf[fn], acc[fm][fn], 0, 0, 0);
  }
  const int HO = H << 1, WO = W << 1;
  #pragma unroll
  for (int fn = 0; fn < 4; ++fn) {
    const int col = co0 + fn * 16 + frow;
    const float bv = bias[col];
    #pragma unroll
    for (int fm = 0; fm < 4; ++fm)
      #pragma unroll
      for (int r = 0; r < 4; ++r) {
        const int pos = wv * 64 + fm * 16 + kg * 4 + r;
        const int oy = ((ty0 + (pos >> 4)) << 1) + pa;
        const int ox = ((tx0 + (pos & 15)) << 1) + pb;
        y[(((size_t)b * HO + oy) * WO + ox) * 256 + col] = (f16)(acc[fm][fn][r] + bv);
      }
  }
}

// ---------------------------------------------------------------- instance-norm stats + normalize
__global__ __launch_bounds__(256) void stats1_k(
    const f16* __restrict__ x, float2* __restrict__ partial, int HW, int NS)
{
  const int s = blockIdx.x, b = blockIdx.y, t = threadIdx.x;
  const int rpb = HW / NS;
  const f16* p = x + ((size_t)b * HW + (size_t)s * rpb) * 256;
  float s1 = 0.f, s2 = 0.f;
  for (int r = 0; r < rpb; ++r) {
    const float v = (float)p[(size_t)r * 256 + t];
    s1 += v; s2 += v * v;
  }
  partial[((size_t)b * NS + s) * 256 + t] = make_float2(s1, s2);
}
__global__ __launch_bounds__(256) void stats2_k(
    const float2* __restrict__ partial, float2* __restrict__ mr, int HW, int NS)
{
  const int b = blockIdx.x, t = threadIdx.x;
  float s1 = 0.f, s2 = 0.f;
  for (int s = 0; s < NS; ++s) {
    const float2 v = partial[((size_t)b * NS + s) * 256 + t];
    s1 += v.x; s2 += v.y;
  }
  const float m = s1 / (float)HW;
  const float var = fmaxf(s2 / (float)HW - m * m, 0.f);
  mr[b * 256 + t] = make_float2(m, rsqrtf(var + 1e-5f));
}
__global__ __launch_bounds__(256) void norm_k(
    f16* __restrict__ x, const float2* __restrict__ mr, int HW)
{
  const int b = blockIdx.y, t = threadIdx.x;
  const float2 v = mr[b * 256 + t];
  f16* p = x + ((size_t)b * HW + (size_t)blockIdx.x * 8) * 256;
  #pragma unroll
  for (int r = 0; r < 8; ++r) {
    float z = ((float)p[(size_t)r * 256 + t] - v.x) * v.y;
    p[(size_t)r * 256 + t] = (f16)(z >= 0.f ? z : 0.01f * z);
  }
}

// ---------------------------------------------------------------- MFMA out conv 3x3: 256 -> 3 (pad 16)
__global__ __launch_bounds__(256) void convoutm2_k(
    const f16* __restrict__ x, const f16* __restrict__ wocp, const float* __restrict__ bias,
    void* __restrict__ yv, const int* __restrict__ flags)
{
  const int ty0 = (blockIdx.x >> 4) << 4, tx0 = (blockIdx.x & 15) << 4;
  const int b = blockIdx.y;
  const int t = threadIdx.x;
  const int lane = t & 63, wv = t >> 6;
  const int frow = lane & 15, kg = lane >> 4;
  __shared__ f16 halo[18][18][40];
  __shared__ f16 bt[9][16][40];
  f32x4 acc[4];
  #pragma unroll
  for (int i = 0; i < 4; ++i) acc[i] = (f32x4){0.f, 0.f, 0.f, 0.f};

  for (int c0 = 0; c0 < 256; c0 += 32) {
    __syncthreads();
    for (int i = t; i < 1296; i += 256) {
      const int cell = i >> 2, part = i & 3;
      const int hy = cell / 18, hx = cell - hy * 18;
      const int gy = ty0 + hy - 1, gx = tx0 + hx - 1;
      f16x8 v = {(f16)0,(f16)0,(f16)0,(f16)0,(f16)0,(f16)0,(f16)0,(f16)0};
      if ((unsigned)gy < 256u && (unsigned)gx < 256u)
        v = *(const f16x8*)&x[(((size_t)b * 256 + gy) * 256 + gx) * 256 + c0 + part * 8];
      *(f16x8*)&halo[hy][hx][part * 8] = v;
    }
    for (int i = t; i < 576; i += 256) {
      const int tap = i >> 6, rem = i & 63, co = rem >> 2, part = rem & 3;
      *(f16x8*)&bt[tap][co][part * 8] =
          *(const f16x8*)&wocp[((size_t)(tap * 16 + co)) * 256 + c0 + part * 8];
    }
    __syncthreads();
    #pragma unroll
    for (int kyr = 0; kyr < 3; ++kyr)
      #pragma unroll
      for (int kx = 0; kx < 3; ++kx) {
        const f16x8 bf = *(const f16x8*)&bt[kyr * 3 + kx][frow][kg * 8];
        #pragma unroll
        for (int fm = 0; fm < 4; ++fm) {
          const int pos = wv * 64 + fm * 16 + frow;
          const f16x8 af = *(const f16x8*)&halo[(pos >> 4) + kyr][(pos & 15) + kx][kg * 8];
          acc[fm] = __builtin_amdgcn_mfma_f32_16x16x32_f16(af, bf, acc[fm], 0, 0, 0);
        }
      }
  }
  if (frow < 3) {
    const int fp32 = flags[0];
    const float bv = bias[frow];
    #pragma unroll
    for (int fm = 0; fm < 4; ++fm)
      #pragma unroll
      for (int r = 0; r < 4; ++r) {
        const int pos = wv * 64 + fm * 16 + kg * 4 + r;
        const int oy = ty0 + (pos >> 4), ox = tx0 + (pos & 15);
        const size_t oidx = (((size_t)b * 3 + frow) * 256 + oy) * 256 + ox;
        const float v = acc[fm][r] + bv;
        if (fp32) ((float*)yv)[oidx] = v;
        else      ((bf16*)yv)[oidx] = __float2bfloat16(v);
      }
  }
}

// ================================================================ host
extern "C" void kernel_launch(void* const* d_in, const int* in_sizes, int n_in,
                              void* d_out, int out_size, void* d_ws, size_t ws_size,
                              hipStream_t stream) {
  (void)in_sizes; (void)n_in; (void)out_size; (void)ws_size;
  const int* pc = (const int*)d_in[1];

  float* P = (float*)d_ws;
  size_t off = 0;
  CvtDesc cd{};
  int seg = 0;
  auto alloc = [&](size_t n) { float* p = P + off; off += n; return p; };
  auto allocCv = [&](int idx, size_t n) {
    float* p = P + off;
    cd.src[seg] = d_in[idx]; cd.dstOff[seg] = (unsigned)off; cd.n[seg] = (unsigned)n;
    ++seg; off += n; return p;
  };

  // ---- persistent small region ----
  int*    flags   = (int*)alloc(16);
  int*    invbuf  = (int*)alloc(1024);
  float2* partial = (float2*)alloc(131072);
  float2* mr1     = (float2*)alloc(1024);
  float* pdb   = allocCv(3, 256);
  float* pw1   = allocCv(4, 512);
  float* pb1   = allocCv(5, 256);
  float* pb2   = allocCv(7, 256);
  float* pln1g = allocCv(9, 512);
  float* pln1b = allocCv(10, 512);
  float* pqkvb = allocCv(12, 1536);
  float* pattb = allocCv(14, 512);
  float* pln2g = allocCv(15, 512);
  float* pln2b = allocCv(16, 512);
  float* pm1b  = allocCv(18, 2048);
  float* pm2b  = allocCv(20, 512);
  float* pdecg = allocCv(21, 256);
  float* pdecb = allocCv(22, 256);
  float* pmg   = allocCv(25, 256);
  float* pmb   = allocCv(26, 256);
  float* pucb  = allocCv(28, 768);
  float* putb  = allocCv(30, 768);
  float* pocw  = allocCv(31, 6912);
  float* pocb  = allocCv(32, 16);
  off = (off + 255) & ~(size_t)255;
  f16* wf3  = (f16*)alloc(884736);
  f16* wt   = (f16*)alloc(393216);
  f16* wocp = (f16*)alloc(18432);      // 9*16*256 f16
  off = (off + 255) & ~(size_t)255;

  // ---- zone A: big fp32 params + transformer scratch, later overlaid by R2 (f16) ----
  float* zoneA = P + off;
  f16*   R2h   = (f16*)zoneA;
  {
    size_t zo = off;
    auto zCv = [&](int idx, size_t n) {
      float* p = P + zo;
      cd.src[seg] = d_in[idx]; cd.dstOff[seg] = (unsigned)zo; cd.n[seg] = (unsigned)n;
      ++seg; zo += n; return p;
    };
    float* px    = zCv(0, 655360);
    float* pdw   = zCv(2, 131072);
    float* pw2   = zCv(6, 65536);
    float* pcls  = zCv(8, 65536);
    float* pqkvw = zCv(11, 393216);
    float* pattw = zCv(13, 131072);
    float* pm1w  = zCv(17, 524288);
    float* pm2w  = zCv(19, 524288);
    float* pprp  = zCv(23, 65536);
    float* pprc  = zCv(24, 65536);
    float* pucw  = zCv(27, 1769472);
    float* putw  = zCv(29, 786432);
    float* xbuf   = P + zo; zo += 458752;
    float* hbuf   = P + zo; zo += 458752;
    float* qkvbuf = P + zo; zo += 1376256;
    float* hidbuf = P + zo; zo += 1835008;
    float* posbuf = P + zo; zo += 163840;
    float* patbuf = P + zo; zo += 327680;
    float* clsbuf = P + zo; zo += 131072;
    float* masksb = P + zo; zo += 327680;
    off += 16777216;
    f16* R0h = (f16*)(P + off); off += 4194304;
    f16* R1h = (f16*)(P + off); off += 4194304;

    // 0) detect dtype, convert inputs to fp32, prep conv weights
    detect_k<<<1, 64, 0, stream>>>((const unsigned short*)d_in[0], flags);
    cvtall_k<<<dim3(256, NSEG), 256, 0, stream>>>(cd, P, flags);
    prepw_k<<<2048, 256, 0, stream>>>(pucw, putw, pocw, wf3, wt, wocp);

    // 1) positional MLP + patch projection + sequence assembly
    pos_k<<<640, 256, 0, stream>>>(pc, pw1, pb1, pw2, pb2, posbuf);
    gemm64_k<false, 0><<<dim3(4, 20), 256, 0, stream>>>(
        px, pdw, pdb, nullptr, hidbuf, 1280, 256, 512);
    assemble_k<<<1792, 256, 0, stream>>>(hidbuf, posbuf, pcls, xbuf);

    // 2) transformer blocks (MFMA GEMMs, 64x64 tiles)
    for (int l = 0; l < 2; ++l) {
      ln_k<<<1792, 256, 0, stream>>>(xbuf, hbuf, pln1g + l * 256, pln1b + l * 256);
      gemm64_k<false, 0><<<dim3(12, 28), 256, 0, stream>>>(
          hbuf, pqkvw + (size_t)l * 196608, pqkvb + l * 768, nullptr, qkvbuf, 1792, 768, 256);
      attnm_k<<<dim3(28, 8, 2), 128, 0, stream>>>(qkvbuf, hbuf);
      gemm64_k<false, 0><<<dim3(4, 28), 256, 0, stream>>>(
          hbuf, pattw + (size_t)l * 65536, pattb + l * 256, xbuf, xbuf, 1792, 256, 256);
      ln_k<<<1792, 256, 0, stream>>>(xbuf, hbuf, pln2g + l * 256, pln2b + l * 256);
      gemm64_k<false, 1><<<dim3(16, 28), 256, 0, stream>>>(
          hbuf, pm1w + (size_t)l * 262144, pm1b + l * 1024, nullptr, hidbuf, 1792, 1024, 256);
      gemm64_k<false, 0><<<dim3(4, 28), 256, 0, stream>>>(
          hidbuf, pm2w + (size_t)l * 262144, pm2b + l * 256, xbuf, xbuf, 1792, 256, 1024);
    }

    // 3) decoder head
    ln_k<<<1792, 256, 0, stream>>>(xbuf, hbuf, pdecg, pdecb);
    for (int b = 0; b < 2; ++b) {
      gemm64_k<false, 0><<<dim3(4, 10), 256, 0, stream>>>(
          hbuf + (size_t)b * 896 * 256, pprp, nullptr, nullptr,
          patbuf + (size_t)b * 640 * 256, 640, 256, 256);
      gemm64_k<false, 0><<<dim3(4, 4), 256, 0, stream>>>(
          hbuf + ((size_t)b * 896 + 640) * 256, pprc, nullptr, nullptr,
          clsbuf + (size_t)b * 65536, 256, 256, 256);
    }
    l2n_k<<<1280, 256, 0, stream>>>(patbuf);
    l2n_k<<<512, 256, 0, stream>>>(clsbuf);
    for (int b = 0; b < 2; ++b) {
      gemm64_k<true, 0><<<dim3(4, 10), 256, 0, stream>>>(
          patbuf + (size_t)b * 163840, clsbuf + (size_t)b * 65536, nullptr, nullptr,
          masksb + (size_t)b * 163840, 640, 256, 256);
    }
    ln_k<<<1280, 256, 0, stream>>>(masksb, masksb, pmg, pmb);

    // 4) scatter table + gather (NHWC f16)
    inv_k<<<1, 1024, 0, stream>>>(pc, invbuf);
    gather16_k<<<2048, 256, 0, stream>>>(masksb, invbuf, R0h);

    // 5) MFMA conv decoder
    const int NS = 128;
    int H = 32;
    for (int i = 0; i < 3; ++i) {
      conv3m_k<<<dim3((H / 16) * (H / 16), 4, 2), 256, 0, stream>>>(
          R0h, wf3 + (size_t)i * 9 * 65536, pucb + i * 256, R1h, H, H);
      stats1_k<<<dim3(NS, 2), 256, 0, stream>>>(R1h, partial, H * H, NS);
      stats2_k<<<2, 256, 0, stream>>>(partial, mr1, H * H, NS);
      norm_k<<<dim3(H * H / 8, 2), 256, 0, stream>>>(R1h, mr1, H * H);
      f16* dst = (i == 2) ? R2h : R0h;
      convtm_k<<<dim3((H / 16) * (H / 16), 16, 2), 256, 0, stream>>>(
          R1h, wt + (size_t)i * 4 * 65536, putb + i * 256, dst, H, H);
      stats1_k<<<dim3(NS, 2), 256, 0, stream>>>(dst, partial, 4 * H * H, NS);
      stats2_k<<<2, 256, 0, stream>>>(partial, mr1, 4 * H * H, NS);
      norm_k<<<dim3(4 * H * H / 8, 2), 256, 0, stream>>>(dst, mr1, 4 * H * H);
      H *= 2;
    }

    // 6) output conv 256 -> 3 via MFMA (co padded to 16)
    convoutm2_k<<<dim3(256, 2), 256, 0, stream>>>(R2h, wocp, pocb, d_out, flags);
  }
}